// Round 1
// baseline (3383.702 us; speedup 1.0000x reference)
//
#include <hip/hip_runtime.h>
#include <math.h>

// Problem constants
#define B_ 4
#define S_ 1024
#define D_ 512
#define H_ 8
#define DH_ 64
#define I_ 2048
#define E_ 8
#define L_ 4
#define T_ 4096   // B*S
#define D2_ 256

using bf16x8 = __attribute__((ext_vector_type(8))) __bf16;
using f32x4  = __attribute__((ext_vector_type(4))) float;

__device__ __forceinline__ float wred_sum(float v){
#pragma unroll
  for(int m=32;m>0;m>>=1) v += __shfl_xor(v, m, 64);
  return v;
}
__device__ __forceinline__ float wred_max(float v){
#pragma unroll
  for(int m=32;m>0;m>>=1) v = fmaxf(v, __shfl_xor(v, m, 64));
  return v;
}
// fp32 -> bf16 (RNE) and back, bit-level (values are finite; no NaN concern)
__device__ __forceinline__ unsigned short f2bf(float f){
  unsigned x = __float_as_uint(f);
  unsigned r = (x + 0x7FFFu + ((x>>16)&1u)) >> 16;
  return (unsigned short)r;
}
__device__ __forceinline__ float bf2f(unsigned short u){
  return __uint_as_float(((unsigned)u)<<16);
}
__device__ __forceinline__ unsigned pk2(float a, float b){
  return (unsigned)f2bf(a) | ((unsigned)f2bf(b)<<16);
}

// ---------------------------------------------------------------------------
// Generic bf16-MFMA tile GEMM, NT convention: C[m,n] = sum_k A[m,k]*B[n,k]
// BM=128 fixed, BN in {128,64}. 256 threads = 4 waves in 2x2, wave tile
// (64, BN/2), fragments of v_mfma_f32_16x16x32_bf16.
// A/B staged fp32->bf16 (or raw bf16) into LDS each BK=32 step.
// MOE mode: blockIdx.z = expert; rows are a compacted segment (optionally
// gathered through rowtok); B/bias strided per expert.
// ---------------------------------------------------------------------------
template<int BN, bool A_BF16, bool B_BF16, bool MOE, bool GATHER, bool OUT_BF16, int ACT, bool ADD_IN>
__global__ __launch_bounds__(256)
void gemm_k(const void* __restrict__ Ap, const void* __restrict__ Bp, void* Cp,
            const float* __restrict__ bias, const float* addin,
            int M, int N, int K, int lda, int ldb, int ldc,
            int hdiv, long sAb, long sAh, long sBb, long sBh, long sCb, long sCh,
            float scale,
            const int* __restrict__ moff, const int* __restrict__ mcnt,
            const int* __restrict__ rowtok, long sBe, int biasStride)
{
  constexpr int BM = 128, BK = 32;
  constexpr int WM = 64, WN = BN/2, FM = 4, FN = BN/32;
  __shared__ unsigned short As[BM][BK];
  __shared__ unsigned short Bs[BN][BK];

  const int tid = threadIdx.x, wid = tid>>6, lane = tid&63;
  const int wy = wid>>1, wx = wid&1, ln16 = lane&15, q8 = (lane>>4)*8;
  const int m0 = blockIdx.x*BM, n0 = blockIdx.y*BN;

  const float* Af = nullptr; const unsigned short* Ah = nullptr;
  const float* Bf = nullptr; const unsigned short* Bh = nullptr;
  float* Cf = nullptr; unsigned short* Ch = nullptr;
  const float* biasp = bias;
  int seg = 0, cnt = M;

  if constexpr (MOE){
    int e = blockIdx.z;
    seg = moff[e]; cnt = mcnt[e];
    if (m0 >= cnt) return;
    if constexpr (A_BF16) Ah = (const unsigned short*)Ap; else Af = (const float*)Ap;
    if constexpr (B_BF16) Bh = (const unsigned short*)Bp + (long)e*sBe; else Bf = (const float*)Bp + (long)e*sBe;
    if constexpr (OUT_BF16) Ch = (unsigned short*)Cp; else Cf = (float*)Cp;
    if (biasp) biasp += (long)e*biasStride;
  } else {
    int z = blockIdx.z, zb = z/hdiv, zh = z%hdiv;
    long aoff = (long)zb*sAb + (long)zh*sAh;
    long boff = (long)zb*sBb + (long)zh*sBh;
    long coff = (long)zb*sCb + (long)zh*sCh;
    if constexpr (A_BF16) Ah = (const unsigned short*)Ap + aoff; else Af = (const float*)Ap + aoff;
    if constexpr (B_BF16) Bh = (const unsigned short*)Bp + boff; else Bf = (const float*)Bp + boff;
    if constexpr (OUT_BF16) Ch = (unsigned short*)Cp + coff; else Cf = ((float*)Cp) + coff;
    if constexpr (ADD_IN) addin += coff;
  }

  // Staging geometry
  const int arow = tid>>1, acol = (tid&1)*16;        // 16 elems/thread for A
  int brow, bcol;
  if constexpr (BN == 128){ brow = tid>>1; bcol = (tid&1)*16; }
  else { brow = tid>>2; bcol = (tid&3)*8; }

  long arb;
  {
    int r = m0 + arow;
    if constexpr (MOE){
      int rl = min(r, cnt-1);
      if constexpr (GATHER) arb = (long)rowtok[seg+rl]*lda;
      else arb = (long)(seg+rl)*lda;
    } else arb = (long)min(r, M-1)*lda;
  }
  long brb = (long)min(n0+brow, N-1)*ldb;

  f32x4 acc[FM][FN];
#pragma unroll
  for(int i=0;i<FM;i++)
#pragma unroll
    for(int j=0;j<FN;j++){ f32x4 z = {0.f,0.f,0.f,0.f}; acc[i][j] = z; }

  for (int k0 = 0; k0 < K; k0 += BK){
    __syncthreads();
    // --- stage A tile ---
    if constexpr (!A_BF16){
      const float* p = Af + arb + k0 + acol;
      float4 v0=*(const float4*)p, v1=*(const float4*)(p+4), v2=*(const float4*)(p+8), v3=*(const float4*)(p+12);
      uint4* d = (uint4*)&As[arow][acol];
      d[0] = make_uint4(pk2(v0.x,v0.y), pk2(v0.z,v0.w), pk2(v1.x,v1.y), pk2(v1.z,v1.w));
      d[1] = make_uint4(pk2(v2.x,v2.y), pk2(v2.z,v2.w), pk2(v3.x,v3.y), pk2(v3.z,v3.w));
    } else {
      const uint4* p = (const uint4*)(Ah + arb + k0 + acol);
      uint4* d = (uint4*)&As[arow][acol];
      d[0] = p[0]; d[1] = p[1];
    }
    // --- stage B tile ---
    if constexpr (BN == 128){
      if constexpr (!B_BF16){
        const float* p = Bf + brb + k0 + bcol;
        float4 v0=*(const float4*)p, v1=*(const float4*)(p+4), v2=*(const float4*)(p+8), v3=*(const float4*)(p+12);
        uint4* d = (uint4*)&Bs[brow][bcol];
        d[0] = make_uint4(pk2(v0.x,v0.y), pk2(v0.z,v0.w), pk2(v1.x,v1.y), pk2(v1.z,v1.w));
        d[1] = make_uint4(pk2(v2.x,v2.y), pk2(v2.z,v2.w), pk2(v3.x,v3.y), pk2(v3.z,v3.w));
      } else {
        const uint4* p = (const uint4*)(Bh + brb + k0 + bcol);
        uint4* d = (uint4*)&Bs[brow][bcol];
        d[0] = p[0]; d[1] = p[1];
      }
    } else {
      if constexpr (!B_BF16){
        const float* p = Bf + brb + k0 + bcol;
        float4 v0=*(const float4*)p, v1=*(const float4*)(p+4);
        *(uint4*)&Bs[brow][bcol] = make_uint4(pk2(v0.x,v0.y), pk2(v0.z,v0.w), pk2(v1.x,v1.y), pk2(v1.z,v1.w));
      } else {
        *(uint4*)&Bs[brow][bcol] = *(const uint4*)(Bh + brb + k0 + bcol);
      }
    }
    __syncthreads();
    // --- fragments + MFMA ---
    bf16x8 fa[FM], fb[FN];
#pragma unroll
    for(int i=0;i<FM;i++) fa[i] = *(const bf16x8*)&As[wy*WM + i*16 + ln16][q8];
#pragma unroll
    for(int j=0;j<FN;j++) fb[j] = *(const bf16x8*)&Bs[wx*WN + j*16 + ln16][q8];
#pragma unroll
    for(int i=0;i<FM;i++)
#pragma unroll
      for(int j=0;j<FN;j++)
        acc[i][j] = __builtin_amdgcn_mfma_f32_16x16x32_bf16(fa[i], fb[j], acc[i][j], 0, 0, 0);
  }

  // --- epilogue: C[m = quad*4+r][n = lane&15] (m89/m91-verified layout) ---
#pragma unroll
  for(int i=0;i<FM;i++){
    int mbase = m0 + wy*WM + i*16 + (lane>>4)*4;
#pragma unroll
    for(int j=0;j<FN;j++){
      int n = n0 + wx*WN + j*16 + ln16;
      float bv = biasp ? biasp[n] : 0.f;
      f32x4 v = acc[i][j];
#pragma unroll
      for(int r=0;r<4;r++){
        int m = mbase + r;
        if (m < cnt && n < N){
          float x = v[r]*scale + bv;
          if constexpr (ACT == 1) x = 0.5f*x*(1.f + erff(x*0.70710678118654752f));
          long ci = (long)(MOE ? seg + m : m)*ldc + n;
          if constexpr (ADD_IN) x += addin[ci];
          if constexpr (OUT_BF16) Ch[ci] = f2bf(x);
          else Cf[ci] = x;
        }
      }
    }
  }
}

// ---------------------------------------------------------------------------
// LayerNorm over D=512, optional residual add (out = LN(in [+ resid]) * w + b)
// ---------------------------------------------------------------------------
__global__ __launch_bounds__(128)
void ln_k(const float* __restrict__ in, const float* __restrict__ resid,
          const float* __restrict__ w, const float* __restrict__ bb, float* __restrict__ outp)
{
  int row = blockIdx.x, t = threadIdx.x, wid = t>>6, lane = t&63;
  float4 v = ((const float4*)(in + (long)row*512))[t];
  if (resid){
    float4 r = ((const float4*)(resid + (long)row*512))[t];
    v.x += r.x; v.y += r.y; v.z += r.z; v.w += r.w;
  }
  float s = v.x+v.y+v.z+v.w;
  float q = v.x*v.x+v.y*v.y+v.z*v.z+v.w*v.w;
  s = wred_sum(s); q = wred_sum(q);
  __shared__ float rs[2], rq[2];
  if (lane==0){ rs[wid]=s; rq[wid]=q; }
  __syncthreads();
  s = rs[0]+rs[1]; q = rq[0]+rq[1];
  float mean = s*(1.f/512.f);
  float var  = q*(1.f/512.f) - mean*mean;
  float inv  = rsqrtf(var + 1e-5f);
  float4 wv = ((const float4*)w)[t], bv = ((const float4*)bb)[t];
  float4 o;
  o.x = (v.x-mean)*inv*wv.x + bv.x;
  o.y = (v.y-mean)*inv*wv.y + bv.y;
  o.z = (v.z-mean)*inv*wv.z + bv.z;
  o.w = (v.w-mean)*inv*wv.w + bv.w;
  ((float4*)(outp + (long)row*512))[t] = o;
}

// Row softmax over len=1024, bf16 in-place (scores already scaled by 1/8)
__global__ __launch_bounds__(256)
void softmax_k(unsigned short* __restrict__ S)
{
  long row = blockIdx.x;
  unsigned short* p = S + row*1024;
  int t = threadIdx.x, wid = t>>6, lane = t&63;
  uint2 u = *(const uint2*)(p + t*4);
  const unsigned short* hb = (const unsigned short*)&u;
  float x0 = bf2f(hb[0]), x1 = bf2f(hb[1]), x2 = bf2f(hb[2]), x3 = bf2f(hb[3]);
  float mx = fmaxf(fmaxf(x0,x1), fmaxf(x2,x3));
  mx = wred_max(mx);
  __shared__ float red[8];
  if (lane==0) red[wid] = mx;
  __syncthreads();
  mx = fmaxf(fmaxf(red[0],red[1]), fmaxf(red[2],red[3]));
  float e0 = __expf(x0-mx), e1 = __expf(x1-mx), e2 = __expf(x2-mx), e3 = __expf(x3-mx);
  float s = e0+e1+e2+e3;
  s = wred_sum(s);
  if (lane==0) red[4+wid] = s;
  __syncthreads();
  s = red[4]+red[5]+red[6]+red[7];
  float inv = 1.f/s;
  *(uint2*)(p + t*4) = make_uint2(pk2(e0*inv, e1*inv), pk2(e2*inv, e3*inv));
}

// Build Vt[bh][d][k] (fp32) from qkv's V slice, LDS tile transpose
__global__ __launch_bounds__(256)
void vt_k(const float* __restrict__ qkv, float* __restrict__ Vt)
{
  __shared__ float tile[64][65];
  int z = blockIdx.y, b = z>>3, h = z&7;
  int k0 = blockIdx.x*64;
  int t = threadIdx.x;
  int kk = t>>2, dd = (t&3)*16;
  const float* p = qkv + ((long)(b*1024 + k0 + kk))*1536 + 1024 + h*64 + dd;
  float4 v0=*(const float4*)p, v1=*(const float4*)(p+4), v2=*(const float4*)(p+8), v3=*(const float4*)(p+12);
  tile[kk][dd+0]=v0.x; tile[kk][dd+1]=v0.y; tile[kk][dd+2]=v0.z; tile[kk][dd+3]=v0.w;
  tile[kk][dd+4]=v1.x; tile[kk][dd+5]=v1.y; tile[kk][dd+6]=v1.z; tile[kk][dd+7]=v1.w;
  tile[kk][dd+8]=v2.x; tile[kk][dd+9]=v2.y; tile[kk][dd+10]=v2.z; tile[kk][dd+11]=v2.w;
  tile[kk][dd+12]=v3.x; tile[kk][dd+13]=v3.y; tile[kk][dd+14]=v3.z; tile[kk][dd+15]=v3.w;
  __syncthreads();
  int dd2 = t>>2, kk2 = (t&3)*16;
  float* o = Vt + (long)z*65536 + (long)dd2*1024 + k0 + kk2;
#pragma unroll
  for(int c=0;c<4;c++){
    float4 w = make_float4(tile[kk2+c*4+0][dd2], tile[kk2+c*4+1][dd2],
                           tile[kk2+c*4+2][dd2], tile[kk2+c*4+3][dd2]);
    *(float4*)(o + c*4) = w;
  }
}

// (B,H,S,dh) -> (B,S,H*dh)
__global__ __launch_bounds__(256)
void permute_k(const float* __restrict__ in, float* __restrict__ outp)
{
  int gid = blockIdx.x*256 + threadIdx.x;
  long o4 = (long)gid*4;
  int b = (int)(o4 >> 19);
  int r = (int)(o4 & 524287);
  int s = r >> 9;
  int c = r & 511;
  int h = c >> 6;
  int dd = c & 63;
  long iidx = (((long)b*8 + h)*1024 + s)*64 + dd;
  *(float4*)(outp + o4) = *(const float4*)(in + iidx);
}

// fp32 (R,C) -> bf16 (C,R), batched over blockIdx.z
__global__ __launch_bounds__(256)
void transpose_cast_k(const float* __restrict__ in, unsigned short* __restrict__ outp, int R, int C)
{
  __shared__ float tile[64][65];
  long zoff = (long)blockIdx.z * R * C;
  in += zoff; outp += zoff;
  int c0 = blockIdx.x*64, r0 = blockIdx.y*64;
  int t = threadIdx.x;
  int rr = t>>2, cc = (t&3)*16;
  const float* p = in + (long)(r0+rr)*C + c0 + cc;
  float4 v0=*(const float4*)p, v1=*(const float4*)(p+4), v2=*(const float4*)(p+8), v3=*(const float4*)(p+12);
  tile[rr][cc+0]=v0.x; tile[rr][cc+1]=v0.y; tile[rr][cc+2]=v0.z; tile[rr][cc+3]=v0.w;
  tile[rr][cc+4]=v1.x; tile[rr][cc+5]=v1.y; tile[rr][cc+6]=v1.z; tile[rr][cc+7]=v1.w;
  tile[rr][cc+8]=v2.x; tile[rr][cc+9]=v2.y; tile[rr][cc+10]=v2.z; tile[rr][cc+11]=v2.w;
  tile[rr][cc+12]=v3.x; tile[rr][cc+13]=v3.y; tile[rr][cc+14]=v3.z; tile[rr][cc+15]=v3.w;
  __syncthreads();
  int cc2 = t>>2, rr2 = (t&3)*16;
  unsigned tmp[8];
#pragma unroll
  for(int jj=0;jj<8;jj++)
    tmp[jj] = pk2(tile[rr2+2*jj][cc2], tile[rr2+2*jj+1][cc2]);
  uint4* dst = (uint4*)(outp + (long)(c0+cc2)*R + r0 + rr2);
  dst[0] = make_uint4(tmp[0],tmp[1],tmp[2],tmp[3]);
  dst[1] = make_uint4(tmp[4],tmp[5],tmp[6],tmp[7]);
}

// Gate: softmax over E=8 logits, top-2, normalized weights; one wave/token
__global__ __launch_bounds__(256)
void route_k(const float* __restrict__ flat, const float* __restrict__ gw,
             int* __restrict__ tok_e, float* __restrict__ tok_w, int* __restrict__ counts)
{
  int wid = threadIdx.x>>6, lane = threadIdx.x&63;
  int t = blockIdx.x*4 + wid;
  const float4* xr = (const float4*)(flat + (long)t*512);
  float4 x0 = xr[lane*2], x1 = xr[lane*2+1];
  float lg[8];
#pragma unroll
  for(int e=0;e<8;e++){
    const float4* gr = (const float4*)(gw + e*512);
    float4 g0 = gr[lane*2], g1 = gr[lane*2+1];
    float d = x0.x*g0.x + x0.y*g0.y + x0.z*g0.z + x0.w*g0.w
            + x1.x*g1.x + x1.y*g1.y + x1.z*g1.z + x1.w*g1.w;
    lg[e] = wred_sum(d);
  }
  if (lane == 0){
    float mx = lg[0];
#pragma unroll
    for(int e=1;e<8;e++) mx = fmaxf(mx, lg[e]);
    float p[8];
#pragma unroll
    for(int e=0;e<8;e++) p[e] = expf(lg[e]-mx);
    int e0 = 0; float p0 = p[0];
#pragma unroll
    for(int e=1;e<8;e++) if (p[e] > p0){ p0 = p[e]; e0 = e; }
    int e1 = -1; float p1 = -1.f;
#pragma unroll
    for(int e=0;e<8;e++) if (e != e0 && p[e] > p1){ p1 = p[e]; e1 = e; }
    float inv = 1.f/(p0+p1);
    tok_e[2*t] = e0; tok_e[2*t+1] = e1;
    tok_w[2*t] = p0*inv; tok_w[2*t+1] = p1*inv;
    atomicAdd(&counts[e0], 1); atomicAdd(&counts[e1], 1);
  }
}

__global__ void offsets_k(const int* __restrict__ counts, int* __restrict__ offs,
                          int* __restrict__ cursors, float* __restrict__ aux)
{
  if (threadIdx.x == 0 && blockIdx.x == 0){
    int o = 0; float a = 0.f;
    for(int e=0;e<8;e++){
      offs[e] = o; o += counts[e]; cursors[e] = 0;
      float u = (float)counts[e]*(1.f/4096.f) - 0.125f;
      a += u*u;
    }
    *aux += a*(1.f/8.f);
  }
}

__global__ __launch_bounds__(256)
void scatter_k(const int* __restrict__ tok_e, const float* __restrict__ tok_w,
               const int* __restrict__ offs, int* __restrict__ cursors,
               int* __restrict__ rowtok, float* __restrict__ roww, int* __restrict__ rowof)
{
  int i = blockIdx.x*256 + threadIdx.x;   // 8192 (token,k) pairs
  int e = tok_e[i]; float w = tok_w[i];
  int pos = offs[e] + atomicAdd(&cursors[e], 1);
  rowtok[pos] = i>>1;
  roww[pos] = w;
  rowof[i] = pos;
}

// moe_out[t,:] = (w0*eout[r0,:] + w1*eout[r1,:]) * mask[t]
__global__ __launch_bounds__(256)
void combine_k(const float* __restrict__ eout, const int* __restrict__ rowof,
               const float* __restrict__ roww, const float* __restrict__ mask, float* __restrict__ moe)
{
  int gid = blockIdx.x*256 + threadIdx.x;
  long o4 = (long)gid*4;
  int tok = (int)(o4 >> 9);
  int d = (int)(o4 & 511);
  int r0 = rowof[2*tok], r1 = rowof[2*tok+1];
  float w0 = roww[r0], w1 = roww[r1];
  float mk = mask[tok];
  float4 a = *(const float4*)(eout + (long)r0*512 + d);
  float4 b = *(const float4*)(eout + (long)r1*512 + d);
  float4 o;
  o.x = (a.x*w0 + b.x*w1)*mk;
  o.y = (a.y*w0 + b.y*w1)*mk;
  o.z = (a.z*w0 + b.z*w1)*mk;
  o.w = (a.w*w0 + b.w*w1)*mk;
  *(float4*)(moe + o4) = o;
}

// masked-sum partial pooling: grid (B*16), each block sums 64 seq positions
__global__ __launch_bounds__(256)
void pool_k(const float* __restrict__ h, const float* __restrict__ mask, float* __restrict__ pooled)
{
  int z = blockIdx.x, b = z>>4, sc = z&15, t = threadIdx.x;
  float a0 = 0.f, a1 = 0.f;
  for(int ss=0;ss<64;ss++){
    int s = sc*64 + ss;
    float mk = mask[b*1024 + s];
    const float* r = h + ((long)b*1024 + s)*512;
    a0 += r[t]*mk; a1 += r[t+256]*mk;
  }
  atomicAdd(&pooled[b*512 + t], a0);
  atomicAdd(&pooled[b*512 + t + 256], a1);
}

__global__ __launch_bounds__(256)
void head_final_k(const float* __restrict__ pooled, const float* __restrict__ mask,
                  const float* __restrict__ pool_w, const float* __restrict__ pool_b,
                  const float* __restrict__ cls_w, const float* __restrict__ cls_b,
                  const float* __restrict__ cf_w1, const float* __restrict__ cf_b1,
                  const float* __restrict__ cf_w2, const float* __restrict__ cf_b2,
                  const float* __restrict__ aux, float* __restrict__ out)
{
  int b = blockIdx.x, t = threadIdx.x, wid = t>>6, lane = t&63;
  __shared__ __align__(16) float pld[512];
  __shared__ __align__(16) float p2[512];
  __shared__ float red[4];
  float ds = 0.f;
  for(int s=t; s<1024; s+=256) ds += mask[b*1024 + s];
  ds = wred_sum(ds);
  if (lane==0) red[wid] = ds;
  __syncthreads();
  float denom = fmaxf(red[0]+red[1]+red[2]+red[3], 1e-9f);
  pld[t]     = pooled[b*512 + t]/denom;
  pld[t+256] = pooled[b*512 + t + 256]/denom;
  __syncthreads();
#pragma unroll
  for(int jj=0;jj<2;jj++){
    int j = t + jj*256;
    const float4* wr = (const float4*)(pool_w + (long)j*512);
    float acc = 0.f;
    for(int i=0;i<128;i++){
      float4 w4 = wr[i]; float4 x4 = ((const float4*)pld)[i];
      acc += w4.x*x4.x + w4.y*x4.y + w4.z*x4.z + w4.w*x4.w;
    }
    p2[j] = tanhf(acc + pool_b[j]);
  }
  __syncthreads();
  if (t < 4){
    const float4* wr = (const float4*)(cls_w + (long)t*512);
    float acc = 0.f;
    for(int i=0;i<128;i++){
      float4 w4 = wr[i]; float4 x4 = ((const float4*)p2)[i];
      acc += w4.x*x4.x + w4.y*x4.y + w4.z*x4.z + w4.w*x4.w;
    }
    out[b*4 + t] = acc + cls_b[t];
  }
  // confidence head: 256 hidden units = 256 threads
  {
    const float4* wr = (const float4*)(cf_w1 + (long)t*512);
    float acc = 0.f;
    for(int i=0;i<128;i++){
      float4 w4 = wr[i]; float4 x4 = ((const float4*)p2)[i];
      acc += w4.x*x4.x + w4.y*x4.y + w4.z*x4.z + w4.w*x4.w;
    }
    acc = fmaxf(acc + cf_b1[t], 0.f) * cf_w2[t];
    acc = wred_sum(acc);
    __syncthreads();
    if (lane==0) red[wid] = acc;
    __syncthreads();
    if (t == 0){
      float sum = red[0]+red[1]+red[2]+red[3];
      out[17 + b] = 1.f/(1.f + expf(-(sum + cf_b2[0])));
    }
  }
  if (b == 0 && t == 0) out[16] = aux[0]*0.25f;
}

// ---------------------------------------------------------------------------
extern "C" void kernel_launch(void* const* d_in, const int* in_sizes, int n_in,
                              void* d_out, int out_size, void* d_ws, size_t ws_size,
                              hipStream_t stream)
{
  (void)in_sizes; (void)n_in; (void)out_size;
  const float* emb    = (const float*)d_in[0];
  const float* mask   = (const float*)d_in[1];
  const float* in_w   = (const float*)d_in[2];
  const float* in_b   = (const float*)d_in[3];
  const float* out_w  = (const float*)d_in[4];
  const float* out_b  = (const float*)d_in[5];
  const float* ln1_w  = (const float*)d_in[6];
  const float* ln1_b  = (const float*)d_in[7];
  const float* ln2_w  = (const float*)d_in[8];
  const float* ln2_b  = (const float*)d_in[9];
  const float* gate_w = (const float*)d_in[10];
  const float* e_w1   = (const float*)d_in[11];
  const float* e_b1   = (const float*)d_in[12];
  const float* e_w2   = (const float*)d_in[13];
  const float* e_b2   = (const float*)d_in[14];
  const float* mln_w  = (const float*)d_in[15];
  const float* mln_b  = (const float*)d_in[16];
  const float* fln_w  = (const float*)d_in[17];
  const float* fln_b  = (const float*)d_in[18];
  const float* pool_w = (const float*)d_in[19];
  const float* pool_b = (const float*)d_in[20];
  const float* cls_w  = (const float*)d_in[21];
  const float* cls_b  = (const float*)d_in[22];
  const float* cf_w1  = (const float*)d_in[23];
  const float* cf_b1  = (const float*)d_in[24];
  const float* cf_w2  = (const float*)d_in[25];
  const float* cf_b2  = (const float*)d_in[26];
  float* out = (float*)d_out;
  char* ws = (char*)d_ws;

  const size_t MiB = 1024*1024;
  if (ws_size < 257*MiB) return;   // insufficient scratch: fail visibly

  // Workspace layout (regions reused across phases; see lifetimes)
  float* x        = (float*)(ws + 0*MiB);     // 8 MiB, persistent
  float* hbuf     = (float*)(ws + 8*MiB);     // 8 MiB: ln1 out -> ln2 out
  float* qkv      = (float*)(ws + 16*MiB);    // 24 MiB (attention) / eout (MoE)
  float* eout     = (float*)(ws + 16*MiB);
  unsigned short* Sb = (unsigned short*)(ws + 40*MiB);  // 64 MiB scores (attn) / mid (MoE)
  float* mid      = (float*)(ws + 40*MiB);
  float* Vt       = (float*)(ws + 104*MiB);   // 8 MiB
  float* ctx_tmp  = (float*)(ws + 112*MiB);   // 8 MiB (attn) / moe_out (MoE)
  float* moe_out  = (float*)(ws + 112*MiB);
  float* ctx      = (float*)(ws + 120*MiB);   // 8 MiB
  unsigned short* w1t = (unsigned short*)(ws + 128*MiB); // 64 MiB bf16 [l,e,i,d]
  unsigned short* w2t = (unsigned short*)(ws + 192*MiB); // 64 MiB bf16 [l,e,d,i]
  char* misc = ws + 256*MiB;
  int*   counts  = (int*)(misc + 0);
  int*   cursors = (int*)(misc + 32);
  int*   offs    = (int*)(misc + 64);
  float* aux     = (float*)(misc + 96);
  float* pooled  = (float*)(misc + 128);
  int*   tok_e   = (int*)(misc + 8320);
  float* tok_w   = (float*)(misc + 41088);
  int*   rowtok  = (int*)(misc + 73856);
  float* roww    = (float*)(misc + 106624);
  int*   rowof   = (int*)(misc + 139392);

  hipMemcpyAsync(x, emb, (size_t)T_*D_*4, hipMemcpyDeviceToDevice, stream);
  hipMemsetAsync(aux, 0, 4, stream);
  hipMemsetAsync(pooled, 0, 2048*4, stream);
  // Pre-transpose expert weights to NT bf16 (B rows over K)
  transpose_cast_k<<<dim3(I_/64, D_/64, L_*E_), 256, 0, stream>>>(e_w1, w1t, D_, I_);
  transpose_cast_k<<<dim3(D_/64, I_/64, L_*E_), 256, 0, stream>>>(e_w2, w2t, I_, D_);

  for (int l=0; l<L_; l++){
    const float* inwl  = in_w  + (size_t)l*3*D_*D_;
    const float* inbl  = in_b  + (size_t)l*3*D_;
    const float* outwl = out_w + (size_t)l*D_*D_;
    const float* outbl = out_b + (size_t)l*D_;
    const float* gwl   = gate_w + (size_t)l*E_*D_;
    const float* eb1l  = e_b1 + (size_t)l*E_*I_;
    const float* eb2l  = e_b2 + (size_t)l*E_*D_;
    const unsigned short* w1tl = w1t + (size_t)l*E_*I_*D_;
    const unsigned short* w2tl = w2t + (size_t)l*E_*D_*I_;

    // h = LN1(x)
    ln_k<<<T_, 128, 0, stream>>>(x, nullptr, ln1_w + (size_t)l*D_, ln1_b + (size_t)l*D_, hbuf);
    // qkv = h @ in_w^T + in_b
    gemm_k<128,false,false,false,false,false,0,false><<<dim3(32,12,1), 256, 0, stream>>>(
      hbuf, inwl, qkv, inbl, nullptr, T_, 3*D_, D_, D_, D_, 3*D_,
      1, 0,0,0,0,0,0, 1.f, nullptr, nullptr, nullptr, 0, 0);
    // S = (Q K^T)/8, bf16 out, batched over (b,h)
    gemm_k<128,false,false,false,false,true,0,false><<<dim3(8,8,32), 256, 0, stream>>>(
      qkv, (const void*)(qkv + 512), Sb, nullptr, nullptr, S_, S_, DH_, 1536, 1536, 1024,
      8, (long)S_*1536, 64, (long)S_*1536, 64, (long)8*S_*S_, (long)S_*S_, 0.125f,
      nullptr, nullptr, nullptr, 0, 0);
    softmax_k<<<B_*H_*S_, 256, 0, stream>>>(Sb);
    vt_k<<<dim3(16,32), 256, 0, stream>>>(qkv, Vt);
    // ctx_tmp = P V   (A=bf16 P, B=fp32 Vt)
    gemm_k<64,true,false,false,false,false,0,false><<<dim3(8,1,32), 256, 0, stream>>>(
      Sb, Vt, ctx_tmp, nullptr, nullptr, S_, DH_, S_, 1024, 1024, 64,
      8, (long)8*S_*S_, (long)S_*S_, (long)8*DH_*S_, (long)DH_*S_, (long)8*S_*DH_, (long)S_*DH_, 1.f,
      nullptr, nullptr, nullptr, 0, 0);
    permute_k<<<2048, 256, 0, stream>>>(ctx_tmp, ctx);
    // x = x + ctx @ out_w^T + out_b
    gemm_k<128,false,false,false,false,false,0,true><<<dim3(32,4,1), 256, 0, stream>>>(
      ctx, outwl, x, outbl, x, T_, D_, D_, D_, D_, D_,
      1, 0,0,0,0,0,0, 1.f, nullptr, nullptr, nullptr, 0, 0);
    // h2 = LN2(x)
    ln_k<<<T_, 128, 0, stream>>>(x, nullptr, ln2_w + (size_t)l*D_, ln2_b + (size_t)l*D_, hbuf);
    // routing + compaction
    hipMemsetAsync(counts, 0, 64, stream);
    route_k<<<T_/4, 256, 0, stream>>>(hbuf, gwl, tok_e, tok_w, counts);
    offsets_k<<<1, 1, 0, stream>>>(counts, offs, cursors, aux);
    scatter_k<<<32, 256, 0, stream>>>(tok_e, tok_w, offs, cursors, rowtok, roww, rowof);
    // FFN1: mid = gelu(gather(h2) @ w1^T + b1), grouped per expert
    gemm_k<128,false,true,true,true,false,1,false><<<dim3(64,16,8), 256, 0, stream>>>(
      hbuf, w1tl, mid, eb1l, nullptr, 2*T_, I_, D_, D_, D_, I_,
      1, 0,0,0,0,0,0, 1.f, offs, counts, rowtok, (long)I_*D_, I_);
    // FFN2: eout = mid @ w2^T + b2
    gemm_k<128,false,true,true,false,false,0,false><<<dim3(64,4,8), 256, 0, stream>>>(
      mid, w2tl, eout, eb2l, nullptr, 2*T_, D_, I_, I_, I_, D_,
      1, 0,0,0,0,0,0, 1.f, offs, counts, nullptr, (long)D_*I_, D_);
    combine_k<<<2048, 256, 0, stream>>>(eout, rowof, roww, mask, moe_out);
    // x = LN(h2 + moe_out)
    ln_k<<<T_, 128, 0, stream>>>(moe_out, hbuf, mln_w + (size_t)l*D_, mln_b + (size_t)l*D_, x);
  }
  // head
  ln_k<<<T_, 128, 0, stream>>>(x, nullptr, fln_w, fln_b, hbuf);
  pool_k<<<64, 256, 0, stream>>>(hbuf, mask, pooled);
  head_final_k<<<4, 256, 0, stream>>>(pooled, mask, pool_w, pool_b, cls_w, cls_b,
                                      cf_w1, cf_b1, cf_w2, cf_b2, aux, out);
}

// Round 2
// 2809.765 us; speedup vs baseline: 1.2043x; 1.2043x over previous
//
#include <hip/hip_runtime.h>
#include <math.h>

// Problem constants
#define B_ 4
#define S_ 1024
#define D_ 512
#define H_ 8
#define DH_ 64
#define I_ 2048
#define E_ 8
#define L_ 4
#define T_ 4096   // B*S

using bf16x8 = __attribute__((ext_vector_type(8))) __bf16;
using f32x4  = __attribute__((ext_vector_type(4))) float;

typedef __attribute__((address_space(1))) const void gvoid;
typedef __attribute__((address_space(3))) void lvoid;
__device__ __forceinline__ void gl_lds16(const void* g, void* l){
  __builtin_amdgcn_global_load_lds((gvoid*)g, (lvoid*)l, 16, 0, 0);
}

__device__ __forceinline__ float wred_sum(float v){
#pragma unroll
  for(int m=32;m>0;m>>=1) v += __shfl_xor(v, m, 64);
  return v;
}
__device__ __forceinline__ float wred_max(float v){
#pragma unroll
  for(int m=32;m>0;m>>=1) v = fmaxf(v, __shfl_xor(v, m, 64));
  return v;
}
__device__ __forceinline__ unsigned short f2bf(float f){
  unsigned x = __float_as_uint(f);
  unsigned r = (x + 0x7FFFu + ((x>>16)&1u)) >> 16;
  return (unsigned short)r;
}
__device__ __forceinline__ float bf2f(unsigned short u){
  return __uint_as_float(((unsigned)u)<<16);
}
__device__ __forceinline__ unsigned pk2(float a, float b){
  return (unsigned)f2bf(a) | ((unsigned)f2bf(b)<<16);
}

// ---------------------------------------------------------------------------
// bf16 MFMA GEMM, NT: C[m,n] = sum_k A[m,k]*B[n,k]. BM=128, BN in {128,64}.
// m97 structure: BK=32, global_load_lds width-16 staging, 2 barriers/iter,
// ds_read_b128 fragments, v_mfma_f32_16x16x32_bf16.
// MOE: blockIdx.z = expert, compacted row segment, optional row gather.
// ---------------------------------------------------------------------------
template<int BN, bool MOE, bool GATHER, bool OUT_BF16, int ACT, bool ADD_IN>
__global__ __launch_bounds__(256)
void gemm2_k(const unsigned short* __restrict__ A, const unsigned short* __restrict__ Bv,
             void* Cp, const float* __restrict__ bias, const float* addin,
             int M, int N, int K, int lda, int ldb, int ldc,
             int hdiv, long sAb, long sAh, long sBb, long sBh, long sCb, long sCh,
             float scale,
             const int* __restrict__ moff, const int* __restrict__ mcnt,
             const int* __restrict__ rowtok, long sBe, int biasStride)
{
  constexpr int BM = 128, BK = 32;
  constexpr int WN = BN/2, FM = 4, FN = BN/64;   // FN: 2 (BN=128) or 1 (BN=64) pairs? no:
  // FN = BN/2/16 per wave: BN=128 -> 4, BN=64 -> 2
  constexpr int FNN = WN/16;
  __shared__ unsigned short As[BM*BK];
  __shared__ unsigned short Bs[BN*BK];

  const int tid = threadIdx.x, wid = tid>>6, lane = tid&63;
  const int wy = wid>>1, wx = wid&1, ln16 = lane&15, q8 = (lane>>4)*8;
  const int m0 = blockIdx.x*BM, n0 = blockIdx.y*BN;

  float* Cf = nullptr; unsigned short* Ch = nullptr;
  const float* biasp = bias;
  const unsigned short* Bp = Bv;
  int seg = 0, cnt = M;

  if constexpr (MOE){
    int e = blockIdx.z;
    seg = moff[e]; cnt = mcnt[e];
    if (m0 >= cnt) return;
    Bp = Bv + (long)e*sBe;
    if constexpr (OUT_BF16) Ch = (unsigned short*)Cp; else Cf = (float*)Cp;
    if (biasp) biasp += (long)e*biasStride;
  } else {
    int z = blockIdx.z, zb = z/hdiv, zh = z%hdiv;
    A  += (long)zb*sAb + (long)zh*sAh;
    Bp += (long)zb*sBb + (long)zh*sBh;
    long coff = (long)zb*sCb + (long)zh*sCh;
    if constexpr (OUT_BF16) Ch = (unsigned short*)Cp + coff; else Cf = ((float*)Cp) + coff;
    if constexpr (ADD_IN) addin += coff;
  }

  // staging geometry: wave w chunk rows w*16 + lane/4, col (lane&3)*8
  const int arow0 = wid*16 + (lane>>2);
  const int colb  = (lane&3)*8;
  long ga0, ga1, gb0, gb1 = 0;
  {
    int r0 = m0 + arow0, r1 = r0 + 64;
    if constexpr (MOE){
      r0 = min(r0, cnt-1); r1 = min(r1, cnt-1);
      long gr0 = GATHER ? (long)rowtok[seg+r0] : (long)(seg+r0);
      long gr1 = GATHER ? (long)rowtok[seg+r1] : (long)(seg+r1);
      ga0 = gr0*lda + colb; ga1 = gr1*lda + colb;
    } else {
      ga0 = (long)min(r0, M-1)*lda + colb;
      ga1 = (long)min(r1, M-1)*lda + colb;
    }
    int b0 = min(n0 + arow0, N-1);
    gb0 = (long)b0*ldb + colb;
    if constexpr (BN == 128){
      int b1 = min(n0 + arow0 + 64, N-1);
      gb1 = (long)b1*ldb + colb;
    }
  }
  unsigned short* lA0 = As + wid*512;
  unsigned short* lA1 = As + 2048 + wid*512;
  unsigned short* lB0 = Bs + wid*512;
  unsigned short* lB1 = Bs + 2048 + wid*512;

  f32x4 acc[FM][FNN];
#pragma unroll
  for(int i=0;i<FM;i++)
#pragma unroll
    for(int j=0;j<FNN;j++){ f32x4 z = {0.f,0.f,0.f,0.f}; acc[i][j] = z; }

  for (int k0 = 0; k0 < K; k0 += BK){
    __syncthreads();
    gl_lds16(A + ga0 + k0, lA0);
    gl_lds16(A + ga1 + k0, lA1);
    gl_lds16(Bp + gb0 + k0, lB0);
    if constexpr (BN == 128) gl_lds16(Bp + gb1 + k0, lB1);
    __syncthreads();
    bf16x8 fa[FM], fb[FNN];
#pragma unroll
    for(int i=0;i<FM;i++) fa[i] = *(const bf16x8*)&As[(wy*64 + i*16 + ln16)*BK + q8];
#pragma unroll
    for(int j=0;j<FNN;j++) fb[j] = *(const bf16x8*)&Bs[(wx*WN + j*16 + ln16)*BK + q8];
#pragma unroll
    for(int i=0;i<FM;i++)
#pragma unroll
      for(int j=0;j<FNN;j++)
        acc[i][j] = __builtin_amdgcn_mfma_f32_16x16x32_bf16(fa[i], fb[j], acc[i][j], 0, 0, 0);
  }

  // epilogue: C[m = quad*4+r][n = lane&15]
#pragma unroll
  for(int i=0;i<FM;i++){
    int mbase = m0 + wy*64 + i*16 + (lane>>4)*4;
#pragma unroll
    for(int j=0;j<FNN;j++){
      int n = n0 + wx*WN + j*16 + ln16;
      float bv = biasp ? biasp[n] : 0.f;
      f32x4 v = acc[i][j];
#pragma unroll
      for(int r=0;r<4;r++){
        int m = mbase + r;
        if (m < cnt){
          float x = v[r]*scale + bv;
          if constexpr (ACT == 1) x = 0.5f*x*(1.f + erff(x*0.70710678118654752f));
          long ci = (long)(MOE ? seg + m : m)*ldc + n;
          if constexpr (ADD_IN) x += addin[ci];
          if constexpr (OUT_BF16) Ch[ci] = f2bf(x);
          else Cf[ci] = x;
        }
      }
    }
  }
}

// ---------------------------------------------------------------------------
// LayerNorm over D=512; in fp32, optional bf16 residual, out fp32 or bf16
// ---------------------------------------------------------------------------
template<bool RES_BF16, bool OUT_BF16>
__global__ __launch_bounds__(128)
void ln_k(const float* __restrict__ in, const void* __restrict__ resid,
          const float* __restrict__ w, const float* __restrict__ bb, void* __restrict__ outp)
{
  int row = blockIdx.x, t = threadIdx.x, wid = t>>6, lane = t&63;
  float4 v = ((const float4*)(in + (long)row*512))[t];
  if (resid){
    if constexpr (RES_BF16){
      uint2 r2 = ((const uint2*)resid)[(long)row*128 + t];
      const unsigned short* h = (const unsigned short*)&r2;
      v.x += bf2f(h[0]); v.y += bf2f(h[1]); v.z += bf2f(h[2]); v.w += bf2f(h[3]);
    } else {
      float4 r = ((const float4*)resid)[(long)row*128 + t];
      v.x += r.x; v.y += r.y; v.z += r.z; v.w += r.w;
    }
  }
  float s = v.x+v.y+v.z+v.w;
  float q = v.x*v.x+v.y*v.y+v.z*v.z+v.w*v.w;
  s = wred_sum(s); q = wred_sum(q);
  __shared__ float rs[2], rq[2];
  if (lane==0){ rs[wid]=s; rq[wid]=q; }
  __syncthreads();
  s = rs[0]+rs[1]; q = rq[0]+rq[1];
  float mean = s*(1.f/512.f);
  float var  = q*(1.f/512.f) - mean*mean;
  float inv  = rsqrtf(var + 1e-5f);
  float4 wv = ((const float4*)w)[t], bv = ((const float4*)bb)[t];
  float4 o;
  o.x = (v.x-mean)*inv*wv.x + bv.x;
  o.y = (v.y-mean)*inv*wv.y + bv.y;
  o.z = (v.z-mean)*inv*wv.z + bv.z;
  o.w = (v.w-mean)*inv*wv.w + bv.w;
  if constexpr (OUT_BF16)
    ((uint2*)outp)[(long)row*128 + t] = make_uint2(pk2(o.x,o.y), pk2(o.z,o.w));
  else
    ((float4*)outp)[(long)row*128 + t] = o;
}

// Row softmax over 1024, bf16 in-place, one wave per row (no barriers)
__global__ __launch_bounds__(256)
void softmax_k(unsigned short* __restrict__ S)
{
  int wid = threadIdx.x>>6, lane = threadIdx.x&63;
  long row = (long)blockIdx.x*4 + wid;
  unsigned short* p = S + row*1024 + lane*16;
  uint4 a = *(const uint4*)p, b = *(const uint4*)(p+8);
  const unsigned short* ha = (const unsigned short*)&a;
  const unsigned short* hb = (const unsigned short*)&b;
  float x[16];
#pragma unroll
  for(int i=0;i<8;i++){ x[i] = bf2f(ha[i]); x[8+i] = bf2f(hb[i]); }
  float mx = x[0];
#pragma unroll
  for(int i=1;i<16;i++) mx = fmaxf(mx, x[i]);
  mx = wred_max(mx);
  float s = 0.f;
#pragma unroll
  for(int i=0;i<16;i++){ x[i] = __expf(x[i]-mx); s += x[i]; }
  s = wred_sum(s);
  float inv = 1.f/s;
  uint4 o0, o1;
  unsigned* u0 = (unsigned*)&o0; unsigned* u1 = (unsigned*)&o1;
#pragma unroll
  for(int i=0;i<4;i++){ u0[i] = pk2(x[2*i]*inv, x[2*i+1]*inv); u1[i] = pk2(x[8+2*i]*inv, x[9+2*i]*inv); }
  *(uint4*)p = o0; *(uint4*)(p+8) = o1;
}

// Build Vt[bh][d][k] bf16 from qkv's V slice (bf16), LDS transpose
__global__ __launch_bounds__(256)
void vt_k(const unsigned short* __restrict__ qkvb, unsigned short* __restrict__ Vt)
{
  __shared__ unsigned short tile[64][80];
  int z = blockIdx.y, b = z>>3, h = z&7;
  int k0 = blockIdx.x*64;
  int t = threadIdx.x;
  int kk = t>>2, dd = (t&3)*16;
  const unsigned short* p = qkvb + ((long)(b*1024 + k0 + kk))*1536 + 1024 + h*64 + dd;
  uint4 u0 = *(const uint4*)p, u1 = *(const uint4*)(p+8);
  *(uint4*)&tile[kk][dd] = u0;
  *(uint4*)&tile[kk][dd+8] = u1;
  __syncthreads();
  int dd2 = t>>2, kk2 = (t&3)*16;
  uint4 o0, o1;
  unsigned short* s0 = (unsigned short*)&o0;
  unsigned short* s1 = (unsigned short*)&o1;
#pragma unroll
  for(int j=0;j<8;j++){ s0[j] = tile[kk2+j][dd2]; s1[j] = tile[kk2+8+j][dd2]; }
  unsigned short* o = Vt + (long)z*65536 + (long)dd2*1024 + k0 + kk2;
  *(uint4*)o = o0; *(uint4*)(o+8) = o1;
}

// bf16 (B,H,S,dh) -> (B,S,H*dh)
__global__ __launch_bounds__(256)
void permute_k(const unsigned short* __restrict__ in, unsigned short* __restrict__ outp)
{
  int gid = blockIdx.x*256 + threadIdx.x;
  long o8 = (long)gid*8;
  int b = (int)(o8 >> 19);
  int r = (int)(o8 & 524287);
  int s = r >> 9;
  int c = r & 511;
  int h = c >> 6;
  int dd = c & 63;
  long iidx = (((long)b*8 + h)*1024 + s)*64 + dd;
  *(uint4*)(outp + o8) = *(const uint4*)(in + iidx);
}

// fp32 (R,C) -> bf16 (C,R), batched over blockIdx.z
__global__ __launch_bounds__(256)
void transpose_cast_k(const float* __restrict__ in, unsigned short* __restrict__ outp, int R, int C)
{
  __shared__ float tile[64][65];
  long zoff = (long)blockIdx.z * R * C;
  in += zoff; outp += zoff;
  int c0 = blockIdx.x*64, r0 = blockIdx.y*64;
  int t = threadIdx.x;
  int rr = t>>2, cc = (t&3)*16;
  const float* p = in + (long)(r0+rr)*C + c0 + cc;
  float4 v0=*(const float4*)p, v1=*(const float4*)(p+4), v2=*(const float4*)(p+8), v3=*(const float4*)(p+12);
  tile[rr][cc+0]=v0.x; tile[rr][cc+1]=v0.y; tile[rr][cc+2]=v0.z; tile[rr][cc+3]=v0.w;
  tile[rr][cc+4]=v1.x; tile[rr][cc+5]=v1.y; tile[rr][cc+6]=v1.z; tile[rr][cc+7]=v1.w;
  tile[rr][cc+8]=v2.x; tile[rr][cc+9]=v2.y; tile[rr][cc+10]=v2.z; tile[rr][cc+11]=v2.w;
  tile[rr][cc+12]=v3.x; tile[rr][cc+13]=v3.y; tile[rr][cc+14]=v3.z; tile[rr][cc+15]=v3.w;
  __syncthreads();
  int cc2 = t>>2, rr2 = (t&3)*16;
  unsigned tmp[8];
#pragma unroll
  for(int jj=0;jj<8;jj++)
    tmp[jj] = pk2(tile[rr2+2*jj][cc2], tile[rr2+2*jj+1][cc2]);
  uint4* dst = (uint4*)(outp + (long)(c0+cc2)*R + r0 + rr2);
  dst[0] = make_uint4(tmp[0],tmp[1],tmp[2],tmp[3]);
  dst[1] = make_uint4(tmp[4],tmp[5],tmp[6],tmp[7]);
}

// fp32 -> bf16 elementwise (8 per thread)
__global__ __launch_bounds__(256)
void cast_bf16_k(const float* __restrict__ in, unsigned short* __restrict__ outp, int n8)
{
  int i = blockIdx.x*256 + threadIdx.x;
  if (i >= n8) return;
  const float4* p = (const float4*)(in + (long)i*8);
  float4 a = p[0], b = p[1];
  *(uint4*)(outp + (long)i*8) = make_uint4(pk2(a.x,a.y), pk2(a.z,a.w), pk2(b.x,b.y), pk2(b.z,b.w));
}

// Gate: softmax over E=8 logits, top-2, normalized weights; one wave/token (bf16 h)
__global__ __launch_bounds__(256)
void route_k(const unsigned short* __restrict__ flat, const float* __restrict__ gw,
             int* __restrict__ tok_e, float* __restrict__ tok_w, int* __restrict__ counts)
{
  int wid = threadIdx.x>>6, lane = threadIdx.x&63;
  int t = blockIdx.x*4 + wid;
  uint4 xu = *(const uint4*)(flat + (long)t*512 + lane*8);
  const unsigned short* xh = (const unsigned short*)&xu;
  float xv[8];
#pragma unroll
  for(int i=0;i<8;i++) xv[i] = bf2f(xh[i]);
  float lg[8];
#pragma unroll
  for(int e=0;e<8;e++){
    const float4* gr = (const float4*)(gw + e*512 + lane*8);
    float4 g0 = gr[0], g1 = gr[1];
    float d = xv[0]*g0.x + xv[1]*g0.y + xv[2]*g0.z + xv[3]*g0.w
            + xv[4]*g1.x + xv[5]*g1.y + xv[6]*g1.z + xv[7]*g1.w;
    lg[e] = wred_sum(d);
  }
  if (lane == 0){
    float mx = lg[0];
#pragma unroll
    for(int e=1;e<8;e++) mx = fmaxf(mx, lg[e]);
    float p[8];
#pragma unroll
    for(int e=0;e<8;e++) p[e] = expf(lg[e]-mx);
    int e0 = 0; float p0 = p[0];
#pragma unroll
    for(int e=1;e<8;e++) if (p[e] > p0){ p0 = p[e]; e0 = e; }
    int e1 = -1; float p1 = -1.f;
#pragma unroll
    for(int e=0;e<8;e++) if (e != e0 && p[e] > p1){ p1 = p[e]; e1 = e; }
    float inv = 1.f/(p0+p1);
    tok_e[2*t] = e0; tok_e[2*t+1] = e1;
    tok_w[2*t] = p0*inv; tok_w[2*t+1] = p1*inv;
    atomicAdd(&counts[e0], 1); atomicAdd(&counts[e1], 1);
  }
}

__global__ void offsets_k(const int* __restrict__ counts, int* __restrict__ offs,
                          int* __restrict__ cursors, float* __restrict__ aux)
{
  if (threadIdx.x == 0 && blockIdx.x == 0){
    int o = 0; float a = 0.f;
    for(int e=0;e<8;e++){
      offs[e] = o; o += counts[e]; cursors[e] = 0;
      float u = (float)counts[e]*(1.f/4096.f) - 0.125f;
      a += u*u;
    }
    *aux += a*(1.f/8.f);
  }
}

__global__ __launch_bounds__(256)
void scatter_k(const int* __restrict__ tok_e, const float* __restrict__ tok_w,
               const int* __restrict__ offs, int* __restrict__ cursors,
               int* __restrict__ rowtok, float* __restrict__ roww, int* __restrict__ rowof)
{
  int i = blockIdx.x*256 + threadIdx.x;   // 8192 (token,k) pairs
  int e = tok_e[i]; float w = tok_w[i];
  int pos = offs[e] + atomicAdd(&cursors[e], 1);
  rowtok[pos] = i>>1;
  roww[pos] = w;
  rowof[i] = pos;
}

// moe_out[t,:] = (w0*eout[r0,:] + w1*eout[r1,:]) * mask[t]
__global__ __launch_bounds__(256)
void combine_k(const float* __restrict__ eout, const int* __restrict__ rowof,
               const float* __restrict__ roww, const float* __restrict__ mask, float* __restrict__ moe)
{
  int gid = blockIdx.x*256 + threadIdx.x;
  long o4 = (long)gid*4;
  int tok = (int)(o4 >> 9);
  int d = (int)(o4 & 511);
  int r0 = rowof[2*tok], r1 = rowof[2*tok+1];
  float w0 = roww[r0], w1 = roww[r1];
  float mk = mask[tok];
  float4 a = *(const float4*)(eout + (long)r0*512 + d);
  float4 b = *(const float4*)(eout + (long)r1*512 + d);
  float4 o;
  o.x = (a.x*w0 + b.x*w1)*mk;
  o.y = (a.y*w0 + b.y*w1)*mk;
  o.z = (a.z*w0 + b.z*w1)*mk;
  o.w = (a.w*w0 + b.w*w1)*mk;
  *(float4*)(moe + o4) = o;
}

// masked-sum partial pooling
__global__ __launch_bounds__(256)
void pool_k(const float* __restrict__ h, const float* __restrict__ mask, float* __restrict__ pooled)
{
  int z = blockIdx.x, b = z>>4, sc = z&15, t = threadIdx.x;
  float a0 = 0.f, a1 = 0.f;
  for(int ss=0;ss<64;ss++){
    int s = sc*64 + ss;
    float mk = mask[b*1024 + s];
    const float* r = h + ((long)b*1024 + s)*512;
    a0 += r[t]*mk; a1 += r[t+256]*mk;
  }
  atomicAdd(&pooled[b*512 + t], a0);
  atomicAdd(&pooled[b*512 + t + 256], a1);
}

__global__ __launch_bounds__(256)
void head_final_k(const float* __restrict__ pooled, const float* __restrict__ mask,
                  const float* __restrict__ pool_w, const float* __restrict__ pool_b,
                  const float* __restrict__ cls_w, const float* __restrict__ cls_b,
                  const float* __restrict__ cf_w1, const float* __restrict__ cf_b1,
                  const float* __restrict__ cf_w2, const float* __restrict__ cf_b2,
                  const float* __restrict__ aux, float* __restrict__ out)
{
  int b = blockIdx.x, t = threadIdx.x, wid = t>>6, lane = t&63;
  __shared__ __align__(16) float pld[512];
  __shared__ __align__(16) float p2[512];
  __shared__ float red[4];
  float ds = 0.f;
  for(int s=t; s<1024; s+=256) ds += mask[b*1024 + s];
  ds = wred_sum(ds);
  if (lane==0) red[wid] = ds;
  __syncthreads();
  float denom = fmaxf(red[0]+red[1]+red[2]+red[3], 1e-9f);
  pld[t]     = pooled[b*512 + t]/denom;
  pld[t+256] = pooled[b*512 + t + 256]/denom;
  __syncthreads();
#pragma unroll
  for(int jj=0;jj<2;jj++){
    int j = t + jj*256;
    const float4* wr = (const float4*)(pool_w + (long)j*512);
    float acc = 0.f;
    for(int i=0;i<128;i++){
      float4 w4 = wr[i]; float4 x4 = ((const float4*)pld)[i];
      acc += w4.x*x4.x + w4.y*x4.y + w4.z*x4.z + w4.w*x4.w;
    }
    p2[j] = tanhf(acc + pool_b[j]);
  }
  __syncthreads();
  if (t < 4){
    const float4* wr = (const float4*)(cls_w + (long)t*512);
    float acc = 0.f;
    for(int i=0;i<128;i++){
      float4 w4 = wr[i]; float4 x4 = ((const float4*)p2)[i];
      acc += w4.x*x4.x + w4.y*x4.y + w4.z*x4.z + w4.w*x4.w;
    }
    out[b*4 + t] = acc + cls_b[t];
  }
  {
    const float4* wr = (const float4*)(cf_w1 + (long)t*512);
    float acc = 0.f;
    for(int i=0;i<128;i++){
      float4 w4 = wr[i]; float4 x4 = ((const float4*)p2)[i];
      acc += w4.x*x4.x + w4.y*x4.y + w4.z*x4.z + w4.w*x4.w;
    }
    acc = fmaxf(acc + cf_b1[t], 0.f) * cf_w2[t];
    acc = wred_sum(acc);
    __syncthreads();
    if (lane==0) red[wid] = acc;
    __syncthreads();
    if (t == 0){
      float sum = red[0]+red[1]+red[2]+red[3];
      out[17 + b] = 1.f/(1.f + expf(-(sum + cf_b2[0])));
    }
  }
  if (b == 0 && t == 0) out[16] = aux[0]*0.25f;
}

// ---------------------------------------------------------------------------
extern "C" void kernel_launch(void* const* d_in, const int* in_sizes, int n_in,
                              void* d_out, int out_size, void* d_ws, size_t ws_size,
                              hipStream_t stream)
{
  (void)in_sizes; (void)n_in; (void)out_size;
  const float* emb    = (const float*)d_in[0];
  const float* mask   = (const float*)d_in[1];
  const float* in_w   = (const float*)d_in[2];
  const float* in_b   = (const float*)d_in[3];
  const float* out_w  = (const float*)d_in[4];
  const float* out_b  = (const float*)d_in[5];
  const float* ln1_w  = (const float*)d_in[6];
  const float* ln1_b  = (const float*)d_in[7];
  const float* ln2_w  = (const float*)d_in[8];
  const float* ln2_b  = (const float*)d_in[9];
  const float* gate_w = (const float*)d_in[10];
  const float* e_w1   = (const float*)d_in[11];
  const float* e_b1   = (const float*)d_in[12];
  const float* e_w2   = (const float*)d_in[13];
  const float* e_b2   = (const float*)d_in[14];
  const float* mln_w  = (const float*)d_in[15];
  const float* mln_b  = (const float*)d_in[16];
  const float* fln_w  = (const float*)d_in[17];
  const float* fln_b  = (const float*)d_in[18];
  const float* pool_w = (const float*)d_in[19];
  const float* pool_b = (const float*)d_in[20];
  const float* cls_w  = (const float*)d_in[21];
  const float* cls_b  = (const float*)d_in[22];
  const float* cf_w1  = (const float*)d_in[23];
  const float* cf_b1  = (const float*)d_in[24];
  const float* cf_w2  = (const float*)d_in[25];
  const float* cf_b2  = (const float*)d_in[26];
  float* out = (float*)d_out;
  char* ws = (char*)d_ws;

  const size_t MiB = 1024*1024;
  if (ws_size < 257*MiB) return;

  // Workspace layout
  float*          x       = (float*)(ws + 0*MiB);            // 8 MiB fp32, persistent
  unsigned short* hb      = (unsigned short*)(ws + 8*MiB);   // 4 MiB bf16 LN out
  unsigned short* qkvb    = (unsigned short*)(ws + 12*MiB);  // 12 MiB bf16
  unsigned short* ctx     = (unsigned short*)(ws + 24*MiB);  // 4 MiB bf16
  unsigned short* Vt      = (unsigned short*)(ws + 28*MiB);  // 4 MiB bf16
  unsigned short* Sb      = (unsigned short*)(ws + 32*MiB);  // 64 MiB bf16 scores
  unsigned short* mid     = (unsigned short*)(ws + 32*MiB);  //   (reuse) 32 MiB bf16
  unsigned short* ctx_tmp = (unsigned short*)(ws + 96*MiB);  // 4 MiB bf16 (attn)
  float*          moe_out = (float*)(ws + 96*MiB);           //   (reuse) 8 MiB fp32
  float*          eout    = (float*)(ws + 104*MiB);          // 16 MiB fp32
  float*          fout    = (float*)(ws + 104*MiB);          //   (reuse) 8 MiB fp32 head
  unsigned short* w1t     = (unsigned short*)(ws + 120*MiB); // 64 MiB bf16
  unsigned short* w2t     = (unsigned short*)(ws + 184*MiB); // 64 MiB bf16
  unsigned short* inwb    = (unsigned short*)(ws + 248*MiB); // 6 MiB bf16
  unsigned short* outwb   = (unsigned short*)(ws + 254*MiB); // 2 MiB bf16
  char* misc = ws + 256*MiB;
  int*   counts  = (int*)(misc + 0);
  int*   cursors = (int*)(misc + 64);
  int*   offs    = (int*)(misc + 128);
  float* aux     = (float*)(misc + 192);
  float* pooled  = (float*)(misc + 256);
  int*   tok_e   = (int*)(misc + 16384);
  float* tok_w   = (float*)(misc + 49152);
  int*   rowtok  = (int*)(misc + 81920);
  float* roww    = (float*)(misc + 114688);
  int*   rowof   = (int*)(misc + 147456);

  hipMemcpyAsync(x, emb, (size_t)T_*D_*4, hipMemcpyDeviceToDevice, stream);
  hipMemsetAsync(aux, 0, 4, stream);
  hipMemsetAsync(pooled, 0, 2048*4, stream);
  // weight prep: bf16 casts / transposes
  cast_bf16_k<<<1536, 256, 0, stream>>>(in_w, inwb, L_*3*D_*D_/8);
  cast_bf16_k<<<512, 256, 0, stream>>>(out_w, outwb, L_*D_*D_/8);
  transpose_cast_k<<<dim3(I_/64, D_/64, L_*E_), 256, 0, stream>>>(e_w1, w1t, D_, I_);
  transpose_cast_k<<<dim3(D_/64, I_/64, L_*E_), 256, 0, stream>>>(e_w2, w2t, I_, D_);

  for (int l=0; l<L_; l++){
    const float* inbl  = in_b  + (size_t)l*3*D_;
    const float* outbl = out_b + (size_t)l*D_;
    const float* gwl   = gate_w + (size_t)l*E_*D_;
    const float* eb1l  = e_b1 + (size_t)l*E_*I_;
    const float* eb2l  = e_b2 + (size_t)l*E_*D_;
    const unsigned short* inwbl = inwb + (size_t)l*3*D_*D_;
    const unsigned short* outwbl = outwb + (size_t)l*D_*D_;
    const unsigned short* w1tl = w1t + (size_t)l*E_*I_*D_;
    const unsigned short* w2tl = w2t + (size_t)l*E_*D_*I_;

    // h = LN1(x) -> bf16
    ln_k<false,true><<<T_, 128, 0, stream>>>(x, nullptr, ln1_w + (size_t)l*D_, ln1_b + (size_t)l*D_, hb);
    // qkv = h @ in_w^T + in_b  -> bf16
    gemm2_k<128,false,false,true,0,false><<<dim3(32,12,1), 256, 0, stream>>>(
      hb, inwbl, qkvb, inbl, nullptr, T_, 3*D_, D_, D_, D_, 3*D_,
      1, 0,0,0,0,0,0, 1.f, nullptr, nullptr, nullptr, 0, 0);
    // S = (Q K^T)/8, bf16, batched over (b,h)
    gemm2_k<128,false,false,true,0,false><<<dim3(8,8,32), 256, 0, stream>>>(
      qkvb, qkvb + 512, Sb, nullptr, nullptr, S_, S_, DH_, 1536, 1536, 1024,
      8, (long)S_*1536, 64, (long)S_*1536, 64, (long)8*S_*S_, (long)S_*S_, 0.125f,
      nullptr, nullptr, nullptr, 0, 0);
    softmax_k<<<B_*H_*S_/4, 256, 0, stream>>>(Sb);
    vt_k<<<dim3(16,32), 256, 0, stream>>>(qkvb, Vt);
    // ctx_tmp = P V  (bf16 out)
    gemm2_k<64,false,false,true,0,false><<<dim3(8,1,32), 256, 0, stream>>>(
      Sb, Vt, ctx_tmp, nullptr, nullptr, S_, DH_, S_, 1024, 1024, 64,
      8, (long)8*S_*S_, (long)S_*S_, (long)8*DH_*S_, (long)DH_*S_, (long)8*S_*DH_, (long)S_*DH_, 1.f,
      nullptr, nullptr, nullptr, 0, 0);
    permute_k<<<1024, 256, 0, stream>>>(ctx_tmp, ctx);
    // x = x + ctx @ out_w^T + out_b  (fp32)
    gemm2_k<128,false,false,false,0,true><<<dim3(32,4,1), 256, 0, stream>>>(
      ctx, outwbl, x, outbl, x, T_, D_, D_, D_, D_, D_,
      1, 0,0,0,0,0,0, 1.f, nullptr, nullptr, nullptr, 0, 0);
    // h2 = LN2(x) -> bf16
    ln_k<false,true><<<T_, 128, 0, stream>>>(x, nullptr, ln2_w + (size_t)l*D_, ln2_b + (size_t)l*D_, hb);
    // routing + compaction
    hipMemsetAsync(counts, 0, 64, stream);
    route_k<<<T_/4, 256, 0, stream>>>(hb, gwl, tok_e, tok_w, counts);
    offsets_k<<<1, 1, 0, stream>>>(counts, offs, cursors, aux);
    scatter_k<<<32, 256, 0, stream>>>(tok_e, tok_w, offs, cursors, rowtok, roww, rowof);
    // FFN1: mid = gelu(gather(h2) @ w1^T + b1) -> bf16
    gemm2_k<128,true,true,true,1,false><<<dim3(64,16,8), 256, 0, stream>>>(
      hb, w1tl, mid, eb1l, nullptr, 2*T_, I_, D_, D_, D_, I_,
      1, 0,0,0,0,0,0, 1.f, offs, counts, rowtok, (long)I_*D_, I_);
    // FFN2: eout = mid @ w2^T + b2 -> fp32
    gemm2_k<64,true,false,false,0,false><<<dim3(64,8,8), 256, 0, stream>>>(
      mid, w2tl, eout, eb2l, nullptr, 2*T_, D_, I_, I_, I_, D_,
      1, 0,0,0,0,0,0, 1.f, offs, counts, nullptr, (long)D_*I_, D_);
    combine_k<<<2048, 256, 0, stream>>>(eout, rowof, roww, mask, moe_out);
    // x = LN(h2 + moe_out)  (fp32)
    ln_k<true,false><<<T_, 128, 0, stream>>>(moe_out, hb, mln_w + (size_t)l*D_, mln_b + (size_t)l*D_, x);
  }
  // head
  ln_k<false,false><<<T_, 128, 0, stream>>>(x, nullptr, fln_w, fln_b, fout);
  pool_k<<<64, 256, 0, stream>>>(fout, mask, pooled);
  head_final_k<<<4, 256, 0, stream>>>(pooled, mask, pool_w, pool_b, cls_w, cls_b,
                                      cf_w1, cf_b1, cf_w2, cf_b2, aux, out);
}

// Round 3
// 2733.308 us; speedup vs baseline: 1.2380x; 1.0280x over previous
//
#include <hip/hip_runtime.h>
#include <math.h>

// Problem constants
#define B_ 4
#define S_ 1024
#define D_ 512
#define H_ 8
#define DH_ 64
#define I_ 2048
#define E_ 8
#define L_ 4
#define T_ 4096   // B*S

using bf16x8 = __attribute__((ext_vector_type(8))) __bf16;
using f32x4  = __attribute__((ext_vector_type(4))) float;

__device__ __forceinline__ float wred_sum(float v){
#pragma unroll
  for(int m=32;m>0;m>>=1) v += __shfl_xor(v, m, 64);
  return v;
}
__device__ __forceinline__ float wred_max(float v){
#pragma unroll
  for(int m=32;m>0;m>>=1) v = fmaxf(v, __shfl_xor(v, m, 64));
  return v;
}
__device__ __forceinline__ unsigned short f2bf(float f){
  unsigned x = __float_as_uint(f);
  unsigned r = (x + 0x7FFFu + ((x>>16)&1u)) >> 16;
  return (unsigned short)r;
}
__device__ __forceinline__ float bf2f(unsigned short u){
  return __uint_as_float(((unsigned)u)<<16);
}
__device__ __forceinline__ unsigned pk2(float a, float b){
  return (unsigned)f2bf(a) | ((unsigned)f2bf(b)<<16);
}

// ---------------------------------------------------------------------------
// bf16 MFMA GEMM, NT: C[m,n] = sum_k A[m,k]*B[n,k]. BM=128, BN in {128,64}.
// Pipelined K-loop: register prefetch (global->VGPR for tile k+1) + LDS
// double buffer, ONE barrier per iter. Loads stay in flight across the
// barrier (only lgkmcnt drains); ds_write of k+1 waits fine-grained vmcnt.
// MOE: blockIdx.z = expert, compacted row segment, optional row gather.
// ---------------------------------------------------------------------------
template<int BN, bool MOE, bool GATHER, bool OUT_BF16, int ACT, bool ADD_IN>
__global__ __launch_bounds__(256)
void gemm3_k(const unsigned short* __restrict__ A, const unsigned short* __restrict__ Bv,
             void* Cp, const float* __restrict__ bias, const float* addin,
             int M, int N, int K, int lda, int ldb, int ldc,
             int hdiv, long sAb, long sAh, long sBb, long sBh, long sCb, long sCh,
             float scale,
             const int* __restrict__ moff, const int* __restrict__ mcnt,
             const int* __restrict__ rowtok, long sBe, int biasStride)
{
  constexpr int BM = 128, BK = 32;
  constexpr int WN = BN/2, FM = 4, FNN = WN/16;
  constexpr int ASZ = BM*BK;   // shorts per A buffer
  constexpr int BSZ = BN*BK;   // shorts per B buffer
  __shared__ unsigned short sh[2*ASZ + 2*BSZ];
  unsigned short* As = sh;
  unsigned short* Bs = sh + 2*ASZ;

  const int tid = threadIdx.x, wid = tid>>6, lane = tid&63;
  const int wy = wid>>1, wx = wid&1, ln16 = lane&15, q8 = (lane>>4)*8;
  const int m0 = blockIdx.x*BM, n0 = blockIdx.y*BN;

  float* Cf = nullptr; unsigned short* Ch = nullptr;
  const float* biasp = bias;
  const unsigned short* Bp = Bv;
  int seg = 0, cnt = M;

  if constexpr (MOE){
    int e = blockIdx.z;
    seg = moff[e]; cnt = mcnt[e];
    if (m0 >= cnt) return;
    Bp = Bv + (long)e*sBe;
    if constexpr (OUT_BF16) Ch = (unsigned short*)Cp; else Cf = (float*)Cp;
    if (biasp) biasp += (long)e*biasStride;
  } else {
    int z = blockIdx.z, zb = z/hdiv, zh = z%hdiv;
    A  += (long)zb*sAb + (long)zh*sAh;
    Bp += (long)zb*sBb + (long)zh*sBh;
    long coff = (long)zb*sCb + (long)zh*sCh;
    if constexpr (OUT_BF16) Ch = (unsigned short*)Cp + coff; else Cf = ((float*)Cp) + coff;
    if constexpr (ADD_IN) addin += coff;
  }

  // staging geometry: wave w rows w*16 + lane/4 (+64 for chunk1), col (lane&3)*8
  const int arow0 = wid*16 + (lane>>2);
  const int colb  = (lane&3)*8;
  long ga0, ga1, gb0, gb1 = 0;
  {
    int r0 = m0 + arow0, r1 = r0 + 64;
    if constexpr (MOE){
      r0 = min(r0, cnt-1); r1 = min(r1, cnt-1);
      long gr0 = GATHER ? (long)rowtok[seg+r0] : (long)(seg+r0);
      long gr1 = GATHER ? (long)rowtok[seg+r1] : (long)(seg+r1);
      ga0 = gr0*lda + colb; ga1 = gr1*lda + colb;
    } else {
      ga0 = (long)min(r0, M-1)*lda + colb;
      ga1 = (long)min(r1, M-1)*lda + colb;
    }
    int b0 = min(n0 + arow0, N-1);
    gb0 = (long)b0*ldb + colb;
    if constexpr (BN == 128){
      int b1 = min(n0 + arow0 + 64, N-1);
      gb1 = (long)b1*ldb + colb;
    }
  }
  const int st = wid*512 + lane*8;  // per-wave LDS staging slot (shorts)

  f32x4 acc[FM][FNN];
#pragma unroll
  for(int i=0;i<FM;i++)
#pragma unroll
    for(int j=0;j<FNN;j++){ f32x4 z = {0.f,0.f,0.f,0.f}; acc[i][j] = z; }

  const int niter = K/BK;
  // ---- prologue: stage tile 0 ----
  uint4 ra0 = *(const uint4*)(A + ga0);
  uint4 ra1 = *(const uint4*)(A + ga1);
  uint4 rb0 = *(const uint4*)(Bp + gb0);
  uint4 rb1 = make_uint4(0,0,0,0);
  if constexpr (BN == 128) rb1 = *(const uint4*)(Bp + gb1);
  *(uint4*)&As[st] = ra0;
  *(uint4*)&As[2048 + st] = ra1;
  *(uint4*)&Bs[st] = rb0;
  if constexpr (BN == 128) *(uint4*)&Bs[2048 + st] = rb1;
  __syncthreads();

  int ab = 0, bb = 0;
  for (int it = 0; it < niter-1; ++it){
    const int kn = (it+1)*BK;
    // issue loads for tile kn (in flight through the MFMA phase)
    ra0 = *(const uint4*)(A + ga0 + kn);
    ra1 = *(const uint4*)(A + ga1 + kn);
    rb0 = *(const uint4*)(Bp + gb0 + kn);
    if constexpr (BN == 128) rb1 = *(const uint4*)(Bp + gb1 + kn);
    // MFMA on current buffer
    bf16x8 fa[FM], fb[FNN];
#pragma unroll
    for(int i=0;i<FM;i++) fa[i] = *(const bf16x8*)&As[ab + (wy*64 + i*16 + ln16)*BK + q8];
#pragma unroll
    for(int j=0;j<FNN;j++) fb[j] = *(const bf16x8*)&Bs[bb + (wx*WN + j*16 + ln16)*BK + q8];
#pragma unroll
    for(int i=0;i<FM;i++)
#pragma unroll
      for(int j=0;j<FNN;j++)
        acc[i][j] = __builtin_amdgcn_mfma_f32_16x16x32_bf16(fa[i], fb[j], acc[i][j], 0, 0, 0);
    // stage tile kn into the other buffer
    const int ab2 = ab ^ ASZ, bb2 = bb ^ BSZ;
    *(uint4*)&As[ab2 + st] = ra0;
    *(uint4*)&As[ab2 + 2048 + st] = ra1;
    *(uint4*)&Bs[bb2 + st] = rb0;
    if constexpr (BN == 128) *(uint4*)&Bs[bb2 + 2048 + st] = rb1;
    __syncthreads();
    ab = ab2; bb = bb2;
  }
  // ---- final tile MFMA ----
  {
    bf16x8 fa[FM], fb[FNN];
#pragma unroll
    for(int i=0;i<FM;i++) fa[i] = *(const bf16x8*)&As[ab + (wy*64 + i*16 + ln16)*BK + q8];
#pragma unroll
    for(int j=0;j<FNN;j++) fb[j] = *(const bf16x8*)&Bs[bb + (wx*WN + j*16 + ln16)*BK + q8];
#pragma unroll
    for(int i=0;i<FM;i++)
#pragma unroll
      for(int j=0;j<FNN;j++)
        acc[i][j] = __builtin_amdgcn_mfma_f32_16x16x32_bf16(fa[i], fb[j], acc[i][j], 0, 0, 0);
  }

  // epilogue: C[m = quad*4+r][n = lane&15]
#pragma unroll
  for(int i=0;i<FM;i++){
    int mbase = m0 + wy*64 + i*16 + (lane>>4)*4;
#pragma unroll
    for(int j=0;j<FNN;j++){
      int n = n0 + wx*WN + j*16 + ln16;
      float bv = biasp ? biasp[n] : 0.f;
      f32x4 v = acc[i][j];
#pragma unroll
      for(int r=0;r<4;r++){
        int m = mbase + r;
        if (m < cnt){
          float x = v[r]*scale + bv;
          if constexpr (ACT == 1) x = 0.5f*x*(1.f + erff(x*0.70710678118654752f));
          long ci = (long)(MOE ? seg + m : m)*ldc + n;
          if constexpr (ADD_IN) x += addin[ci];
          if constexpr (OUT_BF16) Ch[ci] = f2bf(x);
          else Cf[ci] = x;
        }
      }
    }
  }
}

// ---------------------------------------------------------------------------
// LayerNorm over D=512; in fp32, optional bf16 residual, out fp32 or bf16
// ---------------------------------------------------------------------------
template<bool RES_BF16, bool OUT_BF16>
__global__ __launch_bounds__(128)
void ln_k(const float* __restrict__ in, const void* __restrict__ resid,
          const float* __restrict__ w, const float* __restrict__ bb, void* __restrict__ outp)
{
  int row = blockIdx.x, t = threadIdx.x, wid = t>>6, lane = t&63;
  float4 v = ((const float4*)(in + (long)row*512))[t];
  if (resid){
    if constexpr (RES_BF16){
      uint2 r2 = ((const uint2*)resid)[(long)row*128 + t];
      const unsigned short* h = (const unsigned short*)&r2;
      v.x += bf2f(h[0]); v.y += bf2f(h[1]); v.z += bf2f(h[2]); v.w += bf2f(h[3]);
    } else {
      float4 r = ((const float4*)resid)[(long)row*128 + t];
      v.x += r.x; v.y += r.y; v.z += r.z; v.w += r.w;
    }
  }
  float s = v.x+v.y+v.z+v.w;
  float q = v.x*v.x+v.y*v.y+v.z*v.z+v.w*v.w;
  s = wred_sum(s); q = wred_sum(q);
  __shared__ float rs[2], rq[2];
  if (lane==0){ rs[wid]=s; rq[wid]=q; }
  __syncthreads();
  s = rs[0]+rs[1]; q = rq[0]+rq[1];
  float mean = s*(1.f/512.f);
  float var  = q*(1.f/512.f) - mean*mean;
  float inv  = rsqrtf(var + 1e-5f);
  float4 wv = ((const float4*)w)[t], bv = ((const float4*)bb)[t];
  float4 o;
  o.x = (v.x-mean)*inv*wv.x + bv.x;
  o.y = (v.y-mean)*inv*wv.y + bv.y;
  o.z = (v.z-mean)*inv*wv.z + bv.z;
  o.w = (v.w-mean)*inv*wv.w + bv.w;
  if constexpr (OUT_BF16)
    ((uint2*)outp)[(long)row*128 + t] = make_uint2(pk2(o.x,o.y), pk2(o.z,o.w));
  else
    ((float4*)outp)[(long)row*128 + t] = o;
}

// Fused MoE combine + LayerNorm: x = LN(h2 + (w0*eout[r0]+w1*eout[r1])*mask)
__global__ __launch_bounds__(128)
void ln_moe_k(const float* __restrict__ eout, const int* __restrict__ rowof,
              const float* __restrict__ roww, const float* __restrict__ mask,
              const unsigned short* __restrict__ h2,
              const float* __restrict__ w, const float* __restrict__ bb,
              float* __restrict__ outp)
{
  int tok = blockIdx.x, t = threadIdx.x, wid = t>>6, lane = t&63;
  int r0 = rowof[2*tok], r1 = rowof[2*tok+1];
  float w0 = roww[r0], w1 = roww[r1], mk = mask[tok];
  float4 a = ((const float4*)(eout + (long)r0*512))[t];
  float4 b = ((const float4*)(eout + (long)r1*512))[t];
  uint2 r2 = ((const uint2*)h2)[(long)tok*128 + t];
  const unsigned short* hh = (const unsigned short*)&r2;
  float4 v;
  v.x = bf2f(hh[0]) + (a.x*w0 + b.x*w1)*mk;
  v.y = bf2f(hh[1]) + (a.y*w0 + b.y*w1)*mk;
  v.z = bf2f(hh[2]) + (a.z*w0 + b.z*w1)*mk;
  v.w = bf2f(hh[3]) + (a.w*w0 + b.w*w1)*mk;
  float s = v.x+v.y+v.z+v.w;
  float q = v.x*v.x+v.y*v.y+v.z*v.z+v.w*v.w;
  s = wred_sum(s); q = wred_sum(q);
  __shared__ float rs[2], rq[2];
  if (lane==0){ rs[wid]=s; rq[wid]=q; }
  __syncthreads();
  s = rs[0]+rs[1]; q = rq[0]+rq[1];
  float mean = s*(1.f/512.f);
  float var  = q*(1.f/512.f) - mean*mean;
  float inv  = rsqrtf(var + 1e-5f);
  float4 wv = ((const float4*)w)[t], bv = ((const float4*)bb)[t];
  float4 o;
  o.x = (v.x-mean)*inv*wv.x + bv.x;
  o.y = (v.y-mean)*inv*wv.y + bv.y;
  o.z = (v.z-mean)*inv*wv.z + bv.z;
  o.w = (v.w-mean)*inv*wv.w + bv.w;
  ((float4*)(outp + (long)tok*512))[t] = o;
}

// Row softmax over 1024, bf16 in-place, one wave per row
__global__ __launch_bounds__(256)
void softmax_k(unsigned short* __restrict__ S)
{
  int wid = threadIdx.x>>6, lane = threadIdx.x&63;
  long row = (long)blockIdx.x*4 + wid;
  unsigned short* p = S + row*1024 + lane*16;
  uint4 a = *(const uint4*)p, b = *(const uint4*)(p+8);
  const unsigned short* ha = (const unsigned short*)&a;
  const unsigned short* hb = (const unsigned short*)&b;
  float x[16];
#pragma unroll
  for(int i=0;i<8;i++){ x[i] = bf2f(ha[i]); x[8+i] = bf2f(hb[i]); }
  float mx = x[0];
#pragma unroll
  for(int i=1;i<16;i++) mx = fmaxf(mx, x[i]);
  mx = wred_max(mx);
  float s = 0.f;
#pragma unroll
  for(int i=0;i<16;i++){ x[i] = __expf(x[i]-mx); s += x[i]; }
  s = wred_sum(s);
  float inv = 1.f/s;
  uint4 o0, o1;
  unsigned* u0 = (unsigned*)&o0; unsigned* u1 = (unsigned*)&o1;
#pragma unroll
  for(int i=0;i<4;i++){ u0[i] = pk2(x[2*i]*inv, x[2*i+1]*inv); u1[i] = pk2(x[8+2*i]*inv, x[9+2*i]*inv); }
  *(uint4*)p = o0; *(uint4*)(p+8) = o1;
}

// Build Vt[bh][d][k] bf16 from qkv's V slice (bf16), LDS transpose
__global__ __launch_bounds__(256)
void vt_k(const unsigned short* __restrict__ qkvb, unsigned short* __restrict__ Vt)
{
  __shared__ unsigned short tile[64][80];
  int z = blockIdx.y, b = z>>3, h = z&7;
  int k0 = blockIdx.x*64;
  int t = threadIdx.x;
  int kk = t>>2, dd = (t&3)*16;
  const unsigned short* p = qkvb + ((long)(b*1024 + k0 + kk))*1536 + 1024 + h*64 + dd;
  uint4 u0 = *(const uint4*)p, u1 = *(const uint4*)(p+8);
  *(uint4*)&tile[kk][dd] = u0;
  *(uint4*)&tile[kk][dd+8] = u1;
  __syncthreads();
  int dd2 = t>>2, kk2 = (t&3)*16;
  uint4 o0, o1;
  unsigned short* s0 = (unsigned short*)&o0;
  unsigned short* s1 = (unsigned short*)&o1;
#pragma unroll
  for(int j=0;j<8;j++){ s0[j] = tile[kk2+j][dd2]; s1[j] = tile[kk2+8+j][dd2]; }
  unsigned short* o = Vt + (long)z*65536 + (long)dd2*1024 + k0 + kk2;
  *(uint4*)o = o0; *(uint4*)(o+8) = o1;
}

// bf16 (B,H,S,dh) -> (B,S,H*dh)
__global__ __launch_bounds__(256)
void permute_k(const unsigned short* __restrict__ in, unsigned short* __restrict__ outp)
{
  int gid = blockIdx.x*256 + threadIdx.x;
  long o8 = (long)gid*8;
  int b = (int)(o8 >> 19);
  int r = (int)(o8 & 524287);
  int s = r >> 9;
  int c = r & 511;
  int h = c >> 6;
  int dd = c & 63;
  long iidx = (((long)b*8 + h)*1024 + s)*64 + dd;
  *(uint4*)(outp + o8) = *(const uint4*)(in + iidx);
}

// fp32 (R,C) -> bf16 (C,R), batched over blockIdx.z
__global__ __launch_bounds__(256)
void transpose_cast_k(const float* __restrict__ in, unsigned short* __restrict__ outp, int R, int C)
{
  __shared__ float tile[64][65];
  long zoff = (long)blockIdx.z * R * C;
  in += zoff; outp += zoff;
  int c0 = blockIdx.x*64, r0 = blockIdx.y*64;
  int t = threadIdx.x;
  int rr = t>>2, cc = (t&3)*16;
  const float* p = in + (long)(r0+rr)*C + c0 + cc;
  float4 v0=*(const float4*)p, v1=*(const float4*)(p+4), v2=*(const float4*)(p+8), v3=*(const float4*)(p+12);
  tile[rr][cc+0]=v0.x; tile[rr][cc+1]=v0.y; tile[rr][cc+2]=v0.z; tile[rr][cc+3]=v0.w;
  tile[rr][cc+4]=v1.x; tile[rr][cc+5]=v1.y; tile[rr][cc+6]=v1.z; tile[rr][cc+7]=v1.w;
  tile[rr][cc+8]=v2.x; tile[rr][cc+9]=v2.y; tile[rr][cc+10]=v2.z; tile[rr][cc+11]=v2.w;
  tile[rr][cc+12]=v3.x; tile[rr][cc+13]=v3.y; tile[rr][cc+14]=v3.z; tile[rr][cc+15]=v3.w;
  __syncthreads();
  int cc2 = t>>2, rr2 = (t&3)*16;
  unsigned tmp[8];
#pragma unroll
  for(int jj=0;jj<8;jj++)
    tmp[jj] = pk2(tile[rr2+2*jj][cc2], tile[rr2+2*jj+1][cc2]);
  uint4* dst = (uint4*)(outp + (long)(c0+cc2)*R + r0 + rr2);
  dst[0] = make_uint4(tmp[0],tmp[1],tmp[2],tmp[3]);
  dst[1] = make_uint4(tmp[4],tmp[5],tmp[6],tmp[7]);
}

// fp32 -> bf16 elementwise (8 per thread)
__global__ __launch_bounds__(256)
void cast_bf16_k(const float* __restrict__ in, unsigned short* __restrict__ outp, int n8)
{
  int i = blockIdx.x*256 + threadIdx.x;
  if (i >= n8) return;
  const float4* p = (const float4*)(in + (long)i*8);
  float4 a = p[0], b = p[1];
  *(uint4*)(outp + (long)i*8) = make_uint4(pk2(a.x,a.y), pk2(a.z,a.w), pk2(b.x,b.y), pk2(b.z,b.w));
}

// Gate: softmax over E=8 logits, top-2, normalized weights; one wave/token (bf16 h)
__global__ __launch_bounds__(256)
void route_k(const unsigned short* __restrict__ flat, const float* __restrict__ gw,
             int* __restrict__ tok_e, float* __restrict__ tok_w, int* __restrict__ counts)
{
  int wid = threadIdx.x>>6, lane = threadIdx.x&63;
  int t = blockIdx.x*4 + wid;
  uint4 xu = *(const uint4*)(flat + (long)t*512 + lane*8);
  const unsigned short* xh = (const unsigned short*)&xu;
  float xv[8];
#pragma unroll
  for(int i=0;i<8;i++) xv[i] = bf2f(xh[i]);
  float lg[8];
#pragma unroll
  for(int e=0;e<8;e++){
    const float4* gr = (const float4*)(gw + e*512 + lane*8);
    float4 g0 = gr[0], g1 = gr[1];
    float d = xv[0]*g0.x + xv[1]*g0.y + xv[2]*g0.z + xv[3]*g0.w
            + xv[4]*g1.x + xv[5]*g1.y + xv[6]*g1.z + xv[7]*g1.w;
    lg[e] = wred_sum(d);
  }
  if (lane == 0){
    float mx = lg[0];
#pragma unroll
    for(int e=1;e<8;e++) mx = fmaxf(mx, lg[e]);
    float p[8];
#pragma unroll
    for(int e=0;e<8;e++) p[e] = expf(lg[e]-mx);
    int e0 = 0; float p0 = p[0];
#pragma unroll
    for(int e=1;e<8;e++) if (p[e] > p0){ p0 = p[e]; e0 = e; }
    int e1 = -1; float p1 = -1.f;
#pragma unroll
    for(int e=0;e<8;e++) if (e != e0 && p[e] > p1){ p1 = p[e]; e1 = e; }
    float inv = 1.f/(p0+p1);
    tok_e[2*t] = e0; tok_e[2*t+1] = e1;
    tok_w[2*t] = p0*inv; tok_w[2*t+1] = p1*inv;
    atomicAdd(&counts[e0], 1); atomicAdd(&counts[e1], 1);
  }
}

__global__ void offsets_k(const int* __restrict__ counts, int* __restrict__ offs,
                          int* __restrict__ cursors, float* __restrict__ aux)
{
  if (threadIdx.x == 0 && blockIdx.x == 0){
    int o = 0; float a = 0.f;
    for(int e=0;e<8;e++){
      offs[e] = o; o += counts[e]; cursors[e] = 0;
      float u = (float)counts[e]*(1.f/4096.f) - 0.125f;
      a += u*u;
    }
    *aux += a*(1.f/8.f);
  }
}

__global__ __launch_bounds__(256)
void scatter_k(const int* __restrict__ tok_e, const float* __restrict__ tok_w,
               const int* __restrict__ offs, int* __restrict__ cursors,
               int* __restrict__ rowtok, float* __restrict__ roww, int* __restrict__ rowof)
{
  int i = blockIdx.x*256 + threadIdx.x;   // 8192 (token,k) pairs
  int e = tok_e[i]; float w = tok_w[i];
  int pos = offs[e] + atomicAdd(&cursors[e], 1);
  rowtok[pos] = i>>1;
  roww[pos] = w;
  rowof[i] = pos;
}

// masked-sum partial pooling
__global__ __launch_bounds__(256)
void pool_k(const float* __restrict__ h, const float* __restrict__ mask, float* __restrict__ pooled)
{
  int z = blockIdx.x, b = z>>4, sc = z&15, t = threadIdx.x;
  float a0 = 0.f, a1 = 0.f;
  for(int ss=0;ss<64;ss++){
    int s = sc*64 + ss;
    float mk = mask[b*1024 + s];
    const float* r = h + ((long)b*1024 + s)*512;
    a0 += r[t]*mk; a1 += r[t+256]*mk;
  }
  atomicAdd(&pooled[b*512 + t], a0);
  atomicAdd(&pooled[b*512 + t + 256], a1);
}

__global__ __launch_bounds__(256)
void head_final_k(const float* __restrict__ pooled, const float* __restrict__ mask,
                  const float* __restrict__ pool_w, const float* __restrict__ pool_b,
                  const float* __restrict__ cls_w, const float* __restrict__ cls_b,
                  const float* __restrict__ cf_w1, const float* __restrict__ cf_b1,
                  const float* __restrict__ cf_w2, const float* __restrict__ cf_b2,
                  const float* __restrict__ aux, float* __restrict__ out)
{
  int b = blockIdx.x, t = threadIdx.x, wid = t>>6, lane = t&63;
  __shared__ __align__(16) float pld[512];
  __shared__ __align__(16) float p2[512];
  __shared__ float red[4];
  float ds = 0.f;
  for(int s=t; s<1024; s+=256) ds += mask[b*1024 + s];
  ds = wred_sum(ds);
  if (lane==0) red[wid] = ds;
  __syncthreads();
  float denom = fmaxf(red[0]+red[1]+red[2]+red[3], 1e-9f);
  pld[t]     = pooled[b*512 + t]/denom;
  pld[t+256] = pooled[b*512 + t + 256]/denom;
  __syncthreads();
#pragma unroll
  for(int jj=0;jj<2;jj++){
    int j = t + jj*256;
    const float4* wr = (const float4*)(pool_w + (long)j*512);
    float acc = 0.f;
    for(int i=0;i<128;i++){
      float4 w4 = wr[i]; float4 x4 = ((const float4*)pld)[i];
      acc += w4.x*x4.x + w4.y*x4.y + w4.z*x4.z + w4.w*x4.w;
    }
    p2[j] = tanhf(acc + pool_b[j]);
  }
  __syncthreads();
  if (t < 4){
    const float4* wr = (const float4*)(cls_w + (long)t*512);
    float acc = 0.f;
    for(int i=0;i<128;i++){
      float4 w4 = wr[i]; float4 x4 = ((const float4*)p2)[i];
      acc += w4.x*x4.x + w4.y*x4.y + w4.z*x4.z + w4.w*x4.w;
    }
    out[b*4 + t] = acc + cls_b[t];
  }
  {
    const float4* wr = (const float4*)(cf_w1 + (long)t*512);
    float acc = 0.f;
    for(int i=0;i<128;i++){
      float4 w4 = wr[i]; float4 x4 = ((const float4*)p2)[i];
      acc += w4.x*x4.x + w4.y*x4.y + w4.z*x4.z + w4.w*x4.w;
    }
    acc = fmaxf(acc + cf_b1[t], 0.f) * cf_w2[t];
    acc = wred_sum(acc);
    __syncthreads();
    if (lane==0) red[wid] = acc;
    __syncthreads();
    if (t == 0){
      float sum = red[0]+red[1]+red[2]+red[3];
      out[17 + b] = 1.f/(1.f + expf(-(sum + cf_b2[0])));
    }
  }
  if (b == 0 && t == 0) out[16] = aux[0]*0.25f;
}

// ---------------------------------------------------------------------------
extern "C" void kernel_launch(void* const* d_in, const int* in_sizes, int n_in,
                              void* d_out, int out_size, void* d_ws, size_t ws_size,
                              hipStream_t stream)
{
  (void)in_sizes; (void)n_in; (void)out_size;
  const float* emb    = (const float*)d_in[0];
  const float* mask   = (const float*)d_in[1];
  const float* in_w   = (const float*)d_in[2];
  const float* in_b   = (const float*)d_in[3];
  const float* out_w  = (const float*)d_in[4];
  const float* out_b  = (const float*)d_in[5];
  const float* ln1_w  = (const float*)d_in[6];
  const float* ln1_b  = (const float*)d_in[7];
  const float* ln2_w  = (const float*)d_in[8];
  const float* ln2_b  = (const float*)d_in[9];
  const float* gate_w = (const float*)d_in[10];
  const float* e_w1   = (const float*)d_in[11];
  const float* e_b1   = (const float*)d_in[12];
  const float* e_w2   = (const float*)d_in[13];
  const float* e_b2   = (const float*)d_in[14];
  const float* mln_w  = (const float*)d_in[15];
  const float* mln_b  = (const float*)d_in[16];
  const float* fln_w  = (const float*)d_in[17];
  const float* fln_b  = (const float*)d_in[18];
  const float* pool_w = (const float*)d_in[19];
  const float* pool_b = (const float*)d_in[20];
  const float* cls_w  = (const float*)d_in[21];
  const float* cls_b  = (const float*)d_in[22];
  const float* cf_w1  = (const float*)d_in[23];
  const float* cf_b1  = (const float*)d_in[24];
  const float* cf_w2  = (const float*)d_in[25];
  const float* cf_b2  = (const float*)d_in[26];
  float* out = (float*)d_out;
  char* ws = (char*)d_ws;

  const size_t MiB = 1024*1024;
  if (ws_size < 257*MiB) return;

  // Workspace layout
  float*          x       = (float*)(ws + 0*MiB);            // 8 MiB fp32, persistent
  unsigned short* hb      = (unsigned short*)(ws + 8*MiB);   // 4 MiB bf16 LN out
  unsigned short* qkvb    = (unsigned short*)(ws + 12*MiB);  // 12 MiB bf16
  unsigned short* ctx     = (unsigned short*)(ws + 24*MiB);  // 4 MiB bf16
  unsigned short* Vt      = (unsigned short*)(ws + 28*MiB);  // 4 MiB bf16
  unsigned short* Sb      = (unsigned short*)(ws + 32*MiB);  // 64 MiB bf16 scores
  unsigned short* mid     = (unsigned short*)(ws + 32*MiB);  //   (reuse) 32 MiB bf16
  unsigned short* ctx_tmp = (unsigned short*)(ws + 96*MiB);  // 4 MiB bf16 (attn)
  float*          eout    = (float*)(ws + 104*MiB);          // 16 MiB fp32
  float*          fout    = (float*)(ws + 104*MiB);          //   (reuse) 8 MiB fp32 head
  unsigned short* w1t     = (unsigned short*)(ws + 120*MiB); // 64 MiB bf16
  unsigned short* w2t     = (unsigned short*)(ws + 184*MiB); // 64 MiB bf16
  unsigned short* inwb    = (unsigned short*)(ws + 248*MiB); // 6 MiB bf16
  unsigned short* outwb   = (unsigned short*)(ws + 254*MiB); // 2 MiB bf16
  char* misc = ws + 256*MiB;
  int*   counts  = (int*)(misc + 0);
  int*   cursors = (int*)(misc + 64);
  int*   offs    = (int*)(misc + 128);
  float* aux     = (float*)(misc + 192);
  float* pooled  = (float*)(misc + 256);
  int*   tok_e   = (int*)(misc + 16384);
  float* tok_w   = (float*)(misc + 49152);
  int*   rowtok  = (int*)(misc + 81920);
  float* roww    = (float*)(misc + 114688);
  int*   rowof   = (int*)(misc + 147456);

  hipMemcpyAsync(x, emb, (size_t)T_*D_*4, hipMemcpyDeviceToDevice, stream);
  hipMemsetAsync(aux, 0, 4, stream);
  hipMemsetAsync(pooled, 0, 2048*4, stream);
  // weight prep: bf16 casts / transposes
  cast_bf16_k<<<1536, 256, 0, stream>>>(in_w, inwb, L_*3*D_*D_/8);
  cast_bf16_k<<<512, 256, 0, stream>>>(out_w, outwb, L_*D_*D_/8);
  transpose_cast_k<<<dim3(I_/64, D_/64, L_*E_), 256, 0, stream>>>(e_w1, w1t, D_, I_);
  transpose_cast_k<<<dim3(D_/64, I_/64, L_*E_), 256, 0, stream>>>(e_w2, w2t, I_, D_);

  for (int l=0; l<L_; l++){
    const float* inbl  = in_b  + (size_t)l*3*D_;
    const float* outbl = out_b + (size_t)l*D_;
    const float* gwl   = gate_w + (size_t)l*E_*D_;
    const float* eb1l  = e_b1 + (size_t)l*E_*I_;
    const float* eb2l  = e_b2 + (size_t)l*E_*D_;
    const unsigned short* inwbl = inwb + (size_t)l*3*D_*D_;
    const unsigned short* outwbl = outwb + (size_t)l*D_*D_;
    const unsigned short* w1tl = w1t + (size_t)l*E_*I_*D_;
    const unsigned short* w2tl = w2t + (size_t)l*E_*D_*I_;

    // h = LN1(x) -> bf16
    ln_k<false,true><<<T_, 128, 0, stream>>>(x, nullptr, ln1_w + (size_t)l*D_, ln1_b + (size_t)l*D_, hb);
    // qkv = h @ in_w^T + in_b  -> bf16
    gemm3_k<128,false,false,true,0,false><<<dim3(32,12,1), 256, 0, stream>>>(
      hb, inwbl, qkvb, inbl, nullptr, T_, 3*D_, D_, D_, D_, 3*D_,
      1, 0,0,0,0,0,0, 1.f, nullptr, nullptr, nullptr, 0, 0);
    // S = (Q K^T)/8, bf16, batched over (b,h)
    gemm3_k<128,false,false,true,0,false><<<dim3(8,8,32), 256, 0, stream>>>(
      qkvb, qkvb + 512, Sb, nullptr, nullptr, S_, S_, DH_, 1536, 1536, 1024,
      8, (long)S_*1536, 64, (long)S_*1536, 64, (long)8*S_*S_, (long)S_*S_, 0.125f,
      nullptr, nullptr, nullptr, 0, 0);
    softmax_k<<<B_*H_*S_/4, 256, 0, stream>>>(Sb);
    vt_k<<<dim3(16,32), 256, 0, stream>>>(qkvb, Vt);
    // ctx_tmp = P V  (bf16 out)
    gemm3_k<64,false,false,true,0,false><<<dim3(8,1,32), 256, 0, stream>>>(
      Sb, Vt, ctx_tmp, nullptr, nullptr, S_, DH_, S_, 1024, 1024, 64,
      8, (long)8*S_*S_, (long)S_*S_, (long)8*DH_*S_, (long)DH_*S_, (long)8*S_*DH_, (long)S_*DH_, 1.f,
      nullptr, nullptr, nullptr, 0, 0);
    permute_k<<<1024, 256, 0, stream>>>(ctx_tmp, ctx);
    // x = x + ctx @ out_w^T + out_b  (fp32)
    gemm3_k<128,false,false,false,0,true><<<dim3(32,4,1), 256, 0, stream>>>(
      ctx, outwbl, x, outbl, x, T_, D_, D_, D_, D_, D_,
      1, 0,0,0,0,0,0, 1.f, nullptr, nullptr, nullptr, 0, 0);
    // h2 = LN2(x) -> bf16
    ln_k<false,true><<<T_, 128, 0, stream>>>(x, nullptr, ln2_w + (size_t)l*D_, ln2_b + (size_t)l*D_, hb);
    // routing + compaction
    hipMemsetAsync(counts, 0, 64, stream);
    route_k<<<T_/4, 256, 0, stream>>>(hb, gwl, tok_e, tok_w, counts);
    offsets_k<<<1, 1, 0, stream>>>(counts, offs, cursors, aux);
    scatter_k<<<32, 256, 0, stream>>>(tok_e, tok_w, offs, cursors, rowtok, roww, rowof);
    // FFN1: mid = gelu(gather(h2) @ w1^T + b1) -> bf16
    gemm3_k<128,true,true,true,1,false><<<dim3(64,16,8), 256, 0, stream>>>(
      hb, w1tl, mid, eb1l, nullptr, 2*T_, I_, D_, D_, D_, I_,
      1, 0,0,0,0,0,0, 1.f, offs, counts, rowtok, (long)I_*D_, I_);
    // FFN2: eout = mid @ w2^T + b2 -> fp32
    gemm3_k<64,true,false,false,0,false><<<dim3(64,8,8), 256, 0, stream>>>(
      mid, w2tl, eout, eb2l, nullptr, 2*T_, D_, I_, I_, I_, D_,
      1, 0,0,0,0,0,0, 1.f, offs, counts, nullptr, (long)D_*I_, D_);
    // x = LN(h2 + combine(eout))  (fused)
    ln_moe_k<<<T_, 128, 0, stream>>>(eout, rowof, roww, mask, hb,
                                     mln_w + (size_t)l*D_, mln_b + (size_t)l*D_, x);
  }
  // head
  ln_k<false,false><<<T_, 128, 0, stream>>>(x, nullptr, fln_w, fln_b, fout);
  pool_k<<<64, 256, 0, stream>>>(fout, mask, pooled);
  head_final_k<<<4, 256, 0, stream>>>(pooled, mask, pool_w, pool_b, cls_w, cls_b,
                                      cf_w1, cf_b1, cf_w2, cf_b2, aux, out);
}

// Round 4
// 2062.640 us; speedup vs baseline: 1.6405x; 1.3252x over previous
//
#include <hip/hip_runtime.h>
#include <math.h>

// Problem constants
#define B_ 4
#define S_ 1024
#define D_ 512
#define H_ 8
#define DH_ 64
#define I_ 2048
#define E_ 8
#define L_ 4
#define T_ 4096   // B*S

using bf16x8 = __attribute__((ext_vector_type(8))) __bf16;
using f32x4  = __attribute__((ext_vector_type(4))) float;

typedef __attribute__((address_space(1))) const void gvoid;
typedef __attribute__((address_space(3))) void lvoid;
__device__ __forceinline__ void gl_lds16(const void* g, void* l){
  __builtin_amdgcn_global_load_lds((gvoid*)g, (lvoid*)l, 16, 0, 0);
}

__device__ __forceinline__ float wred_sum(float v){
#pragma unroll
  for(int m=32;m>0;m>>=1) v += __shfl_xor(v, m, 64);
  return v;
}
__device__ __forceinline__ unsigned short f2bf(float f){
  unsigned x = __float_as_uint(f);
  unsigned r = (x + 0x7FFFu + ((x>>16)&1u)) >> 16;
  return (unsigned short)r;
}
__device__ __forceinline__ float bf2f(unsigned short u){
  return __uint_as_float(((unsigned)u)<<16);
}
__device__ __forceinline__ unsigned pk2(float a, float b){
  return (unsigned)f2bf(a) | ((unsigned)f2bf(b)<<16);
}

// ---------------------------------------------------------------------------
// bf16 MFMA GEMM (r2 structure: global_load_lds width-16, single buffer,
// 2 barriers/iter). NT: C[m,n] = sum_k A[m,k]*B[n,k]. BM=128, BN {128,64}.
// MOE: block table btab[bx] = (e<<8)|mblk, -1 = dead. Optional row gather.
// ---------------------------------------------------------------------------
template<int BN, bool MOE, bool GATHER, bool OUT_BF16, int ACT, bool ADD_IN>
__global__ __launch_bounds__(256)
void gemm2_k(const unsigned short* __restrict__ A, const unsigned short* __restrict__ Bv,
             void* Cp, const float* __restrict__ bias, const float* addin,
             int M, int N, int K, int lda, int ldb, int ldc,
             int hdiv, long sAb, long sAh, long sBb, long sBh, long sCb, long sCh,
             float scale,
             const int* __restrict__ moff, const int* __restrict__ mcnt,
             const int* __restrict__ rowtok, const int* __restrict__ btab,
             long sBe, int biasStride)
{
  constexpr int BM = 128, BK = 32;
  constexpr int WN = BN/2, FM = 4, FNN = WN/16;
  __shared__ unsigned short As[BM*BK];
  __shared__ unsigned short Bs[BN*BK];

  const int tid = threadIdx.x, wid = tid>>6, lane = tid&63;
  const int wy = wid>>1, wx = wid&1, ln16 = lane&15, q8 = (lane>>4)*8;
  int m0 = blockIdx.x*BM;
  const int n0 = blockIdx.y*BN;

  float* Cf = nullptr; unsigned short* Ch = nullptr;
  const float* biasp = bias;
  const unsigned short* Bp = Bv;
  int seg = 0, cnt = M;

  if constexpr (MOE){
    int tv = btab[blockIdx.x];
    if (tv < 0) return;
    int e = tv>>8;
    m0 = (tv&255)*BM;
    seg = moff[e]; cnt = mcnt[e];
    Bp = Bv + (long)e*sBe;
    if constexpr (OUT_BF16) Ch = (unsigned short*)Cp; else Cf = (float*)Cp;
    if (biasp) biasp += (long)e*biasStride;
  } else {
    int z = blockIdx.z, zb = z/hdiv, zh = z%hdiv;
    A  += (long)zb*sAb + (long)zh*sAh;
    Bp += (long)zb*sBb + (long)zh*sBh;
    long coff = (long)zb*sCb + (long)zh*sCh;
    if constexpr (OUT_BF16) Ch = (unsigned short*)Cp + coff; else Cf = ((float*)Cp) + coff;
    if constexpr (ADD_IN) addin += coff;
  }

  // staging geometry: wave w rows w*16 + lane/4 (+64 chunk1), col (lane&3)*8
  const int arow0 = wid*16 + (lane>>2);
  const int colb  = (lane&3)*8;
  long ga0, ga1, gb0, gb1 = 0;
  {
    int r0 = m0 + arow0, r1 = r0 + 64;
    if constexpr (MOE){
      r0 = min(r0, cnt-1); r1 = min(r1, cnt-1);
      long gr0 = GATHER ? (long)rowtok[seg+r0] : (long)(seg+r0);
      long gr1 = GATHER ? (long)rowtok[seg+r1] : (long)(seg+r1);
      ga0 = gr0*lda + colb; ga1 = gr1*lda + colb;
    } else {
      ga0 = (long)min(r0, M-1)*lda + colb;
      ga1 = (long)min(r1, M-1)*lda + colb;
    }
    int b0 = min(n0 + arow0, N-1);
    gb0 = (long)b0*ldb + colb;
    if constexpr (BN == 128){
      int b1 = min(n0 + arow0 + 64, N-1);
      gb1 = (long)b1*ldb + colb;
    }
  }
  unsigned short* lA0 = As + wid*512;
  unsigned short* lA1 = As + 2048 + wid*512;
  unsigned short* lB0 = Bs + wid*512;
  unsigned short* lB1 = Bs + 2048 + wid*512;

  f32x4 acc[FM][FNN];
#pragma unroll
  for(int i=0;i<FM;i++)
#pragma unroll
    for(int j=0;j<FNN;j++){ f32x4 z = {0.f,0.f,0.f,0.f}; acc[i][j] = z; }

  for (int k0 = 0; k0 < K; k0 += BK){
    __syncthreads();
    gl_lds16(A + ga0 + k0, lA0);
    gl_lds16(A + ga1 + k0, lA1);
    gl_lds16(Bp + gb0 + k0, lB0);
    if constexpr (BN == 128) gl_lds16(Bp + gb1 + k0, lB1);
    __syncthreads();
    bf16x8 fa[FM], fb[FNN];
#pragma unroll
    for(int i=0;i<FM;i++) fa[i] = *(const bf16x8*)&As[(wy*64 + i*16 + ln16)*BK + q8];
#pragma unroll
    for(int j=0;j<FNN;j++) fb[j] = *(const bf16x8*)&Bs[(wx*WN + j*16 + ln16)*BK + q8];
#pragma unroll
    for(int i=0;i<FM;i++)
#pragma unroll
      for(int j=0;j<FNN;j++)
        acc[i][j] = __builtin_amdgcn_mfma_f32_16x16x32_bf16(fa[i], fb[j], acc[i][j], 0, 0, 0);
  }

  // epilogue: C[m = quad*4+r][n = lane&15]
#pragma unroll
  for(int i=0;i<FM;i++){
    int mbase = m0 + wy*64 + i*16 + (lane>>4)*4;
#pragma unroll
    for(int j=0;j<FNN;j++){
      int n = n0 + wx*WN + j*16 + ln16;
      float bv = biasp ? biasp[n] : 0.f;
      f32x4 v = acc[i][j];
#pragma unroll
      for(int r=0;r<4;r++){
        int m = mbase + r;
        if (m < cnt){
          float x = v[r]*scale + bv;
          if constexpr (ACT == 1) x = 0.5f*x*(1.f + erff(x*0.70710678118654752f));
          long ci = (long)(MOE ? seg + m : m)*ldc + n;
          if constexpr (ADD_IN) x += addin[ci];
          if constexpr (OUT_BF16) Ch[ci] = f2bf(x);
          else Cf[ci] = x;
        }
      }
    }
  }
}

// ---------------------------------------------------------------------------
// Fused flash attention. grid (S/64, B*H). 4 waves, each owns 16 Q-rows.
// Q/K/Vt fragments loaded directly from global in MFMA operand layout.
// Online softmax in C-layout regs; P via per-wave padded LDS (no barriers).
// Writes ctx in (B,S,H*dh) layout (permute fused away).
// ---------------------------------------------------------------------------
__global__ __launch_bounds__(256)
void flash_k(const unsigned short* __restrict__ qkvb, const unsigned short* __restrict__ Vt,
             unsigned short* __restrict__ ctx)
{
  __shared__ unsigned short Pl[4][16*72];   // per-wave P, row stride 72 shorts
  const int qt = blockIdx.x, z = blockIdx.y, b = z>>3, h = z&7;
  const int wid = threadIdx.x>>6, lane = threadIdx.x&63;
  const int ln16 = lane&15, g = lane>>4;
  const int q0 = qt*64 + wid*16;
  unsigned short* Pw = &Pl[wid][0];

  // Q A-frags (reused across all KV tiles)
  const unsigned short* Qp = qkvb + (long)(b*1024 + q0 + ln16)*1536 + h*64 + g*8;
  bf16x8 qf0 = *(const bf16x8*)Qp;
  bf16x8 qf1 = *(const bf16x8*)(Qp + 32);
  const unsigned short* Kbase = qkvb + (long)b*1024*1536 + 512 + h*64 + g*8;
  const unsigned short* Vbase = Vt + (long)z*65536 + g*8;

  float m_s[4], l_s[4];
  f32x4 oacc[4];
#pragma unroll
  for(int r=0;r<4;r++){ m_s[r] = -1e30f; l_s[r] = 0.f; }
#pragma unroll
  for(int j=0;j<4;j++){ f32x4 zz = {0.f,0.f,0.f,0.f}; oacc[j] = zz; }

  for (int t = 0; t < 16; ++t){
    // K / Vt B-frags for this tile
    bf16x8 kf[4][2], vf[4][2];
#pragma unroll
    for(int j=0;j<4;j++){
      const unsigned short* kp = Kbase + (long)(t*64 + j*16 + ln16)*1536;
      kf[j][0] = *(const bf16x8*)kp;
      kf[j][1] = *(const bf16x8*)(kp + 32);
      const unsigned short* vp = Vbase + (long)(j*16 + ln16)*1024 + t*64;
      vf[j][0] = *(const bf16x8*)vp;
      vf[j][1] = *(const bf16x8*)(vp + 32);
    }
    // S = Q K^T / 8
    f32x4 sacc[4];
#pragma unroll
    for(int j=0;j<4;j++){ f32x4 zz = {0.f,0.f,0.f,0.f}; sacc[j] = zz; }
#pragma unroll
    for(int j=0;j<4;j++){
      sacc[j] = __builtin_amdgcn_mfma_f32_16x16x32_bf16(qf0, kf[j][0], sacc[j], 0,0,0);
      sacc[j] = __builtin_amdgcn_mfma_f32_16x16x32_bf16(qf1, kf[j][1], sacc[j], 0,0,0);
    }
#pragma unroll
    for(int j=0;j<4;j++)
#pragma unroll
      for(int r=0;r<4;r++) sacc[j][r] *= 0.125f;
    // online softmax update (rows live across the 16 lanes of group g)
    float alpha[4];
#pragma unroll
    for(int r=0;r<4;r++){
      float mx = fmaxf(fmaxf(sacc[0][r], sacc[1][r]), fmaxf(sacc[2][r], sacc[3][r]));
#pragma unroll
      for(int m=1;m<16;m<<=1) mx = fmaxf(mx, __shfl_xor(mx, m, 64));
      float mn = fmaxf(m_s[r], mx);
      alpha[r] = __expf(m_s[r] - mn);
      m_s[r] = mn;
    }
#pragma unroll
    for(int j=0;j<4;j++)
#pragma unroll
      for(int r=0;r<4;r++) sacc[j][r] = __expf(sacc[j][r] - m_s[r]);
#pragma unroll
    for(int r=0;r<4;r++){
      float rs = sacc[0][r]+sacc[1][r]+sacc[2][r]+sacc[3][r];
#pragma unroll
      for(int m=1;m<16;m<<=1) rs += __shfl_xor(rs, m, 64);
      l_s[r] = l_s[r]*alpha[r] + rs;
    }
#pragma unroll
    for(int j=0;j<4;j++)
#pragma unroll
      for(int r=0;r<4;r++) oacc[j][r] *= alpha[r];
    // P -> LDS (C-layout write), read back as A-frags
#pragma unroll
    for(int j=0;j<4;j++)
#pragma unroll
      for(int r=0;r<4;r++)
        Pw[(g*4+r)*72 + j*16 + ln16] = f2bf(sacc[j][r]);
    bf16x8 pf0 = *(const bf16x8*)&Pw[ln16*72 + g*8];
    bf16x8 pf1 = *(const bf16x8*)&Pw[ln16*72 + 32 + g*8];
#pragma unroll
    for(int j=0;j<4;j++){
      oacc[j] = __builtin_amdgcn_mfma_f32_16x16x32_bf16(pf0, vf[j][0], oacc[j], 0,0,0);
      oacc[j] = __builtin_amdgcn_mfma_f32_16x16x32_bf16(pf1, vf[j][1], oacc[j], 0,0,0);
    }
  }
  // epilogue: O = acc / l, store to ctx (B,S,512)
#pragma unroll
  for(int r=0;r<4;r++){
    float inv = 1.f/l_s[r];
    long row = (long)(b*1024 + q0 + g*4 + r)*512 + h*64;
#pragma unroll
    for(int j=0;j<4;j++)
      ctx[row + j*16 + ln16] = f2bf(oacc[j][r]*inv);
  }
}

// ---------------------------------------------------------------------------
// Wave-per-row LayerNorm (D=512): 4 rows/block, no barriers.
// ---------------------------------------------------------------------------
template<bool OUT_BF16>
__global__ __launch_bounds__(256)
void ln_w_k(const float* __restrict__ in, const float* __restrict__ w,
            const float* __restrict__ bb, void* __restrict__ outp)
{
  int row = blockIdx.x*4 + (threadIdx.x>>6), lane = threadIdx.x&63;
  const float4* p = (const float4*)(in + (long)row*512 + lane*8);
  float4 a = p[0], c = p[1];
  float s = a.x+a.y+a.z+a.w + c.x+c.y+c.z+c.w;
  float q = a.x*a.x+a.y*a.y+a.z*a.z+a.w*a.w + c.x*c.x+c.y*c.y+c.z*c.z+c.w*c.w;
  s = wred_sum(s); q = wred_sum(q);
  float mean = s*(1.f/512.f);
  float var  = q*(1.f/512.f) - mean*mean;
  float inv  = rsqrtf(var + 1e-5f);
  const float4* wp = (const float4*)(w + lane*8);
  const float4* bp = (const float4*)(bb + lane*8);
  float4 w0 = wp[0], w1 = wp[1], b0 = bp[0], b1 = bp[1];
  float o0 = (a.x-mean)*inv*w0.x + b0.x, o1 = (a.y-mean)*inv*w0.y + b0.y;
  float o2 = (a.z-mean)*inv*w0.z + b0.z, o3 = (a.w-mean)*inv*w0.w + b0.w;
  float o4 = (c.x-mean)*inv*w1.x + b1.x, o5 = (c.y-mean)*inv*w1.y + b1.y;
  float o6 = (c.z-mean)*inv*w1.z + b1.z, o7 = (c.w-mean)*inv*w1.w + b1.w;
  if constexpr (OUT_BF16){
    *(uint4*)((unsigned short*)outp + (long)row*512 + lane*8) =
      make_uint4(pk2(o0,o1), pk2(o2,o3), pk2(o4,o5), pk2(o6,o7));
  } else {
    float4* op = (float4*)((float*)outp + (long)row*512 + lane*8);
    op[0] = make_float4(o0,o1,o2,o3);
    op[1] = make_float4(o4,o5,o6,o7);
  }
}

// LN2 + router fused: h2 = LN(x) (bf16 out) then top-2 gate on fp32 h2.
__global__ __launch_bounds__(256)
void ln2route_k(const float* __restrict__ in, const float* __restrict__ w,
                const float* __restrict__ bb, unsigned short* __restrict__ h2,
                const float* __restrict__ gw,
                int* __restrict__ tok_e, float* __restrict__ tok_w, int* __restrict__ counts)
{
  int tok = blockIdx.x*4 + (threadIdx.x>>6), lane = threadIdx.x&63;
  const float4* p = (const float4*)(in + (long)tok*512 + lane*8);
  float4 a = p[0], c = p[1];
  float s = a.x+a.y+a.z+a.w + c.x+c.y+c.z+c.w;
  float q = a.x*a.x+a.y*a.y+a.z*a.z+a.w*a.w + c.x*c.x+c.y*c.y+c.z*c.z+c.w*c.w;
  s = wred_sum(s); q = wred_sum(q);
  float mean = s*(1.f/512.f);
  float var  = q*(1.f/512.f) - mean*mean;
  float inv  = rsqrtf(var + 1e-5f);
  const float4* wp = (const float4*)(w + lane*8);
  const float4* bp = (const float4*)(bb + lane*8);
  float4 w0 = wp[0], w1 = wp[1], b0 = bp[0], b1 = bp[1];
  float o[8];
  o[0] = (a.x-mean)*inv*w0.x + b0.x; o[1] = (a.y-mean)*inv*w0.y + b0.y;
  o[2] = (a.z-mean)*inv*w0.z + b0.z; o[3] = (a.w-mean)*inv*w0.w + b0.w;
  o[4] = (c.x-mean)*inv*w1.x + b1.x; o[5] = (c.y-mean)*inv*w1.y + b1.y;
  o[6] = (c.z-mean)*inv*w1.z + b1.z; o[7] = (c.w-mean)*inv*w1.w + b1.w;
  *(uint4*)(h2 + (long)tok*512 + lane*8) =
    make_uint4(pk2(o[0],o[1]), pk2(o[2],o[3]), pk2(o[4],o[5]), pk2(o[6],o[7]));
  float lg[8];
#pragma unroll
  for(int e=0;e<8;e++){
    const float4* gr = (const float4*)(gw + e*512 + lane*8);
    float4 g0 = gr[0], g1 = gr[1];
    float d = o[0]*g0.x + o[1]*g0.y + o[2]*g0.z + o[3]*g0.w
            + o[4]*g1.x + o[5]*g1.y + o[6]*g1.z + o[7]*g1.w;
    lg[e] = wred_sum(d);
  }
  if (lane == 0){
    float mx = lg[0];
#pragma unroll
    for(int e=1;e<8;e++) mx = fmaxf(mx, lg[e]);
    float pr[8];
#pragma unroll
    for(int e=0;e<8;e++) pr[e] = expf(lg[e]-mx);
    int e0 = 0; float p0 = pr[0];
#pragma unroll
    for(int e=1;e<8;e++) if (pr[e] > p0){ p0 = pr[e]; e0 = e; }
    int e1 = -1; float p1 = -1.f;
#pragma unroll
    for(int e=0;e<8;e++) if (e != e0 && pr[e] > p1){ p1 = pr[e]; e1 = e; }
    float invp = 1.f/(p0+p1);
    tok_e[2*tok] = e0; tok_e[2*tok+1] = e1;
    tok_w[2*tok] = p0*invp; tok_w[2*tok+1] = p1*invp;
    atomicAdd(&counts[e0], 1); atomicAdd(&counts[e1], 1);
  }
}

// Fused MoE combine + LN, wave per token
__global__ __launch_bounds__(256)
void ln_moe_k(const float* __restrict__ eout, const int* __restrict__ rowof,
              const float* __restrict__ roww, const float* __restrict__ mask,
              const unsigned short* __restrict__ h2,
              const float* __restrict__ w, const float* __restrict__ bb,
              float* __restrict__ outp)
{
  int tok = blockIdx.x*4 + (threadIdx.x>>6), lane = threadIdx.x&63;
  int r0 = rowof[2*tok], r1 = rowof[2*tok+1];
  float w0w = roww[r0], w1w = roww[r1], mk = mask[tok];
  const float4* ap = (const float4*)(eout + (long)r0*512 + lane*8);
  const float4* bp2 = (const float4*)(eout + (long)r1*512 + lane*8);
  float4 a0 = ap[0], a1 = ap[1], c0 = bp2[0], c1 = bp2[1];
  uint4 hu = *(const uint4*)(h2 + (long)tok*512 + lane*8);
  const unsigned short* hh = (const unsigned short*)&hu;
  float v[8];
  v[0] = bf2f(hh[0]) + (a0.x*w0w + c0.x*w1w)*mk;
  v[1] = bf2f(hh[1]) + (a0.y*w0w + c0.y*w1w)*mk;
  v[2] = bf2f(hh[2]) + (a0.z*w0w + c0.z*w1w)*mk;
  v[3] = bf2f(hh[3]) + (a0.w*w0w + c0.w*w1w)*mk;
  v[4] = bf2f(hh[4]) + (a1.x*w0w + c1.x*w1w)*mk;
  v[5] = bf2f(hh[5]) + (a1.y*w0w + c1.y*w1w)*mk;
  v[6] = bf2f(hh[6]) + (a1.z*w0w + c1.z*w1w)*mk;
  v[7] = bf2f(hh[7]) + (a1.w*w0w + c1.w*w1w)*mk;
  float s = 0.f, q = 0.f;
#pragma unroll
  for(int i=0;i<8;i++){ s += v[i]; q += v[i]*v[i]; }
  s = wred_sum(s); q = wred_sum(q);
  float mean = s*(1.f/512.f);
  float var  = q*(1.f/512.f) - mean*mean;
  float inv  = rsqrtf(var + 1e-5f);
  const float4* wp = (const float4*)(w + lane*8);
  const float4* bpp = (const float4*)(bb + lane*8);
  float4 w0 = wp[0], w1 = wp[1], b0 = bpp[0], b1 = bpp[1];
  float wv[8] = {w0.x,w0.y,w0.z,w0.w,w1.x,w1.y,w1.z,w1.w};
  float bv[8] = {b0.x,b0.y,b0.z,b0.w,b1.x,b1.y,b1.z,b1.w};
  float4* op = (float4*)(outp + (long)tok*512 + lane*8);
  op[0] = make_float4((v[0]-mean)*inv*wv[0]+bv[0], (v[1]-mean)*inv*wv[1]+bv[1],
                      (v[2]-mean)*inv*wv[2]+bv[2], (v[3]-mean)*inv*wv[3]+bv[3]);
  op[1] = make_float4((v[4]-mean)*inv*wv[4]+bv[4], (v[5]-mean)*inv*wv[5]+bv[5],
                      (v[6]-mean)*inv*wv[6]+bv[6], (v[7]-mean)*inv*wv[7]+bv[7]);
}

// Build Vt[bh][d][k] bf16 from qkv V slice; grid (4,32), 4 chunks per block
__global__ __launch_bounds__(256)
void vt_k(const unsigned short* __restrict__ qkvb, unsigned short* __restrict__ Vt)
{
  __shared__ unsigned short tile[64][80];
  int z = blockIdx.y, b = z>>3, h = z&7;
  int t = threadIdx.x;
  int kk = t>>2, dd = (t&3)*16;
  int dd2 = t>>2, kk2 = (t&3)*16;
  for (int c = 0; c < 4; ++c){
    int k0 = (blockIdx.x*4 + c)*64;
    const unsigned short* p = qkvb + ((long)(b*1024 + k0 + kk))*1536 + 1024 + h*64 + dd;
    uint4 u0 = *(const uint4*)p, u1 = *(const uint4*)(p+8);
    __syncthreads();
    *(uint4*)&tile[kk][dd] = u0;
    *(uint4*)&tile[kk][dd+8] = u1;
    __syncthreads();
    uint4 o0, o1;
    unsigned short* s0 = (unsigned short*)&o0;
    unsigned short* s1 = (unsigned short*)&o1;
#pragma unroll
    for(int j=0;j<8;j++){ s0[j] = tile[kk2+j][dd2]; s1[j] = tile[kk2+8+j][dd2]; }
    unsigned short* o = Vt + (long)z*65536 + (long)dd2*1024 + k0 + kk2;
    *(uint4*)o = o0; *(uint4*)(o+8) = o1;
  }
}

// fp32 (R,C) -> bf16 (C,R), z-loop of ZL
__global__ __launch_bounds__(256)
void transpose_cast_k(const float* __restrict__ in, unsigned short* __restrict__ outp,
                      int R, int C, int ZL)
{
  __shared__ float tile[64][65];
  int t = threadIdx.x;
  int rr = t>>2, cc = (t&3)*16;
  int cc2 = t>>2, rr2 = (t&3)*16;
  int c0 = blockIdx.x*64, r0 = blockIdx.y*64;
  for (int zi = 0; zi < ZL; ++zi){
    long zoff = (long)(blockIdx.z*ZL + zi) * R * C;
    const float* pin = in + zoff + (long)(r0+rr)*C + c0 + cc;
    float4 v0=*(const float4*)pin, v1=*(const float4*)(pin+4), v2=*(const float4*)(pin+8), v3=*(const float4*)(pin+12);
    __syncthreads();
    tile[rr][cc+0]=v0.x; tile[rr][cc+1]=v0.y; tile[rr][cc+2]=v0.z; tile[rr][cc+3]=v0.w;
    tile[rr][cc+4]=v1.x; tile[rr][cc+5]=v1.y; tile[rr][cc+6]=v1.z; tile[rr][cc+7]=v1.w;
    tile[rr][cc+8]=v2.x; tile[rr][cc+9]=v2.y; tile[rr][cc+10]=v2.z; tile[rr][cc+11]=v2.w;
    tile[rr][cc+12]=v3.x; tile[rr][cc+13]=v3.y; tile[rr][cc+14]=v3.z; tile[rr][cc+15]=v3.w;
    __syncthreads();
    unsigned tmp[8];
#pragma unroll
    for(int jj=0;jj<8;jj++)
      tmp[jj] = pk2(tile[rr2+2*jj][cc2], tile[rr2+2*jj+1][cc2]);
    uint4* dst = (uint4*)(outp + zoff + (long)(c0+cc2)*R + r0 + rr2);
    dst[0] = make_uint4(tmp[0],tmp[1],tmp[2],tmp[3]);
    dst[1] = make_uint4(tmp[4],tmp[5],tmp[6],tmp[7]);
  }
}

// fp32 -> bf16, grid-stride
__global__ __launch_bounds__(256)
void cast_bf16_k(const float* __restrict__ in, unsigned short* __restrict__ outp, int n8)
{
  for (int i = blockIdx.x*256 + threadIdx.x; i < n8; i += gridDim.x*256){
    const float4* p = (const float4*)(in + (long)i*8);
    float4 a = p[0], b = p[1];
    *(uint4*)(outp + (long)i*8) = make_uint4(pk2(a.x,a.y), pk2(a.z,a.w), pk2(b.x,b.y), pk2(b.z,b.w));
  }
}

// Planner: offsets, cursors, aux, MoE block table (BM=128)
__global__ void plan_k(const int* __restrict__ counts, int* __restrict__ offs,
                       int* __restrict__ cursors, float* __restrict__ aux,
                       int* __restrict__ btab)
{
  if (threadIdx.x == 0 && blockIdx.x == 0){
    int o = 0; float a = 0.f; int idx = 0;
    for(int e=0;e<8;e++){
      offs[e] = o; o += counts[e]; cursors[e] = 0;
      float u = (float)counts[e]*(1.f/4096.f) - 0.125f;
      a += u*u;
      int nb = (counts[e] + 127) >> 7;
      for(int j=0;j<nb;j++) btab[idx++] = (e<<8)|j;
    }
    while (idx < 80) btab[idx++] = -1;
    *aux += a*(1.f/8.f);
  }
}

__global__ __launch_bounds__(256)
void scatter_k(const int* __restrict__ tok_e, const float* __restrict__ tok_w,
               const int* __restrict__ offs, int* __restrict__ cursors,
               int* __restrict__ rowtok, float* __restrict__ roww, int* __restrict__ rowof)
{
  int i = blockIdx.x*256 + threadIdx.x;   // 8192 (token,k) pairs
  int e = tok_e[i]; float w = tok_w[i];
  int pos = offs[e] + atomicAdd(&cursors[e], 1);
  rowtok[pos] = i>>1;
  roww[pos] = w;
  rowof[i] = pos;
}

// masked-sum partial pooling
__global__ __launch_bounds__(256)
void pool_k(const float* __restrict__ h, const float* __restrict__ mask, float* __restrict__ pooled)
{
  int z = blockIdx.x, b = z>>4, sc = z&15, t = threadIdx.x;
  float a0 = 0.f, a1 = 0.f;
  for(int ss=0;ss<64;ss++){
    int s = sc*64 + ss;
    float mk = mask[b*1024 + s];
    const float* r = h + ((long)b*1024 + s)*512;
    a0 += r[t]*mk; a1 += r[t+256]*mk;
  }
  atomicAdd(&pooled[b*512 + t], a0);
  atomicAdd(&pooled[b*512 + t + 256], a1);
}

__global__ __launch_bounds__(256)
void head_final_k(const float* __restrict__ pooled, const float* __restrict__ mask,
                  const float* __restrict__ pool_w, const float* __restrict__ pool_b,
                  const float* __restrict__ cls_w, const float* __restrict__ cls_b,
                  const float* __restrict__ cf_w1, const float* __restrict__ cf_b1,
                  const float* __restrict__ cf_w2, const float* __restrict__ cf_b2,
                  const float* __restrict__ aux, float* __restrict__ out)
{
  int b = blockIdx.x, t = threadIdx.x, wid = t>>6, lane = t&63;
  __shared__ __align__(16) float pld[512];
  __shared__ __align__(16) float p2[512];
  __shared__ float red[4];
  float ds = 0.f;
  for(int s=t; s<1024; s+=256) ds += mask[b*1024 + s];
  ds = wred_sum(ds);
  if (lane==0) red[wid] = ds;
  __syncthreads();
  float denom = fmaxf(red[0]+red[1]+red[2]+red[3], 1e-9f);
  pld[t]     = pooled[b*512 + t]/denom;
  pld[t+256] = pooled[b*512 + t + 256]/denom;
  __syncthreads();
#pragma unroll
  for(int jj=0;jj<2;jj++){
    int j = t + jj*256;
    const float4* wr = (const float4*)(pool_w + (long)j*512);
    float acc = 0.f;
    for(int i=0;i<128;i++){
      float4 w4 = wr[i]; float4 x4 = ((const float4*)pld)[i];
      acc += w4.x*x4.x + w4.y*x4.y + w4.z*x4.z + w4.w*x4.w;
    }
    p2[j] = tanhf(acc + pool_b[j]);
  }
  __syncthreads();
  if (t < 4){
    const float4* wr = (const float4*)(cls_w + (long)t*512);
    float acc = 0.f;
    for(int i=0;i<128;i++){
      float4 w4 = wr[i]; float4 x4 = ((const float4*)p2)[i];
      acc += w4.x*x4.x + w4.y*x4.y + w4.z*x4.z + w4.w*x4.w;
    }
    out[b*4 + t] = acc + cls_b[t];
  }
  {
    const float4* wr = (const float4*)(cf_w1 + (long)t*512);
    float acc = 0.f;
    for(int i=0;i<128;i++){
      float4 w4 = wr[i]; float4 x4 = ((const float4*)p2)[i];
      acc += w4.x*x4.x + w4.y*x4.y + w4.z*x4.z + w4.w*x4.w;
    }
    acc = fmaxf(acc + cf_b1[t], 0.f) * cf_w2[t];
    acc = wred_sum(acc);
    __syncthreads();
    if (lane==0) red[wid] = acc;
    __syncthreads();
    if (t == 0){
      float sum = red[0]+red[1]+red[2]+red[3];
      out[17 + b] = 1.f/(1.f + expf(-(sum + cf_b2[0])));
    }
  }
  if (b == 0 && t == 0) out[16] = aux[0]*0.25f;
}

// ---------------------------------------------------------------------------
extern "C" void kernel_launch(void* const* d_in, const int* in_sizes, int n_in,
                              void* d_out, int out_size, void* d_ws, size_t ws_size,
                              hipStream_t stream)
{
  (void)in_sizes; (void)n_in; (void)out_size;
  const float* emb    = (const float*)d_in[0];
  const float* mask   = (const float*)d_in[1];
  const float* in_w   = (const float*)d_in[2];
  const float* in_b   = (const float*)d_in[3];
  const float* out_w  = (const float*)d_in[4];
  const float* out_b  = (const float*)d_in[5];
  const float* ln1_w  = (const float*)d_in[6];
  const float* ln1_b  = (const float*)d_in[7];
  const float* ln2_w  = (const float*)d_in[8];
  const float* ln2_b  = (const float*)d_in[9];
  const float* gate_w = (const float*)d_in[10];
  const float* e_w1   = (const float*)d_in[11];
  const float* e_b1   = (const float*)d_in[12];
  const float* e_w2   = (const float*)d_in[13];
  const float* e_b2   = (const float*)d_in[14];
  const float* mln_w  = (const float*)d_in[15];
  const float* mln_b  = (const float*)d_in[16];
  const float* fln_w  = (const float*)d_in[17];
  const float* fln_b  = (const float*)d_in[18];
  const float* pool_w = (const float*)d_in[19];
  const float* pool_b = (const float*)d_in[20];
  const float* cls_w  = (const float*)d_in[21];
  const float* cls_b  = (const float*)d_in[22];
  const float* cf_w1  = (const float*)d_in[23];
  const float* cf_b1  = (const float*)d_in[24];
  const float* cf_w2  = (const float*)d_in[25];
  const float* cf_b2  = (const float*)d_in[26];
  float* out = (float*)d_out;
  char* ws = (char*)d_ws;

  const size_t MiB = 1024*1024;
  if (ws_size < 218*MiB) return;

  // Workspace layout
  float*          x     = (float*)(ws + 0*MiB);             // 8 MiB fp32
  unsigned short* hb    = (unsigned short*)(ws + 8*MiB);    // 4 MiB bf16
  unsigned short* qkvb  = (unsigned short*)(ws + 12*MiB);   // 12 MiB bf16
  unsigned short* ctx   = (unsigned short*)(ws + 24*MiB);   // 4 MiB bf16
  unsigned short* Vt    = (unsigned short*)(ws + 28*MiB);   // 4 MiB bf16
  unsigned short* mid   = (unsigned short*)(ws + 32*MiB);   // 32 MiB bf16
  float*          eout  = (float*)(ws + 64*MiB);            // 16 MiB fp32
  float*          fout  = (float*)(ws + 64*MiB);            //   (reuse, head)
  unsigned short* w1t   = (unsigned short*)(ws + 80*MiB);   // 64 MiB bf16
  unsigned short* w2t   = (unsigned short*)(ws + 144*MiB);  // 64 MiB bf16
  unsigned short* inwb  = (unsigned short*)(ws + 208*MiB);  // 6 MiB bf16
  unsigned short* outwb = (unsigned short*)(ws + 214*MiB);  // 2 MiB bf16
  char* misc = ws + 216*MiB;
  int*   counts  = (int*)(misc + 0);
  int*   cursors = (int*)(misc + 64);
  int*   offs    = (int*)(misc + 128);
  float* aux     = (float*)(misc + 192);
  int*   btab    = (int*)(misc + 256);
  float* pooled  = (float*)(misc + 1024);
  int*   tok_e   = (int*)(misc + 16384);
  float* tok_w   = (float*)(misc + 49152);
  int*   rowtok  = (int*)(misc + 81920);
  float* roww    = (float*)(misc + 114688);
  int*   rowof   = (int*)(misc + 147456);

  hipMemcpyAsync(x, emb, (size_t)T_*D_*4, hipMemcpyDeviceToDevice, stream);
  hipMemsetAsync(aux, 0, 4, stream);
  hipMemsetAsync(pooled, 0, 2048*4, stream);
  // weight prep
  cast_bf16_k<<<512, 256, 0, stream>>>(in_w, inwb, L_*3*D_*D_/8);
  cast_bf16_k<<<256, 256, 0, stream>>>(out_w, outwb, L_*D_*D_/8);
  transpose_cast_k<<<dim3(I_/64, D_/64, 4), 256, 0, stream>>>(e_w1, w1t, D_, I_, 8);
  transpose_cast_k<<<dim3(D_/64, I_/64, 4), 256, 0, stream>>>(e_w2, w2t, I_, D_, 8);

  for (int l=0; l<L_; l++){
    const float* inbl  = in_b  + (size_t)l*3*D_;
    const float* outbl = out_b + (size_t)l*D_;
    const float* gwl   = gate_w + (size_t)l*E_*D_;
    const float* eb1l  = e_b1 + (size_t)l*E_*I_;
    const float* eb2l  = e_b2 + (size_t)l*E_*D_;
    const unsigned short* inwbl  = inwb + (size_t)l*3*D_*D_;
    const unsigned short* outwbl = outwb + (size_t)l*D_*D_;
    const unsigned short* w1tl = w1t + (size_t)l*E_*I_*D_;
    const unsigned short* w2tl = w2t + (size_t)l*E_*D_*I_;

    // h = LN1(x) -> bf16
    ln_w_k<true><<<T_/4, 256, 0, stream>>>(x, ln1_w + (size_t)l*D_, ln1_b + (size_t)l*D_, hb);
    // qkv = h @ in_w^T + in_b -> bf16
    gemm2_k<128,false,false,true,0,false><<<dim3(32,12,1), 256, 0, stream>>>(
      hb, inwbl, qkvb, inbl, nullptr, T_, 3*D_, D_, D_, D_, 3*D_,
      1, 0,0,0,0,0,0, 1.f, nullptr, nullptr, nullptr, nullptr, 0, 0);
    vt_k<<<dim3(4,32), 256, 0, stream>>>(qkvb, Vt);
    // fused attention -> ctx (B,S,512) bf16
    flash_k<<<dim3(16,32), 256, 0, stream>>>(qkvb, Vt, ctx);
    // x = x + ctx @ out_w^T + out_b  (fp32)
    gemm2_k<128,false,false,false,0,true><<<dim3(32,4,1), 256, 0, stream>>>(
      ctx, outwbl, x, outbl, x, T_, D_, D_, D_, D_, D_,
      1, 0,0,0,0,0,0, 1.f, nullptr, nullptr, nullptr, nullptr, 0, 0);
    // h2 = LN2(x) -> bf16, + routing
    hipMemsetAsync(counts, 0, 64, stream);
    ln2route_k<<<T_/4, 256, 0, stream>>>(x, ln2_w + (size_t)l*D_, ln2_b + (size_t)l*D_,
                                         hb, gwl, tok_e, tok_w, counts);
    plan_k<<<1, 1, 0, stream>>>(counts, offs, cursors, aux, btab);
    scatter_k<<<32, 256, 0, stream>>>(tok_e, tok_w, offs, cursors, rowtok, roww, rowof);
    // FFN1: mid = gelu(gather(h2) @ w1^T + b1) -> bf16
    gemm2_k<128,true,true,true,1,false><<<dim3(71,16,1), 256, 0, stream>>>(
      hb, w1tl, mid, eb1l, nullptr, 2*T_, I_, D_, D_, D_, I_,
      1, 0,0,0,0,0,0, 1.f, offs, counts, rowtok, btab, (long)I_*D_, I_);
    // FFN2: eout = mid @ w2^T + b2 -> fp32
    gemm2_k<128,true,false,false,0,false><<<dim3(71,4,1), 256, 0, stream>>>(
      mid, w2tl, eout, eb2l, nullptr, 2*T_, D_, I_, I_, I_, D_,
      1, 0,0,0,0,0,0, 1.f, offs, counts, nullptr, btab, (long)D_*I_, D_);
    // x = LN(h2 + combine(eout))
    ln_moe_k<<<T_/4, 256, 0, stream>>>(eout, rowof, roww, mask, hb,
                                       mln_w + (size_t)l*D_, mln_b + (size_t)l*D_, x);
  }
  // head
  ln_w_k<false><<<T_/4, 256, 0, stream>>>(x, fln_w, fln_b, fout);
  pool_k<<<64, 256, 0, stream>>>(fout, mask, pooled);
  head_final_k<<<4, 256, 0, stream>>>(pooled, mask, pool_w, pool_b, cls_w, cls_b,
                                      cf_w1, cf_b1, cf_w2, cf_b2, aux, out);
}

// Round 5
// 1597.275 us; speedup vs baseline: 2.1184x; 1.2913x over previous
//
#include <hip/hip_runtime.h>
#include <math.h>

// Problem constants
#define B_ 4
#define S_ 1024
#define D_ 512
#define H_ 8
#define DH_ 64
#define I_ 2048
#define E_ 8
#define L_ 4
#define T_ 4096   // B*S

using bf16x8 = __attribute__((ext_vector_type(8))) __bf16;
using f32x4  = __attribute__((ext_vector_type(4))) float;

typedef __attribute__((address_space(1))) const void gvoid;
typedef __attribute__((address_space(3))) void lvoid;
__device__ __forceinline__ void gl_lds16(const void* g, void* l){
  __builtin_amdgcn_global_load_lds((gvoid*)g, (lvoid*)l, 16, 0, 0);
}

__device__ __forceinline__ float wred_sum(float v){
#pragma unroll
  for(int m=32;m>0;m>>=1) v += __shfl_xor(v, m, 64);
  return v;
}
__device__ __forceinline__ unsigned short f2bf(float f){
  unsigned x = __float_as_uint(f);
  unsigned r = (x + 0x7FFFu + ((x>>16)&1u)) >> 16;
  return (unsigned short)r;
}
__device__ __forceinline__ float bf2f(unsigned short u){
  return __uint_as_float(((unsigned)u)<<16);
}
__device__ __forceinline__ unsigned pk2(float a, float b){
  return (unsigned)f2bf(a) | ((unsigned)f2bf(b)<<16);
}

// ---------------------------------------------------------------------------
// bf16 MFMA GEMM (global_load_lds width-16, single buffer, 2 barriers/iter).
// NT: C[m,n] = sum_k A[m,k]*B[n,k]. BM=128, BN {128,64}.
// MOE: block table btab[bx] = (e<<8)|mblk, -1 = dead. Optional row gather.
// ---------------------------------------------------------------------------
template<int BN, bool MOE, bool GATHER, bool OUT_BF16, int ACT, bool ADD_IN>
__global__ __launch_bounds__(256)
void gemm2_k(const unsigned short* __restrict__ A, const unsigned short* __restrict__ Bv,
             void* Cp, const float* __restrict__ bias, const float* addin,
             int M, int N, int K, int lda, int ldb, int ldc,
             int hdiv, long sAb, long sAh, long sBb, long sBh, long sCb, long sCh,
             float scale,
             const int* __restrict__ moff, const int* __restrict__ mcnt,
             const int* __restrict__ rowtok, const int* __restrict__ btab,
             long sBe, int biasStride)
{
  constexpr int BM = 128, BK = 32;
  constexpr int WN = BN/2, FM = 4, FNN = WN/16;
  __shared__ unsigned short As[BM*BK];
  __shared__ unsigned short Bs[BN*BK];

  const int tid = threadIdx.x, wid = tid>>6, lane = tid&63;
  const int wy = wid>>1, wx = wid&1, ln16 = lane&15, q8 = (lane>>4)*8;
  int m0 = blockIdx.x*BM;
  const int n0 = blockIdx.y*BN;

  float* Cf = nullptr; unsigned short* Ch = nullptr;
  const float* biasp = bias;
  const unsigned short* Bp = Bv;
  int seg = 0, cnt = M;

  if constexpr (MOE){
    int tv = btab[blockIdx.x];
    if (tv < 0) return;
    int e = tv>>8;
    m0 = (tv&255)*BM;
    seg = moff[e]; cnt = mcnt[e];
    Bp = Bv + (long)e*sBe;
    if constexpr (OUT_BF16) Ch = (unsigned short*)Cp; else Cf = (float*)Cp;
    if (biasp) biasp += (long)e*biasStride;
  } else {
    int z = blockIdx.z, zb = z/hdiv, zh = z%hdiv;
    A  += (long)zb*sAb + (long)zh*sAh;
    Bp += (long)zb*sBb + (long)zh*sBh;
    long coff = (long)zb*sCb + (long)zh*sCh;
    if constexpr (OUT_BF16) Ch = (unsigned short*)Cp + coff; else Cf = ((float*)Cp) + coff;
    if constexpr (ADD_IN) addin += coff;
  }

  // staging geometry: wave w rows w*16 + lane/4 (+64 chunk1), col (lane&3)*8
  const int arow0 = wid*16 + (lane>>2);
  const int colb  = (lane&3)*8;
  long ga0, ga1, gb0, gb1 = 0;
  {
    int r0 = m0 + arow0, r1 = r0 + 64;
    if constexpr (MOE){
      r0 = min(r0, cnt-1); r1 = min(r1, cnt-1);
      long gr0 = GATHER ? (long)rowtok[seg+r0] : (long)(seg+r0);
      long gr1 = GATHER ? (long)rowtok[seg+r1] : (long)(seg+r1);
      ga0 = gr0*lda + colb; ga1 = gr1*lda + colb;
    } else {
      ga0 = (long)min(r0, M-1)*lda + colb;
      ga1 = (long)min(r1, M-1)*lda + colb;
    }
    int b0 = min(n0 + arow0, N-1);
    gb0 = (long)b0*ldb + colb;
    if constexpr (BN == 128){
      int b1 = min(n0 + arow0 + 64, N-1);
      gb1 = (long)b1*ldb + colb;
    }
  }
  unsigned short* lA0 = As + wid*512;
  unsigned short* lA1 = As + 2048 + wid*512;
  unsigned short* lB0 = Bs + wid*512;
  unsigned short* lB1 = Bs + 2048 + wid*512;

  f32x4 acc[FM][FNN];
#pragma unroll
  for(int i=0;i<FM;i++)
#pragma unroll
    for(int j=0;j<FNN;j++){ f32x4 z = {0.f,0.f,0.f,0.f}; acc[i][j] = z; }

  for (int k0 = 0; k0 < K; k0 += BK){
    __syncthreads();
    gl_lds16(A + ga0 + k0, lA0);
    gl_lds16(A + ga1 + k0, lA1);
    gl_lds16(Bp + gb0 + k0, lB0);
    if constexpr (BN == 128) gl_lds16(Bp + gb1 + k0, lB1);
    __syncthreads();
    bf16x8 fa[FM], fb[FNN];
#pragma unroll
    for(int i=0;i<FM;i++) fa[i] = *(const bf16x8*)&As[(wy*64 + i*16 + ln16)*BK + q8];
#pragma unroll
    for(int j=0;j<FNN;j++) fb[j] = *(const bf16x8*)&Bs[(wx*WN + j*16 + ln16)*BK + q8];
#pragma unroll
    for(int i=0;i<FM;i++)
#pragma unroll
      for(int j=0;j<FNN;j++)
        acc[i][j] = __builtin_amdgcn_mfma_f32_16x16x32_bf16(fa[i], fb[j], acc[i][j], 0, 0, 0);
  }

  // epilogue: C[m = quad*4+r][n = lane&15]
#pragma unroll
  for(int i=0;i<FM;i++){
    int mbase = m0 + wy*64 + i*16 + (lane>>4)*4;
#pragma unroll
    for(int j=0;j<FNN;j++){
      int n = n0 + wx*WN + j*16 + ln16;
      float bv = biasp ? biasp[n] : 0.f;
      f32x4 v = acc[i][j];
#pragma unroll
      for(int r=0;r<4;r++){
        int m = mbase + r;
        if (m < cnt){
          float x = v[r]*scale + bv;
          if constexpr (ACT == 1) x = 0.5f*x*(1.f + erff(x*0.70710678118654752f));
          long ci = (long)(MOE ? seg + m : m)*ldc + n;
          if constexpr (ADD_IN) x += addin[ci];
          if constexpr (OUT_BF16) Ch[ci] = f2bf(x);
          else Cf[ci] = x;
        }
      }
    }
  }
}

// ---------------------------------------------------------------------------
// Fused flash attention. grid (S/64, B*H). 4 waves, each owns 16 Q-rows.
// ---------------------------------------------------------------------------
__global__ __launch_bounds__(256)
void flash_k(const unsigned short* __restrict__ qkvb, const unsigned short* __restrict__ Vt,
             unsigned short* __restrict__ ctx)
{
  __shared__ unsigned short Pl[4][16*72];
  const int qt = blockIdx.x, z = blockIdx.y, b = z>>3, h = z&7;
  const int wid = threadIdx.x>>6, lane = threadIdx.x&63;
  const int ln16 = lane&15, g = lane>>4;
  const int q0 = qt*64 + wid*16;
  unsigned short* Pw = &Pl[wid][0];

  const unsigned short* Qp = qkvb + (long)(b*1024 + q0 + ln16)*1536 + h*64 + g*8;
  bf16x8 qf0 = *(const bf16x8*)Qp;
  bf16x8 qf1 = *(const bf16x8*)(Qp + 32);
  const unsigned short* Kbase = qkvb + (long)b*1024*1536 + 512 + h*64 + g*8;
  const unsigned short* Vbase = Vt + (long)z*65536 + g*8;

  float m_s[4], l_s[4];
  f32x4 oacc[4];
#pragma unroll
  for(int r=0;r<4;r++){ m_s[r] = -1e30f; l_s[r] = 0.f; }
#pragma unroll
  for(int j=0;j<4;j++){ f32x4 zz = {0.f,0.f,0.f,0.f}; oacc[j] = zz; }

  for (int t = 0; t < 16; ++t){
    bf16x8 kf[4][2], vf[4][2];
#pragma unroll
    for(int j=0;j<4;j++){
      const unsigned short* kp = Kbase + (long)(t*64 + j*16 + ln16)*1536;
      kf[j][0] = *(const bf16x8*)kp;
      kf[j][1] = *(const bf16x8*)(kp + 32);
      const unsigned short* vp = Vbase + (long)(j*16 + ln16)*1024 + t*64;
      vf[j][0] = *(const bf16x8*)vp;
      vf[j][1] = *(const bf16x8*)(vp + 32);
    }
    f32x4 sacc[4];
#pragma unroll
    for(int j=0;j<4;j++){ f32x4 zz = {0.f,0.f,0.f,0.f}; sacc[j] = zz; }
#pragma unroll
    for(int j=0;j<4;j++){
      sacc[j] = __builtin_amdgcn_mfma_f32_16x16x32_bf16(qf0, kf[j][0], sacc[j], 0,0,0);
      sacc[j] = __builtin_amdgcn_mfma_f32_16x16x32_bf16(qf1, kf[j][1], sacc[j], 0,0,0);
    }
#pragma unroll
    for(int j=0;j<4;j++)
#pragma unroll
      for(int r=0;r<4;r++) sacc[j][r] *= 0.125f;
    float alpha[4];
#pragma unroll
    for(int r=0;r<4;r++){
      float mx = fmaxf(fmaxf(sacc[0][r], sacc[1][r]), fmaxf(sacc[2][r], sacc[3][r]));
#pragma unroll
      for(int m=1;m<16;m<<=1) mx = fmaxf(mx, __shfl_xor(mx, m, 64));
      float mn = fmaxf(m_s[r], mx);
      alpha[r] = __expf(m_s[r] - mn);
      m_s[r] = mn;
    }
#pragma unroll
    for(int j=0;j<4;j++)
#pragma unroll
      for(int r=0;r<4;r++) sacc[j][r] = __expf(sacc[j][r] - m_s[r]);
#pragma unroll
    for(int r=0;r<4;r++){
      float rs = sacc[0][r]+sacc[1][r]+sacc[2][r]+sacc[3][r];
#pragma unroll
      for(int m=1;m<16;m<<=1) rs += __shfl_xor(rs, m, 64);
      l_s[r] = l_s[r]*alpha[r] + rs;
    }
#pragma unroll
    for(int j=0;j<4;j++)
#pragma unroll
      for(int r=0;r<4;r++) oacc[j][r] *= alpha[r];
#pragma unroll
    for(int j=0;j<4;j++)
#pragma unroll
      for(int r=0;r<4;r++)
        Pw[(g*4+r)*72 + j*16 + ln16] = f2bf(sacc[j][r]);
    bf16x8 pf0 = *(const bf16x8*)&Pw[ln16*72 + g*8];
    bf16x8 pf1 = *(const bf16x8*)&Pw[ln16*72 + 32 + g*8];
#pragma unroll
    for(int j=0;j<4;j++){
      oacc[j] = __builtin_amdgcn_mfma_f32_16x16x32_bf16(pf0, vf[j][0], oacc[j], 0,0,0);
      oacc[j] = __builtin_amdgcn_mfma_f32_16x16x32_bf16(pf1, vf[j][1], oacc[j], 0,0,0);
    }
  }
#pragma unroll
  for(int r=0;r<4;r++){
    float inv = 1.f/l_s[r];
    long row = (long)(b*1024 + q0 + g*4 + r)*512 + h*64;
#pragma unroll
    for(int j=0;j<4;j++)
      ctx[row + j*16 + ln16] = f2bf(oacc[j][r]*inv);
  }
}

// ---------------------------------------------------------------------------
// Wave-per-row LayerNorm (D=512): 4 rows/block, no barriers.
// ---------------------------------------------------------------------------
template<bool OUT_BF16>
__global__ __launch_bounds__(256)
void ln_w_k(const float* __restrict__ in, const float* __restrict__ w,
            const float* __restrict__ bb, void* __restrict__ outp)
{
  int row = blockIdx.x*4 + (threadIdx.x>>6), lane = threadIdx.x&63;
  const float4* p = (const float4*)(in + (long)row*512 + lane*8);
  float4 a = p[0], c = p[1];
  float s = a.x+a.y+a.z+a.w + c.x+c.y+c.z+c.w;
  float q = a.x*a.x+a.y*a.y+a.z*a.z+a.w*a.w + c.x*c.x+c.y*c.y+c.z*c.z+c.w*c.w;
  s = wred_sum(s); q = wred_sum(q);
  float mean = s*(1.f/512.f);
  float var  = q*(1.f/512.f) - mean*mean;
  float inv  = rsqrtf(var + 1e-5f);
  const float4* wp = (const float4*)(w + lane*8);
  const float4* bp = (const float4*)(bb + lane*8);
  float4 w0 = wp[0], w1 = wp[1], b0 = bp[0], b1 = bp[1];
  float o0 = (a.x-mean)*inv*w0.x + b0.x, o1 = (a.y-mean)*inv*w0.y + b0.y;
  float o2 = (a.z-mean)*inv*w0.z + b0.z, o3 = (a.w-mean)*inv*w0.w + b0.w;
  float o4 = (c.x-mean)*inv*w1.x + b1.x, o5 = (c.y-mean)*inv*w1.y + b1.y;
  float o6 = (c.z-mean)*inv*w1.z + b1.z, o7 = (c.w-mean)*inv*w1.w + b1.w;
  if constexpr (OUT_BF16){
    *(uint4*)((unsigned short*)outp + (long)row*512 + lane*8) =
      make_uint4(pk2(o0,o1), pk2(o2,o3), pk2(o4,o5), pk2(o6,o7));
  } else {
    float4* op = (float4*)((float*)outp + (long)row*512 + lane*8);
    op[0] = make_float4(o0,o1,o2,o3);
    op[1] = make_float4(o4,o5,o6,o7);
  }
}

// LN2 + router fused: h2 = LN(x) (bf16 out) then top-2 gate; NO global atomics.
__global__ __launch_bounds__(256)
void ln2route_k(const float* __restrict__ in, const float* __restrict__ w,
                const float* __restrict__ bb, unsigned short* __restrict__ h2,
                const float* __restrict__ gw,
                int* __restrict__ tok_e, float* __restrict__ tok_w)
{
  int tok = blockIdx.x*4 + (threadIdx.x>>6), lane = threadIdx.x&63;
  const float4* p = (const float4*)(in + (long)tok*512 + lane*8);
  float4 a = p[0], c = p[1];
  float s = a.x+a.y+a.z+a.w + c.x+c.y+c.z+c.w;
  float q = a.x*a.x+a.y*a.y+a.z*a.z+a.w*a.w + c.x*c.x+c.y*c.y+c.z*c.z+c.w*c.w;
  s = wred_sum(s); q = wred_sum(q);
  float mean = s*(1.f/512.f);
  float var  = q*(1.f/512.f) - mean*mean;
  float inv  = rsqrtf(var + 1e-5f);
  const float4* wp = (const float4*)(w + lane*8);
  const float4* bp = (const float4*)(bb + lane*8);
  float4 w0 = wp[0], w1 = wp[1], b0 = bp[0], b1 = bp[1];
  float o[8];
  o[0] = (a.x-mean)*inv*w0.x + b0.x; o[1] = (a.y-mean)*inv*w0.y + b0.y;
  o[2] = (a.z-mean)*inv*w0.z + b0.z; o[3] = (a.w-mean)*inv*w0.w + b0.w;
  o[4] = (c.x-mean)*inv*w1.x + b1.x; o[5] = (c.y-mean)*inv*w1.y + b1.y;
  o[6] = (c.z-mean)*inv*w1.z + b1.z; o[7] = (c.w-mean)*inv*w1.w + b1.w;
  *(uint4*)(h2 + (long)tok*512 + lane*8) =
    make_uint4(pk2(o[0],o[1]), pk2(o[2],o[3]), pk2(o[4],o[5]), pk2(o[6],o[7]));
  float lg[8];
#pragma unroll
  for(int e=0;e<8;e++){
    const float4* gr = (const float4*)(gw + e*512 + lane*8);
    float4 g0 = gr[0], g1 = gr[1];
    float d = o[0]*g0.x + o[1]*g0.y + o[2]*g0.z + o[3]*g0.w
            + o[4]*g1.x + o[5]*g1.y + o[6]*g1.z + o[7]*g1.w;
    lg[e] = wred_sum(d);
  }
  if (lane == 0){
    float mx = lg[0];
#pragma unroll
    for(int e=1;e<8;e++) mx = fmaxf(mx, lg[e]);
    float pr[8];
#pragma unroll
    for(int e=0;e<8;e++) pr[e] = expf(lg[e]-mx);
    int e0 = 0; float p0 = pr[0];
#pragma unroll
    for(int e=1;e<8;e++) if (pr[e] > p0){ p0 = pr[e]; e0 = e; }
    int e1 = -1; float p1 = -1.f;
#pragma unroll
    for(int e=0;e<8;e++) if (e != e0 && pr[e] > p1){ p1 = pr[e]; e1 = e; }
    float invp = 1.f/(p0+p1);
    tok_e[2*tok] = e0; tok_e[2*tok+1] = e1;
    tok_w[2*tok] = p0*invp; tok_w[2*tok+1] = p1*invp;
  }
}

// ---------------------------------------------------------------------------
// Single-block planner + scatter: LDS-atomic histogram, offsets, block table,
// aux, and compaction scatter. ZERO global atomics.
// ---------------------------------------------------------------------------
__global__ __launch_bounds__(1024)
void plan_scatter_k(const int* __restrict__ tok_e, const float* __restrict__ tok_w,
                    int* __restrict__ offs, int* __restrict__ cnts, float* __restrict__ aux,
                    int* __restrict__ btab,
                    int* __restrict__ rowtok, float* __restrict__ roww, int* __restrict__ rowof)
{
  __shared__ int hist[8];
  __shared__ int offsS[8];
  __shared__ int base[8];
  const int t = threadIdx.x;
  if (t < 8) hist[t] = 0;
  __syncthreads();
  int e[8]; float w[8];
#pragma unroll
  for (int i=0;i<8;i++){
    e[i] = tok_e[t + i*1024];
    w[i] = tok_w[t + i*1024];
    atomicAdd(&hist[e[i]], 1);
  }
  __syncthreads();
  if (t == 0){
    int o = 0, idx = 0; float a = 0.f;
    for (int ee=0; ee<8; ee++){
      offsS[ee] = o;
      int c = hist[ee];
      o += c;
      float u = (float)c*(1.f/4096.f) - 0.125f;
      a += u*u;
      int nb = (c + 127) >> 7;
      for (int j=0;j<nb;j++) btab[idx++] = (ee<<8)|j;
    }
    while (idx < 80) btab[idx++] = -1;
    *aux += a*(1.f/8.f);
  }
  __syncthreads();
  if (t < 8){
    cnts[t] = hist[t];
    offs[t] = offsS[t];
    base[t] = offsS[t];
  }
  __syncthreads();
#pragma unroll
  for (int i=0;i<8;i++){
    int pos = atomicAdd(&base[e[i]], 1);   // LDS atomic
    int gi = t + i*1024;
    rowtok[pos] = gi>>1;
    roww[pos] = w[i];
    rowof[gi] = pos;
  }
}

// Fused MoE combine + LN, wave per token
__global__ __launch_bounds__(256)
void ln_moe_k(const float* __restrict__ eout, const int* __restrict__ rowof,
              const float* __restrict__ roww, const float* __restrict__ mask,
              const unsigned short* __restrict__ h2,
              const float* __restrict__ w, const float* __restrict__ bb,
              float* __restrict__ outp)
{
  int tok = blockIdx.x*4 + (threadIdx.x>>6), lane = threadIdx.x&63;
  int r0 = rowof[2*tok], r1 = rowof[2*tok+1];
  float w0w = roww[r0], w1w = roww[r1], mk = mask[tok];
  const float4* ap = (const float4*)(eout + (long)r0*512 + lane*8);
  const float4* bp2 = (const float4*)(eout + (long)r1*512 + lane*8);
  float4 a0 = ap[0], a1 = ap[1], c0 = bp2[0], c1 = bp2[1];
  uint4 hu = *(const uint4*)(h2 + (long)tok*512 + lane*8);
  const unsigned short* hh = (const unsigned short*)&hu;
  float v[8];
  v[0] = bf2f(hh[0]) + (a0.x*w0w + c0.x*w1w)*mk;
  v[1] = bf2f(hh[1]) + (a0.y*w0w + c0.y*w1w)*mk;
  v[2] = bf2f(hh[2]) + (a0.z*w0w + c0.z*w1w)*mk;
  v[3] = bf2f(hh[3]) + (a0.w*w0w + c0.w*w1w)*mk;
  v[4] = bf2f(hh[4]) + (a1.x*w0w + c1.x*w1w)*mk;
  v[5] = bf2f(hh[5]) + (a1.y*w0w + c1.y*w1w)*mk;
  v[6] = bf2f(hh[6]) + (a1.z*w0w + c1.z*w1w)*mk;
  v[7] = bf2f(hh[7]) + (a1.w*w0w + c1.w*w1w)*mk;
  float s = 0.f, q = 0.f;
#pragma unroll
  for(int i=0;i<8;i++){ s += v[i]; q += v[i]*v[i]; }
  s = wred_sum(s); q = wred_sum(q);
  float mean = s*(1.f/512.f);
  float var  = q*(1.f/512.f) - mean*mean;
  float inv  = rsqrtf(var + 1e-5f);
  const float4* wp = (const float4*)(w + lane*8);
  const float4* bpp = (const float4*)(bb + lane*8);
  float4 w0 = wp[0], w1 = wp[1], b0 = bpp[0], b1 = bpp[1];
  float wv[8] = {w0.x,w0.y,w0.z,w0.w,w1.x,w1.y,w1.z,w1.w};
  float bv[8] = {b0.x,b0.y,b0.z,b0.w,b1.x,b1.y,b1.z,b1.w};
  float4* op = (float4*)(outp + (long)tok*512 + lane*8);
  op[0] = make_float4((v[0]-mean)*inv*wv[0]+bv[0], (v[1]-mean)*inv*wv[1]+bv[1],
                      (v[2]-mean)*inv*wv[2]+bv[2], (v[3]-mean)*inv*wv[3]+bv[3]);
  op[1] = make_float4((v[4]-mean)*inv*wv[4]+bv[4], (v[5]-mean)*inv*wv[5]+bv[5],
                      (v[6]-mean)*inv*wv[6]+bv[6], (v[7]-mean)*inv*wv[7]+bv[7]);
}

// Build Vt[bh][d][k] bf16 from qkv V slice; grid (4,32), 4 chunks per block
__global__ __launch_bounds__(256)
void vt_k(const unsigned short* __restrict__ qkvb, unsigned short* __restrict__ Vt)
{
  __shared__ unsigned short tile[64][80];
  int z = blockIdx.y, b = z>>3, h = z&7;
  int t = threadIdx.x;
  int kk = t>>2, dd = (t&3)*16;
  int dd2 = t>>2, kk2 = (t&3)*16;
  for (int c = 0; c < 4; ++c){
    int k0 = (blockIdx.x*4 + c)*64;
    const unsigned short* p = qkvb + ((long)(b*1024 + k0 + kk))*1536 + 1024 + h*64 + dd;
    uint4 u0 = *(const uint4*)p, u1 = *(const uint4*)(p+8);
    __syncthreads();
    *(uint4*)&tile[kk][dd] = u0;
    *(uint4*)&tile[kk][dd+8] = u1;
    __syncthreads();
    uint4 o0, o1;
    unsigned short* s0 = (unsigned short*)&o0;
    unsigned short* s1 = (unsigned short*)&o1;
#pragma unroll
    for(int j=0;j<8;j++){ s0[j] = tile[kk2+j][dd2]; s1[j] = tile[kk2+8+j][dd2]; }
    unsigned short* o = Vt + (long)z*65536 + (long)dd2*1024 + k0 + kk2;
    *(uint4*)o = o0; *(uint4*)(o+8) = o1;
  }
}

// fp32 (R,C) -> bf16 (C,R), z-loop of ZL
__global__ __launch_bounds__(256)
void transpose_cast_k(const float* __restrict__ in, unsigned short* __restrict__ outp,
                      int R, int C, int ZL)
{
  __shared__ float tile[64][65];
  int t = threadIdx.x;
  int rr = t>>2, cc = (t&3)*16;
  int cc2 = t>>2, rr2 = (t&3)*16;
  int c0 = blockIdx.x*64, r0 = blockIdx.y*64;
  for (int zi = 0; zi < ZL; ++zi){
    long zoff = (long)(blockIdx.z*ZL + zi) * R * C;
    const float* pin = in + zoff + (long)(r0+rr)*C + c0 + cc;
    float4 v0=*(const float4*)pin, v1=*(const float4*)(pin+4), v2=*(const float4*)(pin+8), v3=*(const float4*)(pin+12);
    __syncthreads();
    tile[rr][cc+0]=v0.x; tile[rr][cc+1]=v0.y; tile[rr][cc+2]=v0.z; tile[rr][cc+3]=v0.w;
    tile[rr][cc+4]=v1.x; tile[rr][cc+5]=v1.y; tile[rr][cc+6]=v1.z; tile[rr][cc+7]=v1.w;
    tile[rr][cc+8]=v2.x; tile[rr][cc+9]=v2.y; tile[rr][cc+10]=v2.z; tile[rr][cc+11]=v2.w;
    tile[rr][cc+12]=v3.x; tile[rr][cc+13]=v3.y; tile[rr][cc+14]=v3.z; tile[rr][cc+15]=v3.w;
    __syncthreads();
    unsigned tmp[8];
#pragma unroll
    for(int jj=0;jj<8;jj++)
      tmp[jj] = pk2(tile[rr2+2*jj][cc2], tile[rr2+2*jj+1][cc2]);
    uint4* dst = (uint4*)(outp + zoff + (long)(c0+cc2)*R + r0 + rr2);
    dst[0] = make_uint4(tmp[0],tmp[1],tmp[2],tmp[3]);
    dst[1] = make_uint4(tmp[4],tmp[5],tmp[6],tmp[7]);
  }
}

// fp32 -> bf16, grid-stride
__global__ __launch_bounds__(256)
void cast_bf16_k(const float* __restrict__ in, unsigned short* __restrict__ outp, int n8)
{
  for (int i = blockIdx.x*256 + threadIdx.x; i < n8; i += gridDim.x*256){
    const float4* p = (const float4*)(in + (long)i*8);
    float4 a = p[0], b = p[1];
    *(uint4*)(outp + (long)i*8) = make_uint4(pk2(a.x,a.y), pk2(a.z,a.w), pk2(b.x,b.y), pk2(b.z,b.w));
  }
}

// masked-sum partial pooling, NO atomics: grid (4,8) -> 8 partials per batch
__global__ __launch_bounds__(256)
void pool2_k(const float* __restrict__ h, const float* __restrict__ mask, float* __restrict__ pooled)
{
  int b = blockIdx.x, sc = blockIdx.y, t = threadIdx.x;
  float a0 = 0.f, a1 = 0.f;
  const float* mb = mask + b*1024 + sc*128;
  const float* hbase = h + ((long)b*1024 + sc*128)*512;
  for (int s = 0; s < 128; ++s){
    float mk = mb[s];
    const float* r = hbase + (long)s*512;
    a0 += r[t]*mk; a1 += r[t+256]*mk;
  }
  pooled[((b*8 + sc)*512) + t] = a0;
  pooled[((b*8 + sc)*512) + t + 256] = a1;
}

__global__ __launch_bounds__(256)
void head_final_k(const float* __restrict__ pooled, const float* __restrict__ mask,
                  const float* __restrict__ pool_w, const float* __restrict__ pool_b,
                  const float* __restrict__ cls_w, const float* __restrict__ cls_b,
                  const float* __restrict__ cf_w1, const float* __restrict__ cf_b1,
                  const float* __restrict__ cf_w2, const float* __restrict__ cf_b2,
                  const float* __restrict__ aux, float* __restrict__ out)
{
  int b = blockIdx.x, t = threadIdx.x, wid = t>>6, lane = t&63;
  __shared__ __align__(16) float pld[512];
  __shared__ __align__(16) float p2[512];
  __shared__ float red[4];
  float ds = 0.f;
  for(int s=t; s<1024; s+=256) ds += mask[b*1024 + s];
  ds = wred_sum(ds);
  if (lane==0) red[wid] = ds;
  __syncthreads();
  float denom = fmaxf(red[0]+red[1]+red[2]+red[3], 1e-9f);
  float s0 = 0.f, s1 = 0.f;
#pragma unroll
  for(int sc=0;sc<8;sc++){
    s0 += pooled[((b*8+sc)*512) + t];
    s1 += pooled[((b*8+sc)*512) + t + 256];
  }
  pld[t]     = s0/denom;
  pld[t+256] = s1/denom;
  __syncthreads();
#pragma unroll
  for(int jj=0;jj<2;jj++){
    int j = t + jj*256;
    const float4* wr = (const float4*)(pool_w + (long)j*512);
    float acc = 0.f;
    for(int i=0;i<128;i++){
      float4 w4 = wr[i]; float4 x4 = ((const float4*)pld)[i];
      acc += w4.x*x4.x + w4.y*x4.y + w4.z*x4.z + w4.w*x4.w;
    }
    p2[j] = tanhf(acc + pool_b[j]);
  }
  __syncthreads();
  if (t < 4){
    const float4* wr = (const float4*)(cls_w + (long)t*512);
    float acc = 0.f;
    for(int i=0;i<128;i++){
      float4 w4 = wr[i]; float4 x4 = ((const float4*)p2)[i];
      acc += w4.x*x4.x + w4.y*x4.y + w4.z*x4.z + w4.w*x4.w;
    }
    out[b*4 + t] = acc + cls_b[t];
  }
  {
    const float4* wr = (const float4*)(cf_w1 + (long)t*512);
    float acc = 0.f;
    for(int i=0;i<128;i++){
      float4 w4 = wr[i]; float4 x4 = ((const float4*)p2)[i];
      acc += w4.x*x4.x + w4.y*x4.y + w4.z*x4.z + w4.w*x4.w;
    }
    acc = fmaxf(acc + cf_b1[t], 0.f) * cf_w2[t];
    acc = wred_sum(acc);
    __syncthreads();
    if (lane==0) red[wid] = acc;
    __syncthreads();
    if (t == 0){
      float sum = red[0]+red[1]+red[2]+red[3];
      out[17 + b] = 1.f/(1.f + expf(-(sum + cf_b2[0])));
    }
  }
  if (b == 0 && t == 0) out[16] = aux[0]*0.25f;
}

// ---------------------------------------------------------------------------
extern "C" void kernel_launch(void* const* d_in, const int* in_sizes, int n_in,
                              void* d_out, int out_size, void* d_ws, size_t ws_size,
                              hipStream_t stream)
{
  (void)in_sizes; (void)n_in; (void)out_size;
  const float* emb    = (const float*)d_in[0];
  const float* mask   = (const float*)d_in[1];
  const float* in_w   = (const float*)d_in[2];
  const float* in_b   = (const float*)d_in[3];
  const float* out_w  = (const float*)d_in[4];
  const float* out_b  = (const float*)d_in[5];
  const float* ln1_w  = (const float*)d_in[6];
  const float* ln1_b  = (const float*)d_in[7];
  const float* ln2_w  = (const float*)d_in[8];
  const float* ln2_b  = (const float*)d_in[9];
  const float* gate_w = (const float*)d_in[10];
  const float* e_w1   = (const float*)d_in[11];
  const float* e_b1   = (const float*)d_in[12];
  const float* e_w2   = (const float*)d_in[13];
  const float* e_b2   = (const float*)d_in[14];
  const float* mln_w  = (const float*)d_in[15];
  const float* mln_b  = (const float*)d_in[16];
  const float* fln_w  = (const float*)d_in[17];
  const float* fln_b  = (const float*)d_in[18];
  const float* pool_w = (const float*)d_in[19];
  const float* pool_b = (const float*)d_in[20];
  const float* cls_w  = (const float*)d_in[21];
  const float* cls_b  = (const float*)d_in[22];
  const float* cf_w1  = (const float*)d_in[23];
  const float* cf_b1  = (const float*)d_in[24];
  const float* cf_w2  = (const float*)d_in[25];
  const float* cf_b2  = (const float*)d_in[26];
  float* out = (float*)d_out;
  char* ws = (char*)d_ws;

  const size_t MiB = 1024*1024;
  if (ws_size < 218*MiB) return;

  // Workspace layout
  float*          x     = (float*)(ws + 0*MiB);             // 8 MiB fp32
  unsigned short* hb    = (unsigned short*)(ws + 8*MiB);    // 4 MiB bf16
  unsigned short* qkvb  = (unsigned short*)(ws + 12*MiB);   // 12 MiB bf16
  unsigned short* ctx   = (unsigned short*)(ws + 24*MiB);   // 4 MiB bf16
  unsigned short* Vt    = (unsigned short*)(ws + 28*MiB);   // 4 MiB bf16
  unsigned short* mid   = (unsigned short*)(ws + 32*MiB);   // 32 MiB bf16
  float*          eout  = (float*)(ws + 64*MiB);            // 16 MiB fp32
  float*          fout  = (float*)(ws + 64*MiB);            //   (reuse, head)
  unsigned short* w1t   = (unsigned short*)(ws + 80*MiB);   // 64 MiB bf16
  unsigned short* w2t   = (unsigned short*)(ws + 144*MiB);  // 64 MiB bf16
  unsigned short* inwb  = (unsigned short*)(ws + 208*MiB);  // 6 MiB bf16
  unsigned short* outwb = (unsigned short*)(ws + 214*MiB);  // 2 MiB bf16
  char* misc = ws + 216*MiB;
  int*   counts  = (int*)(misc + 0);
  int*   offs    = (int*)(misc + 64);
  float* aux     = (float*)(misc + 128);
  int*   btab    = (int*)(misc + 256);
  float* pooled  = (float*)(misc + 4096);      // 64 KiB (4*8*512 floats)
  int*   tok_e   = (int*)(misc + 81920);       // 32 KiB
  float* tok_w   = (float*)(misc + 114688);    // 32 KiB
  int*   rowtok  = (int*)(misc + 147456);      // 32 KiB
  float* roww    = (float*)(misc + 180224);    // 32 KiB
  int*   rowof   = (int*)(misc + 212992);      // 32 KiB

  hipMemcpyAsync(x, emb, (size_t)T_*D_*4, hipMemcpyDeviceToDevice, stream);
  hipMemsetAsync(aux, 0, 4, stream);
  // weight prep
  cast_bf16_k<<<512, 256, 0, stream>>>(in_w, inwb, L_*3*D_*D_/8);
  cast_bf16_k<<<256, 256, 0, stream>>>(out_w, outwb, L_*D_*D_/8);
  transpose_cast_k<<<dim3(I_/64, D_/64, 4), 256, 0, stream>>>(e_w1, w1t, D_, I_, 8);
  transpose_cast_k<<<dim3(D_/64, I_/64, 4), 256, 0, stream>>>(e_w2, w2t, I_, D_, 8);

  for (int l=0; l<L_; l++){
    const float* inbl  = in_b  + (size_t)l*3*D_;
    const float* outbl = out_b + (size_t)l*D_;
    const float* gwl   = gate_w + (size_t)l*E_*D_;
    const float* eb1l  = e_b1 + (size_t)l*E_*I_;
    const float* eb2l  = e_b2 + (size_t)l*E_*D_;
    const unsigned short* inwbl  = inwb + (size_t)l*3*D_*D_;
    const unsigned short* outwbl = outwb + (size_t)l*D_*D_;
    const unsigned short* w1tl = w1t + (size_t)l*E_*I_*D_;
    const unsigned short* w2tl = w2t + (size_t)l*E_*D_*I_;

    // h = LN1(x) -> bf16
    ln_w_k<true><<<T_/4, 256, 0, stream>>>(x, ln1_w + (size_t)l*D_, ln1_b + (size_t)l*D_, hb);
    // qkv = h @ in_w^T + in_b -> bf16
    gemm2_k<128,false,false,true,0,false><<<dim3(32,12,1), 256, 0, stream>>>(
      hb, inwbl, qkvb, inbl, nullptr, T_, 3*D_, D_, D_, D_, 3*D_,
      1, 0,0,0,0,0,0, 1.f, nullptr, nullptr, nullptr, nullptr, 0, 0);
    vt_k<<<dim3(4,32), 256, 0, stream>>>(qkvb, Vt);
    // fused attention -> ctx (B,S,512) bf16
    flash_k<<<dim3(16,32), 256, 0, stream>>>(qkvb, Vt, ctx);
    // x = x + ctx @ out_w^T + out_b  (fp32)
    gemm2_k<128,false,false,false,0,true><<<dim3(32,4,1), 256, 0, stream>>>(
      ctx, outwbl, x, outbl, x, T_, D_, D_, D_, D_, D_,
      1, 0,0,0,0,0,0, 1.f, nullptr, nullptr, nullptr, nullptr, 0, 0);
    // h2 = LN2(x) -> bf16, + routing (no atomics)
    ln2route_k<<<T_/4, 256, 0, stream>>>(x, ln2_w + (size_t)l*D_, ln2_b + (size_t)l*D_,
                                         hb, gwl, tok_e, tok_w);
    // plan + scatter, single block, LDS atomics only
    plan_scatter_k<<<1, 1024, 0, stream>>>(tok_e, tok_w, offs, counts, aux, btab,
                                           rowtok, roww, rowof);
    // FFN1: mid = gelu(gather(h2) @ w1^T + b1) -> bf16
    gemm2_k<128,true,true,true,1,false><<<dim3(71,16,1), 256, 0, stream>>>(
      hb, w1tl, mid, eb1l, nullptr, 2*T_, I_, D_, D_, D_, I_,
      1, 0,0,0,0,0,0, 1.f, offs, counts, rowtok, btab, (long)I_*D_, I_);
    // FFN2: eout = mid @ w2^T + b2 -> fp32
    gemm2_k<128,true,false,false,0,false><<<dim3(71,4,1), 256, 0, stream>>>(
      mid, w2tl, eout, eb2l, nullptr, 2*T_, D_, I_, I_, I_, D_,
      1, 0,0,0,0,0,0, 1.f, offs, counts, nullptr, btab, (long)D_*I_, D_);
    // x = LN(h2 + combine(eout))
    ln_moe_k<<<T_/4, 256, 0, stream>>>(eout, rowof, roww, mask, hb,
                                       mln_w + (size_t)l*D_, mln_b + (size_t)l*D_, x);
  }
  // head
  ln_w_k<false><<<T_/4, 256, 0, stream>>>(x, fln_w, fln_b, fout);
  pool2_k<<<dim3(4,8), 256, 0, stream>>>(fout, mask, pooled);
  head_final_k<<<4, 256, 0, stream>>>(pooled, mask, pool_w, pool_b, cls_w, cls_b,
                                      cf_w1, cf_b1, cf_w2, cf_b2, aux, out);
}

// Round 6
// 1508.522 us; speedup vs baseline: 2.2431x; 1.0588x over previous
//
#include <hip/hip_runtime.h>
#include <math.h>

// Problem constants
#define B_ 4
#define S_ 1024
#define D_ 512
#define H_ 8
#define DH_ 64
#define I_ 2048
#define E_ 8
#define L_ 4
#define T_ 4096   // B*S

using bf16x8 = __attribute__((ext_vector_type(8))) __bf16;
using f32x4  = __attribute__((ext_vector_type(4))) float;

typedef __attribute__((address_space(1))) const void gvoid;
typedef __attribute__((address_space(3))) void lvoid;
__device__ __forceinline__ void gl_lds16(const void* g, void* l){
  __builtin_amdgcn_global_load_lds((gvoid*)g, (lvoid*)l, 16, 0, 0);
}

__device__ __forceinline__ float wred_sum(float v){
#pragma unroll
  for(int m=32;m>0;m>>=1) v += __shfl_xor(v, m, 64);
  return v;
}
__device__ __forceinline__ unsigned short f2bf(float f){
  unsigned x = __float_as_uint(f);
  unsigned r = (x + 0x7FFFu + ((x>>16)&1u)) >> 16;
  return (unsigned short)r;
}
__device__ __forceinline__ float bf2f(unsigned short u){
  return __uint_as_float(((unsigned)u)<<16);
}
__device__ __forceinline__ unsigned pk2(float a, float b){
  return (unsigned)f2bf(a) | ((unsigned)f2bf(b)<<16);
}

// ---------------------------------------------------------------------------
// bf16 MFMA GEMM. NT: C[m,n] = sum_k A[m,k]*B[n,k].
// BK=64: 2 MFMA k-substeps per barrier pair (double arithmetic density vs
// BK=32). global_load_lds width-16 staging, single LDS buffer.
// 4 waves in 2x2. BM in {64,128}, BN in {64,128}.
// MOE: block table btab[bx] = (e<<8)|mblk, -1 = dead. Optional row gather.
// ---------------------------------------------------------------------------
template<int BM, int BN, bool MOE, bool GATHER, bool OUT_BF16, int ACT, bool ADD_IN>
__global__ __launch_bounds__(256)
void gemm_k(const unsigned short* __restrict__ A, const unsigned short* __restrict__ Bv,
            void* Cp, const float* __restrict__ bias, const float* addin,
            int M, int N, int K, int lda, int ldb, int ldc,
            int hdiv, long sAb, long sAh, long sBb, long sBh, long sCb, long sCh,
            float scale,
            const int* __restrict__ moff, const int* __restrict__ mcnt,
            const int* __restrict__ rowtok, const int* __restrict__ btab,
            long sBe, int biasStride)
{
  constexpr int BK = 64;
  constexpr int WM = BM/2, WN = BN/2, FM = WM/16, FNN = WN/16;
  constexpr int RPC = 2048/BK;       // rows covered per block-wide gl_lds16 call
  constexpr int NA = BM/RPC, NB = BN/RPC;
  __shared__ unsigned short As[BM*BK];
  __shared__ unsigned short Bs[BN*BK];

  const int tid = threadIdx.x, wid = tid>>6, lane = tid&63;
  const int wy = wid>>1, wx = wid&1, ln16 = lane&15, q8 = (lane>>4)*8;
  int m0 = blockIdx.x*BM;
  const int n0 = blockIdx.y*BN;

  float* Cf = nullptr; unsigned short* Ch = nullptr;
  const float* biasp = bias;
  const unsigned short* Bp = Bv;
  int seg = 0, cnt = M;

  if constexpr (MOE){
    int tv = btab[blockIdx.x];
    if (tv < 0) return;
    int e = tv>>8;
    m0 = (tv&255)*BM;
    seg = moff[e]; cnt = mcnt[e];
    Bp = Bv + (long)e*sBe;
    if constexpr (OUT_BF16) Ch = (unsigned short*)Cp; else Cf = (float*)Cp;
    if (biasp) biasp += (long)e*biasStride;
  } else {
    int z = blockIdx.z, zb = z/hdiv, zh = z%hdiv;
    A  += (long)zb*sAb + (long)zh*sAh;
    Bp += (long)zb*sBb + (long)zh*sBh;
    long coff = (long)zb*sCb + (long)zh*sCh;
    if constexpr (OUT_BF16) Ch = (unsigned short*)Cp + coff; else Cf = ((float*)Cp) + coff;
    if constexpr (ADD_IN) addin += coff;
  }

  // staging geometry: call j covers rows j*RPC + tid/(BK/8), col (tid%(BK/8))*8
  const int srow = tid >> 3;          // BK/8 = 8 lanes per row
  const int scol = (tid & 7) * 8;
  long ga[NA], gb[NB];
#pragma unroll
  for (int j=0; j<NA; j++){
    int r = m0 + j*RPC + srow;
    if constexpr (MOE){
      r = min(r, cnt-1);
      long gr = GATHER ? (long)rowtok[seg+r] : (long)(seg+r);
      ga[j] = gr*lda + scol;
    } else {
      ga[j] = (long)min(r, M-1)*lda + scol;
    }
  }
#pragma unroll
  for (int j=0; j<NB; j++){
    int bn = min(n0 + j*RPC + srow, N-1);
    gb[j] = (long)bn*ldb + scol;
  }

  f32x4 acc[FM][FNN];
#pragma unroll
  for(int i=0;i<FM;i++)
#pragma unroll
    for(int j=0;j<FNN;j++){ f32x4 z = {0.f,0.f,0.f,0.f}; acc[i][j] = z; }

  for (int k0 = 0; k0 < K; k0 += BK){
    __syncthreads();
#pragma unroll
    for (int j=0; j<NA; j++) gl_lds16(A + ga[j] + k0, As + j*2048 + wid*512);
#pragma unroll
    for (int j=0; j<NB; j++) gl_lds16(Bp + gb[j] + k0, Bs + j*2048 + wid*512);
    __syncthreads();
#pragma unroll
    for (int kk=0; kk<2; kk++){
      bf16x8 fa[FM], fb[FNN];
#pragma unroll
      for(int i=0;i<FM;i++) fa[i] = *(const bf16x8*)&As[(wy*WM + i*16 + ln16)*BK + kk*32 + q8];
#pragma unroll
      for(int j=0;j<FNN;j++) fb[j] = *(const bf16x8*)&Bs[(wx*WN + j*16 + ln16)*BK + kk*32 + q8];
#pragma unroll
      for(int i=0;i<FM;i++)
#pragma unroll
        for(int j=0;j<FNN;j++)
          acc[i][j] = __builtin_amdgcn_mfma_f32_16x16x32_bf16(fa[i], fb[j], acc[i][j], 0, 0, 0);
    }
  }

  // epilogue: C[m = quad*4+r][n = lane&15]
#pragma unroll
  for(int i=0;i<FM;i++){
    int mbase = m0 + wy*WM + i*16 + (lane>>4)*4;
#pragma unroll
    for(int j=0;j<FNN;j++){
      int n = n0 + wx*WN + j*16 + ln16;
      float bv = biasp ? biasp[n] : 0.f;
      f32x4 v = acc[i][j];
#pragma unroll
      for(int r=0;r<4;r++){
        int m = mbase + r;
        if (m < cnt){
          float x = v[r]*scale + bv;
          if constexpr (ACT == 1) x = 0.5f*x*(1.f + erff(x*0.70710678118654752f));
          long ci = (long)(MOE ? seg + m : m)*ldc + n;
          if constexpr (ADD_IN) x += addin[ci];
          if constexpr (OUT_BF16) Ch[ci] = f2bf(x);
          else Cf[ci] = x;
        }
      }
    }
  }
}

// ---------------------------------------------------------------------------
// Fused flash attention. grid (S/64, B*H). 4 waves, each owns 16 Q-rows.
// ---------------------------------------------------------------------------
__global__ __launch_bounds__(256)
void flash_k(const unsigned short* __restrict__ qkvb, const unsigned short* __restrict__ Vt,
             unsigned short* __restrict__ ctx)
{
  __shared__ unsigned short Pl[4][16*72];
  const int qt = blockIdx.x, z = blockIdx.y, b = z>>3, h = z&7;
  const int wid = threadIdx.x>>6, lane = threadIdx.x&63;
  const int ln16 = lane&15, g = lane>>4;
  const int q0 = qt*64 + wid*16;
  unsigned short* Pw = &Pl[wid][0];

  const unsigned short* Qp = qkvb + (long)(b*1024 + q0 + ln16)*1536 + h*64 + g*8;
  bf16x8 qf0 = *(const bf16x8*)Qp;
  bf16x8 qf1 = *(const bf16x8*)(Qp + 32);
  const unsigned short* Kbase = qkvb + (long)b*1024*1536 + 512 + h*64 + g*8;
  const unsigned short* Vbase = Vt + (long)z*65536 + g*8;

  float m_s[4], l_s[4];
  f32x4 oacc[4];
#pragma unroll
  for(int r=0;r<4;r++){ m_s[r] = -1e30f; l_s[r] = 0.f; }
#pragma unroll
  for(int j=0;j<4;j++){ f32x4 zz = {0.f,0.f,0.f,0.f}; oacc[j] = zz; }

  for (int t = 0; t < 16; ++t){
    bf16x8 kf[4][2], vf[4][2];
#pragma unroll
    for(int j=0;j<4;j++){
      const unsigned short* kp = Kbase + (long)(t*64 + j*16 + ln16)*1536;
      kf[j][0] = *(const bf16x8*)kp;
      kf[j][1] = *(const bf16x8*)(kp + 32);
      const unsigned short* vp = Vbase + (long)(j*16 + ln16)*1024 + t*64;
      vf[j][0] = *(const bf16x8*)vp;
      vf[j][1] = *(const bf16x8*)(vp + 32);
    }
    f32x4 sacc[4];
#pragma unroll
    for(int j=0;j<4;j++){ f32x4 zz = {0.f,0.f,0.f,0.f}; sacc[j] = zz; }
#pragma unroll
    for(int j=0;j<4;j++){
      sacc[j] = __builtin_amdgcn_mfma_f32_16x16x32_bf16(qf0, kf[j][0], sacc[j], 0,0,0);
      sacc[j] = __builtin_amdgcn_mfma_f32_16x16x32_bf16(qf1, kf[j][1], sacc[j], 0,0,0);
    }
#pragma unroll
    for(int j=0;j<4;j++)
#pragma unroll
      for(int r=0;r<4;r++) sacc[j][r] *= 0.125f;
    float alpha[4];
#pragma unroll
    for(int r=0;r<4;r++){
      float mx = fmaxf(fmaxf(sacc[0][r], sacc[1][r]), fmaxf(sacc[2][r], sacc[3][r]));
#pragma unroll
      for(int m=1;m<16;m<<=1) mx = fmaxf(mx, __shfl_xor(mx, m, 64));
      float mn = fmaxf(m_s[r], mx);
      alpha[r] = __expf(m_s[r] - mn);
      m_s[r] = mn;
    }
#pragma unroll
    for(int j=0;j<4;j++)
#pragma unroll
      for(int r=0;r<4;r++) sacc[j][r] = __expf(sacc[j][r] - m_s[r]);
#pragma unroll
    for(int r=0;r<4;r++){
      float rs = sacc[0][r]+sacc[1][r]+sacc[2][r]+sacc[3][r];
#pragma unroll
      for(int m=1;m<16;m<<=1) rs += __shfl_xor(rs, m, 64);
      l_s[r] = l_s[r]*alpha[r] + rs;
    }
#pragma unroll
    for(int j=0;j<4;j++)
#pragma unroll
      for(int r=0;r<4;r++) oacc[j][r] *= alpha[r];
#pragma unroll
    for(int j=0;j<4;j++)
#pragma unroll
      for(int r=0;r<4;r++)
        Pw[(g*4+r)*72 + j*16 + ln16] = f2bf(sacc[j][r]);
    bf16x8 pf0 = *(const bf16x8*)&Pw[ln16*72 + g*8];
    bf16x8 pf1 = *(const bf16x8*)&Pw[ln16*72 + 32 + g*8];
#pragma unroll
    for(int j=0;j<4;j++){
      oacc[j] = __builtin_amdgcn_mfma_f32_16x16x32_bf16(pf0, vf[j][0], oacc[j], 0,0,0);
      oacc[j] = __builtin_amdgcn_mfma_f32_16x16x32_bf16(pf1, vf[j][1], oacc[j], 0,0,0);
    }
  }
#pragma unroll
  for(int r=0;r<4;r++){
    float inv = 1.f/l_s[r];
    long row = (long)(b*1024 + q0 + g*4 + r)*512 + h*64;
#pragma unroll
    for(int j=0;j<4;j++)
      ctx[row + j*16 + ln16] = f2bf(oacc[j][r]*inv);
  }
}

// ---------------------------------------------------------------------------
// Wave-per-row LayerNorm (D=512): 4 rows/block, no barriers.
// ---------------------------------------------------------------------------
template<bool OUT_BF16>
__global__ __launch_bounds__(256)
void ln_w_k(const float* __restrict__ in, const float* __restrict__ w,
            const float* __restrict__ bb, void* __restrict__ outp)
{
  int row = blockIdx.x*4 + (threadIdx.x>>6), lane = threadIdx.x&63;
  const float4* p = (const float4*)(in + (long)row*512 + lane*8);
  float4 a = p[0], c = p[1];
  float s = a.x+a.y+a.z+a.w + c.x+c.y+c.z+c.w;
  float q = a.x*a.x+a.y*a.y+a.z*a.z+a.w*a.w + c.x*c.x+c.y*c.y+c.z*c.z+c.w*c.w;
  s = wred_sum(s); q = wred_sum(q);
  float mean = s*(1.f/512.f);
  float var  = q*(1.f/512.f) - mean*mean;
  float inv  = rsqrtf(var + 1e-5f);
  const float4* wp = (const float4*)(w + lane*8);
  const float4* bp = (const float4*)(bb + lane*8);
  float4 w0 = wp[0], w1 = wp[1], b0 = bp[0], b1 = bp[1];
  float o0 = (a.x-mean)*inv*w0.x + b0.x, o1 = (a.y-mean)*inv*w0.y + b0.y;
  float o2 = (a.z-mean)*inv*w0.z + b0.z, o3 = (a.w-mean)*inv*w0.w + b0.w;
  float o4 = (c.x-mean)*inv*w1.x + b1.x, o5 = (c.y-mean)*inv*w1.y + b1.y;
  float o6 = (c.z-mean)*inv*w1.z + b1.z, o7 = (c.w-mean)*inv*w1.w + b1.w;
  if constexpr (OUT_BF16){
    *(uint4*)((unsigned short*)outp + (long)row*512 + lane*8) =
      make_uint4(pk2(o0,o1), pk2(o2,o3), pk2(o4,o5), pk2(o6,o7));
  } else {
    float4* op = (float4*)((float*)outp + (long)row*512 + lane*8);
    op[0] = make_float4(o0,o1,o2,o3);
    op[1] = make_float4(o4,o5,o6,o7);
  }
}

// LN2 + router fused: h2 = LN(x) (bf16 out) then top-2 gate; NO global atomics.
__global__ __launch_bounds__(256)
void ln2route_k(const float* __restrict__ in, const float* __restrict__ w,
                const float* __restrict__ bb, unsigned short* __restrict__ h2,
                const float* __restrict__ gw,
                int* __restrict__ tok_e, float* __restrict__ tok_w)
{
  int tok = blockIdx.x*4 + (threadIdx.x>>6), lane = threadIdx.x&63;
  const float4* p = (const float4*)(in + (long)tok*512 + lane*8);
  float4 a = p[0], c = p[1];
  float s = a.x+a.y+a.z+a.w + c.x+c.y+c.z+c.w;
  float q = a.x*a.x+a.y*a.y+a.z*a.z+a.w*a.w + c.x*c.x+c.y*c.y+c.z*c.z+c.w*c.w;
  s = wred_sum(s); q = wred_sum(q);
  float mean = s*(1.f/512.f);
  float var  = q*(1.f/512.f) - mean*mean;
  float inv  = rsqrtf(var + 1e-5f);
  const float4* wp = (const float4*)(w + lane*8);
  const float4* bp = (const float4*)(bb + lane*8);
  float4 w0 = wp[0], w1 = wp[1], b0 = bp[0], b1 = bp[1];
  float o[8];
  o[0] = (a.x-mean)*inv*w0.x + b0.x; o[1] = (a.y-mean)*inv*w0.y + b0.y;
  o[2] = (a.z-mean)*inv*w0.z + b0.z; o[3] = (a.w-mean)*inv*w0.w + b0.w;
  o[4] = (c.x-mean)*inv*w1.x + b1.x; o[5] = (c.y-mean)*inv*w1.y + b1.y;
  o[6] = (c.z-mean)*inv*w1.z + b1.z; o[7] = (c.w-mean)*inv*w1.w + b1.w;
  *(uint4*)(h2 + (long)tok*512 + lane*8) =
    make_uint4(pk2(o[0],o[1]), pk2(o[2],o[3]), pk2(o[4],o[5]), pk2(o[6],o[7]));
  float lg[8];
#pragma unroll
  for(int e=0;e<8;e++){
    const float4* gr = (const float4*)(gw + e*512 + lane*8);
    float4 g0 = gr[0], g1 = gr[1];
    float d = o[0]*g0.x + o[1]*g0.y + o[2]*g0.z + o[3]*g0.w
            + o[4]*g1.x + o[5]*g1.y + o[6]*g1.z + o[7]*g1.w;
    lg[e] = wred_sum(d);
  }
  if (lane == 0){
    float mx = lg[0];
#pragma unroll
    for(int e=1;e<8;e++) mx = fmaxf(mx, lg[e]);
    float pr[8];
#pragma unroll
    for(int e=0;e<8;e++) pr[e] = expf(lg[e]-mx);
    int e0 = 0; float p0 = pr[0];
#pragma unroll
    for(int e=1;e<8;e++) if (pr[e] > p0){ p0 = pr[e]; e0 = e; }
    int e1 = -1; float p1 = -1.f;
#pragma unroll
    for(int e=0;e<8;e++) if (e != e0 && pr[e] > p1){ p1 = pr[e]; e1 = e; }
    float invp = 1.f/(p0+p1);
    tok_e[2*tok] = e0; tok_e[2*tok+1] = e1;
    tok_w[2*tok] = p0*invp; tok_w[2*tok+1] = p1*invp;
  }
}

// ---------------------------------------------------------------------------
// Single-block planner + scatter: LDS-atomic histogram, offsets, two block
// tables (BM=128 for FFN1, BM=64 for FFN2), aux, and compaction scatter.
// ---------------------------------------------------------------------------
__global__ __launch_bounds__(1024)
void plan_scatter_k(const int* __restrict__ tok_e, const float* __restrict__ tok_w,
                    int* __restrict__ offs, int* __restrict__ cnts, float* __restrict__ aux,
                    int* __restrict__ btab, int* __restrict__ btab64,
                    int* __restrict__ rowtok, float* __restrict__ roww, int* __restrict__ rowof)
{
  __shared__ int hist[8];
  __shared__ int offsS[8];
  __shared__ int base[8];
  const int t = threadIdx.x;
  if (t < 8) hist[t] = 0;
  __syncthreads();
  int e[8]; float w[8];
#pragma unroll
  for (int i=0;i<8;i++){
    e[i] = tok_e[t + i*1024];
    w[i] = tok_w[t + i*1024];
    atomicAdd(&hist[e[i]], 1);
  }
  __syncthreads();
  if (t == 0){
    int o = 0, idx = 0, idx2 = 0; float a = 0.f;
    for (int ee=0; ee<8; ee++){
      offsS[ee] = o;
      int c = hist[ee];
      o += c;
      float u = (float)c*(1.f/4096.f) - 0.125f;
      a += u*u;
      int nb = (c + 127) >> 7;
      for (int j=0;j<nb;j++) btab[idx++] = (ee<<8)|j;
      int nb2 = (c + 63) >> 6;
      for (int j=0;j<nb2;j++) btab64[idx2++] = (ee<<8)|j;
    }
    while (idx < 80) btab[idx++] = -1;
    while (idx2 < 144) btab64[idx2++] = -1;
    *aux += a*(1.f/8.f);
  }
  __syncthreads();
  if (t < 8){
    cnts[t] = hist[t];
    offs[t] = offsS[t];
    base[t] = offsS[t];
  }
  __syncthreads();
#pragma unroll
  for (int i=0;i<8;i++){
    int pos = atomicAdd(&base[e[i]], 1);   // LDS atomic
    int gi = t + i*1024;
    rowtok[pos] = gi>>1;
    roww[pos] = w[i];
    rowof[gi] = pos;
  }
}

// Fused MoE combine + LN, wave per token
__global__ __launch_bounds__(256)
void ln_moe_k(const float* __restrict__ eout, const int* __restrict__ rowof,
              const float* __restrict__ roww, const float* __restrict__ mask,
              const unsigned short* __restrict__ h2,
              const float* __restrict__ w, const float* __restrict__ bb,
              float* __restrict__ outp)
{
  int tok = blockIdx.x*4 + (threadIdx.x>>6), lane = threadIdx.x&63;
  int r0 = rowof[2*tok], r1 = rowof[2*tok+1];
  float w0w = roww[r0], w1w = roww[r1], mk = mask[tok];
  const float4* ap = (const float4*)(eout + (long)r0*512 + lane*8);
  const float4* bp2 = (const float4*)(eout + (long)r1*512 + lane*8);
  float4 a0 = ap[0], a1 = ap[1], c0 = bp2[0], c1 = bp2[1];
  uint4 hu = *(const uint4*)(h2 + (long)tok*512 + lane*8);
  const unsigned short* hh = (const unsigned short*)&hu;
  float v[8];
  v[0] = bf2f(hh[0]) + (a0.x*w0w + c0.x*w1w)*mk;
  v[1] = bf2f(hh[1]) + (a0.y*w0w + c0.y*w1w)*mk;
  v[2] = bf2f(hh[2]) + (a0.z*w0w + c0.z*w1w)*mk;
  v[3] = bf2f(hh[3]) + (a0.w*w0w + c0.w*w1w)*mk;
  v[4] = bf2f(hh[4]) + (a1.x*w0w + c1.x*w1w)*mk;
  v[5] = bf2f(hh[5]) + (a1.y*w0w + c1.y*w1w)*mk;
  v[6] = bf2f(hh[6]) + (a1.z*w0w + c1.z*w1w)*mk;
  v[7] = bf2f(hh[7]) + (a1.w*w0w + c1.w*w1w)*mk;
  float s = 0.f, q = 0.f;
#pragma unroll
  for(int i=0;i<8;i++){ s += v[i]; q += v[i]*v[i]; }
  s = wred_sum(s); q = wred_sum(q);
  float mean = s*(1.f/512.f);
  float var  = q*(1.f/512.f) - mean*mean;
  float inv  = rsqrtf(var + 1e-5f);
  const float4* wp = (const float4*)(w + lane*8);
  const float4* bpp = (const float4*)(bb + lane*8);
  float4 w0 = wp[0], w1 = wp[1], b0 = bpp[0], b1 = bpp[1];
  float wv[8] = {w0.x,w0.y,w0.z,w0.w,w1.x,w1.y,w1.z,w1.w};
  float bv[8] = {b0.x,b0.y,b0.z,b0.w,b1.x,b1.y,b1.z,b1.w};
  float4* op = (float4*)(outp + (long)tok*512 + lane*8);
  op[0] = make_float4((v[0]-mean)*inv*wv[0]+bv[0], (v[1]-mean)*inv*wv[1]+bv[1],
                      (v[2]-mean)*inv*wv[2]+bv[2], (v[3]-mean)*inv*wv[3]+bv[3]);
  op[1] = make_float4((v[4]-mean)*inv*wv[4]+bv[4], (v[5]-mean)*inv*wv[5]+bv[5],
                      (v[6]-mean)*inv*wv[6]+bv[6], (v[7]-mean)*inv*wv[7]+bv[7]);
}

// Build Vt[bh][d][k] bf16 from qkv V slice; grid (4,32), 4 chunks per block
__global__ __launch_bounds__(256)
void vt_k(const unsigned short* __restrict__ qkvb, unsigned short* __restrict__ Vt)
{
  __shared__ unsigned short tile[64][80];
  int z = blockIdx.y, b = z>>3, h = z&7;
  int t = threadIdx.x;
  int kk = t>>2, dd = (t&3)*16;
  int dd2 = t>>2, kk2 = (t&3)*16;
  for (int c = 0; c < 4; ++c){
    int k0 = (blockIdx.x*4 + c)*64;
    const unsigned short* p = qkvb + ((long)(b*1024 + k0 + kk))*1536 + 1024 + h*64 + dd;
    uint4 u0 = *(const uint4*)p, u1 = *(const uint4*)(p+8);
    __syncthreads();
    *(uint4*)&tile[kk][dd] = u0;
    *(uint4*)&tile[kk][dd+8] = u1;
    __syncthreads();
    uint4 o0, o1;
    unsigned short* s0 = (unsigned short*)&o0;
    unsigned short* s1 = (unsigned short*)&o1;
#pragma unroll
    for(int j=0;j<8;j++){ s0[j] = tile[kk2+j][dd2]; s1[j] = tile[kk2+8+j][dd2]; }
    unsigned short* o = Vt + (long)z*65536 + (long)dd2*1024 + k0 + kk2;
    *(uint4*)o = o0; *(uint4*)(o+8) = o1;
  }
}

// fp32 (R,C) -> bf16 (C,R), z-loop of ZL
__global__ __launch_bounds__(256)
void transpose_cast_k(const float* __restrict__ in, unsigned short* __restrict__ outp,
                      int R, int C, int ZL)
{
  __shared__ float tile[64][65];
  int t = threadIdx.x;
  int rr = t>>2, cc = (t&3)*16;
  int cc2 = t>>2, rr2 = (t&3)*16;
  int c0 = blockIdx.x*64, r0 = blockIdx.y*64;
  for (int zi = 0; zi < ZL; ++zi){
    long zoff = (long)(blockIdx.z*ZL + zi) * R * C;
    const float* pin = in + zoff + (long)(r0+rr)*C + c0 + cc;
    float4 v0=*(const float4*)pin, v1=*(const float4*)(pin+4), v2=*(const float4*)(pin+8), v3=*(const float4*)(pin+12);
    __syncthreads();
    tile[rr][cc+0]=v0.x; tile[rr][cc+1]=v0.y; tile[rr][cc+2]=v0.z; tile[rr][cc+3]=v0.w;
    tile[rr][cc+4]=v1.x; tile[rr][cc+5]=v1.y; tile[rr][cc+6]=v1.z; tile[rr][cc+7]=v1.w;
    tile[rr][cc+8]=v2.x; tile[rr][cc+9]=v2.y; tile[rr][cc+10]=v2.z; tile[rr][cc+11]=v2.w;
    tile[rr][cc+12]=v3.x; tile[rr][cc+13]=v3.y; tile[rr][cc+14]=v3.z; tile[rr][cc+15]=v3.w;
    __syncthreads();
    unsigned tmp[8];
#pragma unroll
    for(int jj=0;jj<8;jj++)
      tmp[jj] = pk2(tile[rr2+2*jj][cc2], tile[rr2+2*jj+1][cc2]);
    uint4* dst = (uint4*)(outp + zoff + (long)(c0+cc2)*R + r0 + rr2);
    dst[0] = make_uint4(tmp[0],tmp[1],tmp[2],tmp[3]);
    dst[1] = make_uint4(tmp[4],tmp[5],tmp[6],tmp[7]);
  }
}

// fp32 -> bf16, grid-stride
__global__ __launch_bounds__(256)
void cast_bf16_k(const float* __restrict__ in, unsigned short* __restrict__ outp, int n8)
{
  for (int i = blockIdx.x*256 + threadIdx.x; i < n8; i += gridDim.x*256){
    const float4* p = (const float4*)(in + (long)i*8);
    float4 a = p[0], b = p[1];
    *(uint4*)(outp + (long)i*8) = make_uint4(pk2(a.x,a.y), pk2(a.z,a.w), pk2(b.x,b.y), pk2(b.z,b.w));
  }
}

// masked-sum partial pooling, NO atomics: grid (4,8) -> 8 partials per batch
__global__ __launch_bounds__(256)
void pool2_k(const float* __restrict__ h, const float* __restrict__ mask, float* __restrict__ pooled)
{
  int b = blockIdx.x, sc = blockIdx.y, t = threadIdx.x;
  float a0 = 0.f, a1 = 0.f;
  const float* mb = mask + b*1024 + sc*128;
  const float* hbase = h + ((long)b*1024 + sc*128)*512;
  for (int s = 0; s < 128; ++s){
    float mk = mb[s];
    const float* r = hbase + (long)s*512;
    a0 += r[t]*mk; a1 += r[t+256]*mk;
  }
  pooled[((b*8 + sc)*512) + t] = a0;
  pooled[((b*8 + sc)*512) + t + 256] = a1;
}

__global__ __launch_bounds__(256)
void head_final_k(const float* __restrict__ pooled, const float* __restrict__ mask,
                  const float* __restrict__ pool_w, const float* __restrict__ pool_b,
                  const float* __restrict__ cls_w, const float* __restrict__ cls_b,
                  const float* __restrict__ cf_w1, const float* __restrict__ cf_b1,
                  const float* __restrict__ cf_w2, const float* __restrict__ cf_b2,
                  const float* __restrict__ aux, float* __restrict__ out)
{
  int b = blockIdx.x, t = threadIdx.x, wid = t>>6, lane = t&63;
  __shared__ __align__(16) float pld[512];
  __shared__ __align__(16) float p2[512];
  __shared__ float red[4];
  float ds = 0.f;
  for(int s=t; s<1024; s+=256) ds += mask[b*1024 + s];
  ds = wred_sum(ds);
  if (lane==0) red[wid] = ds;
  __syncthreads();
  float denom = fmaxf(red[0]+red[1]+red[2]+red[3], 1e-9f);
  float s0 = 0.f, s1 = 0.f;
#pragma unroll
  for(int sc=0;sc<8;sc++){
    s0 += pooled[((b*8+sc)*512) + t];
    s1 += pooled[((b*8+sc)*512) + t + 256];
  }
  pld[t]     = s0/denom;
  pld[t+256] = s1/denom;
  __syncthreads();
#pragma unroll
  for(int jj=0;jj<2;jj++){
    int j = t + jj*256;
    const float4* wr = (const float4*)(pool_w + (long)j*512);
    float acc = 0.f;
    for(int i=0;i<128;i++){
      float4 w4 = wr[i]; float4 x4 = ((const float4*)pld)[i];
      acc += w4.x*x4.x + w4.y*x4.y + w4.z*x4.z + w4.w*x4.w;
    }
    p2[j] = tanhf(acc + pool_b[j]);
  }
  __syncthreads();
  if (t < 4){
    const float4* wr = (const float4*)(cls_w + (long)t*512);
    float acc = 0.f;
    for(int i=0;i<128;i++){
      float4 w4 = wr[i]; float4 x4 = ((const float4*)p2)[i];
      acc += w4.x*x4.x + w4.y*x4.y + w4.z*x4.z + w4.w*x4.w;
    }
    out[b*4 + t] = acc + cls_b[t];
  }
  {
    const float4* wr = (const float4*)(cf_w1 + (long)t*512);
    float acc = 0.f;
    for(int i=0;i<128;i++){
      float4 w4 = wr[i]; float4 x4 = ((const float4*)p2)[i];
      acc += w4.x*x4.x + w4.y*x4.y + w4.z*x4.z + w4.w*x4.w;
    }
    acc = fmaxf(acc + cf_b1[t], 0.f) * cf_w2[t];
    acc = wred_sum(acc);
    __syncthreads();
    if (lane==0) red[wid] = acc;
    __syncthreads();
    if (t == 0){
      float sum = red[0]+red[1]+red[2]+red[3];
      out[17 + b] = 1.f/(1.f + expf(-(sum + cf_b2[0])));
    }
  }
  if (b == 0 && t == 0) out[16] = aux[0]*0.25f;
}

// ---------------------------------------------------------------------------
extern "C" void kernel_launch(void* const* d_in, const int* in_sizes, int n_in,
                              void* d_out, int out_size, void* d_ws, size_t ws_size,
                              hipStream_t stream)
{
  (void)in_sizes; (void)n_in; (void)out_size;
  const float* emb    = (const float*)d_in[0];
  const float* mask   = (const float*)d_in[1];
  const float* in_w   = (const float*)d_in[2];
  const float* in_b   = (const float*)d_in[3];
  const float* out_w  = (const float*)d_in[4];
  const float* out_b  = (const float*)d_in[5];
  const float* ln1_w  = (const float*)d_in[6];
  const float* ln1_b  = (const float*)d_in[7];
  const float* ln2_w  = (const float*)d_in[8];
  const float* ln2_b  = (const float*)d_in[9];
  const float* gate_w = (const float*)d_in[10];
  const float* e_w1   = (const float*)d_in[11];
  const float* e_b1   = (const float*)d_in[12];
  const float* e_w2   = (const float*)d_in[13];
  const float* e_b2   = (const float*)d_in[14];
  const float* mln_w  = (const float*)d_in[15];
  const float* mln_b  = (const float*)d_in[16];
  const float* fln_w  = (const float*)d_in[17];
  const float* fln_b  = (const float*)d_in[18];
  const float* pool_w = (const float*)d_in[19];
  const float* pool_b = (const float*)d_in[20];
  const float* cls_w  = (const float*)d_in[21];
  const float* cls_b  = (const float*)d_in[22];
  const float* cf_w1  = (const float*)d_in[23];
  const float* cf_b1  = (const float*)d_in[24];
  const float* cf_w2  = (const float*)d_in[25];
  const float* cf_b2  = (const float*)d_in[26];
  float* out = (float*)d_out;
  char* ws = (char*)d_ws;

  const size_t MiB = 1024*1024;
  if (ws_size < 218*MiB) return;

  // Workspace layout
  float*          x     = (float*)(ws + 0*MiB);             // 8 MiB fp32
  unsigned short* hb    = (unsigned short*)(ws + 8*MiB);    // 4 MiB bf16
  unsigned short* qkvb  = (unsigned short*)(ws + 12*MiB);   // 12 MiB bf16
  unsigned short* ctx   = (unsigned short*)(ws + 24*MiB);   // 4 MiB bf16
  unsigned short* Vt    = (unsigned short*)(ws + 28*MiB);   // 4 MiB bf16
  unsigned short* mid   = (unsigned short*)(ws + 32*MiB);   // 32 MiB bf16
  float*          eout  = (float*)(ws + 64*MiB);            // 16 MiB fp32
  float*          fout  = (float*)(ws + 64*MiB);            //   (reuse, head)
  unsigned short* w1t   = (unsigned short*)(ws + 80*MiB);   // 64 MiB bf16
  unsigned short* w2t   = (unsigned short*)(ws + 144*MiB);  // 64 MiB bf16
  unsigned short* inwb  = (unsigned short*)(ws + 208*MiB);  // 6 MiB bf16
  unsigned short* outwb = (unsigned short*)(ws + 214*MiB);  // 2 MiB bf16
  char* misc = ws + 216*MiB;
  int*   counts  = (int*)(misc + 0);
  int*   offs    = (int*)(misc + 64);
  float* aux     = (float*)(misc + 128);
  int*   btab    = (int*)(misc + 256);       // 80 ints
  int*   btab64  = (int*)(misc + 1024);      // 144 ints
  float* pooled  = (float*)(misc + 4096);    // 64 KiB
  int*   tok_e   = (int*)(misc + 81920);
  float* tok_w   = (float*)(misc + 114688);
  int*   rowtok  = (int*)(misc + 147456);
  float* roww    = (float*)(misc + 180224);
  int*   rowof   = (int*)(misc + 212992);

  hipMemcpyAsync(x, emb, (size_t)T_*D_*4, hipMemcpyDeviceToDevice, stream);
  hipMemsetAsync(aux, 0, 4, stream);
  // weight prep
  cast_bf16_k<<<512, 256, 0, stream>>>(in_w, inwb, L_*3*D_*D_/8);
  cast_bf16_k<<<256, 256, 0, stream>>>(out_w, outwb, L_*D_*D_/8);
  transpose_cast_k<<<dim3(I_/64, D_/64, 4), 256, 0, stream>>>(e_w1, w1t, D_, I_, 8);
  transpose_cast_k<<<dim3(D_/64, I_/64, 4), 256, 0, stream>>>(e_w2, w2t, I_, D_, 8);

  for (int l=0; l<L_; l++){
    const float* inbl  = in_b  + (size_t)l*3*D_;
    const float* outbl = out_b + (size_t)l*D_;
    const float* gwl   = gate_w + (size_t)l*E_*D_;
    const float* eb1l  = e_b1 + (size_t)l*E_*I_;
    const float* eb2l  = e_b2 + (size_t)l*E_*D_;
    const unsigned short* inwbl  = inwb + (size_t)l*3*D_*D_;
    const unsigned short* outwbl = outwb + (size_t)l*D_*D_;
    const unsigned short* w1tl = w1t + (size_t)l*E_*I_*D_;
    const unsigned short* w2tl = w2t + (size_t)l*E_*D_*I_;

    // h = LN1(x) -> bf16
    ln_w_k<true><<<T_/4, 256, 0, stream>>>(x, ln1_w + (size_t)l*D_, ln1_b + (size_t)l*D_, hb);
    // qkv = h @ in_w^T + in_b -> bf16   (BM=64: 768 blocks)
    gemm_k<64,128,false,false,true,0,false><<<dim3(64,12,1), 256, 0, stream>>>(
      hb, inwbl, qkvb, inbl, nullptr, T_, 3*D_, D_, D_, D_, 3*D_,
      1, 0,0,0,0,0,0, 1.f, nullptr, nullptr, nullptr, nullptr, 0, 0);
    vt_k<<<dim3(4,32), 256, 0, stream>>>(qkvb, Vt);
    // fused attention -> ctx (B,S,512) bf16
    flash_k<<<dim3(16,32), 256, 0, stream>>>(qkvb, Vt, ctx);
    // x = x + ctx @ out_w^T + out_b  (fp32)   (64x64: 512 blocks)
    gemm_k<64,64,false,false,false,0,true><<<dim3(64,8,1), 256, 0, stream>>>(
      ctx, outwbl, x, outbl, x, T_, D_, D_, D_, D_, D_,
      1, 0,0,0,0,0,0, 1.f, nullptr, nullptr, nullptr, nullptr, 0, 0);
    // h2 = LN2(x) -> bf16, + routing (no atomics)
    ln2route_k<<<T_/4, 256, 0, stream>>>(x, ln2_w + (size_t)l*D_, ln2_b + (size_t)l*D_,
                                         hb, gwl, tok_e, tok_w);
    // plan + scatter, single block, LDS atomics only
    plan_scatter_k<<<1, 1024, 0, stream>>>(tok_e, tok_w, offs, counts, aux, btab, btab64,
                                           rowtok, roww, rowof);
    // FFN1: mid = gelu(gather(h2) @ w1^T + b1) -> bf16   (BM=128)
    gemm_k<128,128,true,true,true,1,false><<<dim3(71,16,1), 256, 0, stream>>>(
      hb, w1tl, mid, eb1l, nullptr, 2*T_, I_, D_, D_, D_, I_,
      1, 0,0,0,0,0,0, 1.f, offs, counts, rowtok, btab, (long)I_*D_, I_);
    // FFN2: eout = mid @ w2^T + b2 -> fp32   (BM=64: ~535 live blocks)
    gemm_k<64,128,true,false,false,0,false><<<dim3(136,4,1), 256, 0, stream>>>(
      mid, w2tl, eout, eb2l, nullptr, 2*T_, D_, I_, I_, I_, D_,
      1, 0,0,0,0,0,0, 1.f, offs, counts, nullptr, btab64, (long)D_*I_, D_);
    // x = LN(h2 + combine(eout))
    ln_moe_k<<<T_/4, 256, 0, stream>>>(eout, rowof, roww, mask, hb,
                                       mln_w + (size_t)l*D_, mln_b + (size_t)l*D_, x);
  }
  // head
  ln_w_k<false><<<T_/4, 256, 0, stream>>>(x, fln_w, fln_b, fout);
  pool2_k<<<dim3(4,8), 256, 0, stream>>>(fout, mask, pooled);
  head_final_k<<<4, 256, 0, stream>>>(pooled, mask, pool_w, pool_b, cls_w, cls_b,
                                      cf_w1, cf_b1, cf_w2, cf_b2, aux, out);
}